// Round 1
// baseline (5111.389 us; speedup 1.0000x reference)
//
#include <hip/hip_runtime.h>
#include <hip/hip_bf16.h>
#include <math.h>

#define EPSF 1e-5f
#define B_N 8
#define L_N 256
#define DM_N 1024
#define DI_N 2048
#define DS_N 64
#define NH_N 32
#define HD_N 64
#define DCONV_N 2176
#define DPROJ_N 4256
#define NTOK 2048
#define FFH_N 2048

__device__ __forceinline__ float sigf(float x) { return 1.f / (1.f + __expf(-x)); }

// ---------------- stem: conv1 (7x7 s2 p3, 1->32) + bn1 ----------------
__global__ __launch_bounds__(256) void k_conv1(
    const float* __restrict__ img, const float* __restrict__ w,
    const float* __restrict__ bnp, float* __restrict__ X1) {
  int idx = blockIdx.x * 256 + threadIdx.x;
  if (idx >= B_N * 32 * 32 * 512) return;
  int j = idx & 511;
  int i = (idx >> 9) & 31;
  int co = (idx >> 14) & 31;
  int b = idx >> 19;
  float acc = 0.f;
  const float* wp = w + co * 49;
  const float* ip = img + (size_t)b * 64 * 1024;
#pragma unroll
  for (int r = 0; r < 7; ++r) {
    int y = 2 * i + r - 3;
    if (y < 0 || y >= 64) continue;
#pragma unroll
    for (int s = 0; s < 7; ++s) {
      int x = 2 * j + s - 3;
      if (x < 0 || x >= 1024) continue;
      acc = fmaf(ip[y * 1024 + x], wp[r * 7 + s], acc);
    }
  }
  float g = bnp[co], be = bnp[32 + co], mm = bnp[64 + co], vv = bnp[96 + co];
  X1[idx] = (acc - mm) * rsqrtf(vv + EPSF) * g + be;
}

// ------- stem: conv2 (7x7 s2 p3, 32->64)+bn2 + ds(1x1 s4)+bn + relu -> Tok -------
// grid (b, ho_tile=4, wo_tile=8), 256 thr; out tile 4ho x 32wo x 64co
__global__ __launch_bounds__(256) void k_conv2(
    const float* __restrict__ X1, const float* __restrict__ w2,
    const float* __restrict__ bn2p, const float* __restrict__ img,
    const float* __restrict__ dsw, const float* __restrict__ dsbnp,
    float* __restrict__ Tok) {
  __shared__ float sIn[13 * 70];
  __shared__ float sW[64 * 49];
  int b = blockIdx.x, ht = blockIdx.y, wt = blockIdx.z;
  int ho0 = ht * 4, wo0 = wt * 32;
  int t = threadIdx.x;
  int wo = t & 31, cg = t >> 5;
  float acc[4][8];
#pragma unroll
  for (int a = 0; a < 4; ++a)
#pragma unroll
    for (int c = 0; c < 8; ++c) acc[a][c] = 0.f;
  for (int ci = 0; ci < 32; ++ci) {
    __syncthreads();
    for (int p = t; p < 13 * 70; p += 256) {
      int rr = p / 70, cc = p % 70;
      int y = 2 * ho0 - 3 + rr, x = 2 * wo0 - 3 + cc;
      float v = 0.f;
      if (y >= 0 && y < 32 && x >= 0 && x < 512)
        v = X1[((size_t)(b * 32 + ci) * 32 + y) * 512 + x];
      sIn[p] = v;
    }
    for (int p = t; p < 64 * 49; p += 256) {
      int co = p / 49, rs = p % 49;
      sW[p] = w2[(size_t)(co * 32 + ci) * 49 + rs];
    }
    __syncthreads();
    for (int r = 0; r < 7; ++r) {
#pragma unroll
      for (int s = 0; s < 7; ++s) {
        float iv[4];
#pragma unroll
        for (int ho = 0; ho < 4; ++ho)
          iv[ho] = sIn[(2 * ho + r) * 70 + 2 * wo + s];
#pragma unroll
        for (int c8 = 0; c8 < 8; ++c8) {
          float wv = sW[(cg * 8 + c8) * 49 + r * 7 + s];
#pragma unroll
          for (int ho = 0; ho < 4; ++ho)
            acc[ho][c8] = fmaf(iv[ho], wv, acc[ho][c8]);
        }
      }
    }
  }
#pragma unroll
  for (int c8 = 0; c8 < 8; ++c8) {
    int co = cg * 8 + c8;
    float g = bn2p[co], be = bn2p[64 + co], mm = bn2p[128 + co], vv = bn2p[192 + co];
    float sc = rsqrtf(vv + EPSF) * g, sh = be - mm * sc;
    float dg = dsbnp[co], dbe = dsbnp[64 + co], dmm = dsbnp[128 + co], dvv = dsbnp[192 + co];
    float dsc = rsqrtf(dvv + EPSF) * dg, dsh = dbe - dmm * dsc;
    float wv = dsw[co];
#pragma unroll
    for (int ho = 0; ho < 4; ++ho) {
      int i = ho0 + ho, j = wo0 + wo;
      float dval = fmaf(img[(size_t)(b * 64 + 4 * i) * 1024 + 4 * j] * wv, dsc, dsh);
      float v = fmaf(acc[ho][c8], sc, sh) + dval;
      v = v > 0.f ? v : 0.f;
      // tokens[b, co*16+i, j] in token-major: Tok[(b*256+j)][co*16+i]
      Tok[(size_t)(b * 256 + j) * DM_N + co * 16 + i] = v;
    }
  }
}

// ---------------- generic fp32 GEMM: C[M,N] = A[M,K] * Bw[N,K]^T ----------------
// MODE 0: plain store. MODE 1: bn(v)+res. MODE 2: relu(bn(v+bias)). MODE 3: bn(v+bias)+res.
template <int MODE>
__global__ __launch_bounds__(256) void k_gemm(
    const float* __restrict__ A, const float* __restrict__ Bw,
    float* C, int M, int N, int K,
    const float* __restrict__ bias, const float* __restrict__ bnp,
    const float* res) {
  __shared__ float As[16][132];
  __shared__ float Bs[16][132];
  int n0 = blockIdx.x * 128, m0 = blockIdx.y * 128;
  int t = threadIdx.x;
  int tx = t & 15, ty = t >> 4;
  float acc[8][8];
#pragma unroll
  for (int i = 0; i < 8; ++i)
#pragma unroll
    for (int j = 0; j < 8; ++j) acc[i][j] = 0.f;
  for (int k0 = 0; k0 < K; k0 += 16) {
    float4 av[2], bv[2];
#pragma unroll
    for (int u = 0; u < 2; ++u) {
      int cidx = t + u * 256;
      int row = cidx >> 2, kk0 = (cidx & 3) * 4;
      av[u] = *(const float4*)&A[(size_t)(m0 + row) * K + k0 + kk0];
      int rn = n0 + row;
      if (rn < N)
        bv[u] = *(const float4*)&Bw[(size_t)rn * K + k0 + kk0];
      else
        bv[u] = make_float4(0.f, 0.f, 0.f, 0.f);
    }
    __syncthreads();
#pragma unroll
    for (int u = 0; u < 2; ++u) {
      int cidx = t + u * 256;
      int row = cidx >> 2, kk0 = (cidx & 3) * 4;
      As[kk0 + 0][row] = av[u].x;
      As[kk0 + 1][row] = av[u].y;
      As[kk0 + 2][row] = av[u].z;
      As[kk0 + 3][row] = av[u].w;
      Bs[kk0 + 0][row] = bv[u].x;
      Bs[kk0 + 1][row] = bv[u].y;
      Bs[kk0 + 2][row] = bv[u].z;
      Bs[kk0 + 3][row] = bv[u].w;
    }
    __syncthreads();
#pragma unroll
    for (int kk = 0; kk < 16; ++kk) {
      float4 a0 = *(const float4*)&As[kk][ty * 4];
      float4 a1 = *(const float4*)&As[kk][64 + ty * 4];
      float4 b0 = *(const float4*)&Bs[kk][tx * 4];
      float4 b1 = *(const float4*)&Bs[kk][64 + tx * 4];
      float aa[8] = {a0.x, a0.y, a0.z, a0.w, a1.x, a1.y, a1.z, a1.w};
      float bb[8] = {b0.x, b0.y, b0.z, b0.w, b1.x, b1.y, b1.z, b1.w};
#pragma unroll
      for (int i = 0; i < 8; ++i)
#pragma unroll
        for (int j = 0; j < 8; ++j)
          acc[i][j] = fmaf(aa[i], bb[j], acc[i][j]);
    }
    __syncthreads();
  }
#pragma unroll
  for (int i = 0; i < 8; ++i) {
    int row = m0 + ((i < 4) ? (ty * 4 + i) : (64 + ty * 4 + i - 4));
#pragma unroll
    for (int j = 0; j < 8; ++j) {
      int col = n0 + ((j < 4) ? (tx * 4 + j) : (64 + tx * 4 + j - 4));
      if (col >= N) continue;
      float v = acc[i][j];
      if (MODE == 2 || MODE == 3) v += bias[col];
      if (MODE >= 1) {
        float g = bnp[col], be = bnp[N + col], mm = bnp[2 * N + col], vv = bnp[3 * N + col];
        v = fmaf(v - mm, rsqrtf(vv + EPSF) * g, be);
      }
      if (MODE == 2) v = v > 0.f ? v : 0.f;
      if (MODE == 1 || MODE == 3) v += res[(size_t)row * N + col];
      C[(size_t)row * N + col] = v;
    }
  }
}

// ------- causal depthwise conv1d + silu on xBC; softplus dt; dA -------
__global__ __launch_bounds__(256) void k_convprep(
    const float* __restrict__ ZX, const float* __restrict__ cw,
    const float* __restrict__ cb, const float* __restrict__ dtb,
    const float* __restrict__ Alog, float* __restrict__ XBC,
    float* __restrict__ DT, float* __restrict__ DA) {
  int m = blockIdx.x;
  int c = blockIdx.y * 256 + threadIdx.x;
  int l = m & 255;
  if (c < DCONV_N) {
    const float* cwp = cw + c * 4;
    float acc = cb[c];
#pragma unroll
    for (int k = 0; k < 4; ++k) {
      int dl = l + k - 3;
      if (dl >= 0)
        acc = fmaf(ZX[(size_t)(m + k - 3) * DPROJ_N + DI_N + c], cwp[k], acc);
    }
    XBC[(size_t)m * DCONV_N + c] = acc * sigf(acc);
  } else if (c < DCONV_N + NH_N) {
    int h = c - DCONV_N;
    float xx = ZX[(size_t)m * DPROJ_N + DI_N + DCONV_N + h] + dtb[h];
    float dt = xx > 20.f ? xx : log1pf(__expf(xx));
    DT[m * NH_N + h] = dt;
    DA[m * NH_N + h] = __expf(-dt * __expf(Alog[h]));
  }
}

// ------- selective scan: grid 256 = (b,h); 256 thr; thread owns (p = t>>2, 16 n) -------
__global__ __launch_bounds__(256) void k_scan(
    const float* __restrict__ XBC, const float* __restrict__ DT,
    const float* __restrict__ DA, const float* __restrict__ Dp,
    float* __restrict__ Y) {
  int b = blockIdx.x >> 5, h = blockIdx.x & 31;
  int t = threadIdx.x;
  int p = t >> 2, nq = t & 3, n0 = nq * 16;
  float hs[16];
#pragma unroll
  for (int j = 0; j < 16; ++j) hs[j] = 0.f;
  float Dh = Dp[h];
  for (int l = 0; l < L_N; ++l) {
    int m = b * L_N + l;
    const float* row = XBC + (size_t)m * DCONV_N;
    float xv = row[h * HD_N + p];
    float dt = DT[m * NH_N + h];
    float da = DA[m * NH_N + h];
    float dtx = dt * xv;
    float py = 0.f;
#pragma unroll
    for (int q = 0; q < 4; ++q) {
      float4 Bv = *(const float4*)(row + DI_N + n0 + 4 * q);
      float4 Cv = *(const float4*)(row + DI_N + DS_N + n0 + 4 * q);
      hs[4 * q + 0] = fmaf(hs[4 * q + 0], da, dtx * Bv.x); py = fmaf(hs[4 * q + 0], Cv.x, py);
      hs[4 * q + 1] = fmaf(hs[4 * q + 1], da, dtx * Bv.y); py = fmaf(hs[4 * q + 1], Cv.y, py);
      hs[4 * q + 2] = fmaf(hs[4 * q + 2], da, dtx * Bv.z); py = fmaf(hs[4 * q + 2], Cv.z, py);
      hs[4 * q + 3] = fmaf(hs[4 * q + 3], da, dtx * Bv.w); py = fmaf(hs[4 * q + 3], Cv.w, py);
    }
    py += __shfl_xor(py, 1);
    py += __shfl_xor(py, 2);
    if (nq == 0) Y[(size_t)m * DI_N + h * HD_N + p] = fmaf(Dh, xv, py);
  }
}

// ------- gate with silu(z) + RMSNorm (over DI) -------
__global__ __launch_bounds__(256) void k_gatenorm(
    const float* __restrict__ Y, const float* __restrict__ ZX,
    const float* __restrict__ nw, float* __restrict__ YN) {
  int m = blockIdx.x, t = threadIdx.x;
  const float* y = Y + (size_t)m * DI_N;
  const float* z = ZX + (size_t)m * DPROJ_N;
  float vals[8];
  float ss = 0.f;
#pragma unroll
  for (int j = 0; j < 8; ++j) {
    int c = t + 256 * j;
    float zz = z[c];
    float vv = y[c] * zz * sigf(zz);
    vals[j] = vv;
    ss = fmaf(vv, vv, ss);
  }
#pragma unroll
  for (int o = 1; o < 64; o <<= 1) ss += __shfl_xor(ss, o);
  __shared__ float sred[4];
  if ((t & 63) == 0) sred[t >> 6] = ss;
  __syncthreads();
  float tot = sred[0] + sred[1] + sred[2] + sred[3];
  float scale = rsqrtf(tot * (1.f / DI_N) + EPSF);
#pragma unroll
  for (int j = 0; j < 8; ++j) {
    int c = t + 256 * j;
    YN[(size_t)m * DI_N + c] = vals[j] * scale * nw[c];
  }
}

// ------- final transpose: Tok[m][d] -> out[b][d][l] -------
__global__ __launch_bounds__(256) void k_transpose(
    const float* __restrict__ Tok, float* __restrict__ out) {
  __shared__ float tile[32][33];
  int d0 = blockIdx.x * 32, m0 = blockIdx.y * 32;
  int tx = threadIdx.x & 31, ty = threadIdx.x >> 5;
  for (int i = ty; i < 32; i += 8)
    tile[i][tx] = Tok[(size_t)(m0 + i) * DM_N + d0 + tx];
  __syncthreads();
  int b = m0 >> 8, l0 = m0 & 255;
  for (int i = ty; i < 32; i += 8)
    out[((size_t)b * DM_N + d0 + i) * L_N + l0 + tx] = tile[tx][i];
}

extern "C" void kernel_launch(void* const* d_in, const int* in_sizes, int n_in,
                              void* d_out, int out_size, void* d_ws, size_t ws_size,
                              hipStream_t stream) {
  const float* image = (const float*)d_in[0];
  const float* conv1_w = (const float*)d_in[1];
  const float* bn1 = (const float*)d_in[2];
  const float* conv2_w = (const float*)d_in[3];
  const float* bn2 = (const float*)d_in[4];
  const float* ds_w = (const float*)d_in[5];
  const float* ds_bn = (const float*)d_in[6];
  const float* in_proj_w = (const float*)d_in[7];
  const float* conv1d_w = (const float*)d_in[8];
  const float* conv1d_b = (const float*)d_in[9];
  const float* dt_bias = (const float*)d_in[10];
  const float* A_log = (const float*)d_in[11];
  const float* Dpar = (const float*)d_in[12];
  const float* norm_w = (const float*)d_in[13];
  const float* out_proj_w = (const float*)d_in[14];
  const float* blk_bn = (const float*)d_in[15];
  const float* ff_w1 = (const float*)d_in[16];
  const float* ff_b1 = (const float*)d_in[17];
  const float* ff_bn1 = (const float*)d_in[18];
  const float* ff_w2 = (const float*)d_in[19];
  const float* ff_b2 = (const float*)d_in[20];
  const float* ff_bn2 = (const float*)d_in[21];

  // workspace layout (floats): ~112 MB total
  float* ws = (float*)d_ws;
  float* Tok = ws;                                        // 2048*1024
  float* ZX = Tok + (size_t)NTOK * DM_N;                  // 2048*4256
  float* XBC = ZX + (size_t)NTOK * DPROJ_N;               // 2048*2176
  float* DTb = XBC + (size_t)NTOK * DCONV_N;              // 2048*32
  float* DAb = DTb + (size_t)NTOK * NH_N;                 // 2048*32
  float* YR = DAb + (size_t)NTOK * NH_N;                  // 2048*2048
  float* YN = YR + (size_t)NTOK * DI_N;                   // 2048*2048
  float* H1 = YN + (size_t)NTOK * DI_N;                   // 2048*2048
  float* X1 = YR;  // stem scratch aliases YR (8*32*32*512 == 2048*2048)

  k_conv1<<<(B_N * 32 * 32 * 512) / 256, 256, 0, stream>>>(image, conv1_w, bn1, X1);
  k_conv2<<<dim3(8, 4, 8), 256, 0, stream>>>(X1, conv2_w, bn2, image, ds_w, ds_bn, Tok);

  for (int i = 0; i < 4; ++i) {
    const float* Wi = in_proj_w + (size_t)i * DPROJ_N * DM_N;
    const float* cw = conv1d_w + (size_t)i * DCONV_N * 4;
    const float* cb = conv1d_b + (size_t)i * DCONV_N;
    const float* dtb = dt_bias + i * NH_N;
    const float* al = A_log + i * NH_N;
    const float* dd = Dpar + i * NH_N;
    const float* nw = norm_w + i * DI_N;
    const float* Wo = out_proj_w + (size_t)i * DM_N * DI_N;
    const float* bbn = blk_bn + (size_t)i * 4 * DM_N;
    const float* w1 = ff_w1 + (size_t)i * FFH_N * DM_N;
    const float* b1 = ff_b1 + i * FFH_N;
    const float* fbn1 = ff_bn1 + (size_t)i * 4 * FFH_N;
    const float* w2 = ff_w2 + (size_t)i * DM_N * FFH_N;
    const float* b2 = ff_b2 + i * DM_N;
    const float* fbn2 = ff_bn2 + (size_t)i * 4 * DM_N;

    k_gemm<0><<<dim3(34, 16), 256, 0, stream>>>(Tok, Wi, ZX, NTOK, DPROJ_N, DM_N,
                                                nullptr, nullptr, nullptr);
    k_convprep<<<dim3(NTOK, 9), 256, 0, stream>>>(ZX, cw, cb, dtb, al, XBC, DTb, DAb);
    k_scan<<<256, 256, 0, stream>>>(XBC, DTb, DAb, dd, YR);
    k_gatenorm<<<NTOK, 256, 0, stream>>>(YR, ZX, nw, YN);
    k_gemm<1><<<dim3(8, 16), 256, 0, stream>>>(YN, Wo, Tok, NTOK, DM_N, DI_N,
                                               nullptr, bbn, Tok);
    k_gemm<2><<<dim3(16, 16), 256, 0, stream>>>(Tok, w1, H1, NTOK, FFH_N, DM_N,
                                                b1, fbn1, nullptr);
    k_gemm<3><<<dim3(8, 16), 256, 0, stream>>>(H1, w2, Tok, NTOK, DM_N, FFH_N,
                                               b2, fbn2, Tok);
  }
  k_transpose<<<dim3(32, 64), 256, 0, stream>>>(Tok, (float*)d_out);
}

// Round 4
// 1601.222 us; speedup vs baseline: 3.1922x; 3.1922x over previous
//
#include <hip/hip_runtime.h>
#include <hip/hip_bf16.h>
#include <hip/hip_fp16.h>
#include <math.h>

#define EPSF 1e-5f
#define B_N 8
#define L_N 256
#define DM_N 1024
#define DI_N 2048
#define DS_N 64
#define NH_N 32
#define HD_N 64
#define DCONV_N 2176
#define DPROJ_N 4256
#define NTOK 2048
#define FFH_N 2048
#define NPAD_INPROJ 4352  // 4256 padded to multiple of 128

typedef _Float16 f16x8 __attribute__((ext_vector_type(8)));
typedef float f32x4 __attribute__((ext_vector_type(4)));

__device__ __forceinline__ float sigf(float x) { return 1.f / (1.f + __expf(-x)); }

__device__ __forceinline__ void gll16(const void* g, void* l) {
  typedef __attribute__((address_space(1))) const void gv;
  typedef __attribute__((address_space(3))) void lv;
  __builtin_amdgcn_global_load_lds((gv*)g, (lv*)l, 16, 0, 0);
}

// ---------------- fp32 -> fp16 converter (8 elems/thread), zero-pads to ntot ----------------
__global__ __launch_bounds__(256) void k_tohalf8(
    const float* __restrict__ src, _Float16* __restrict__ dst, int n, int ntot) {
  int i = (blockIdx.x * 256 + threadIdx.x) * 8;
  if (i >= ntot) return;
  f16x8 o;
  if (i < n) {
    float4 a = *(const float4*)(src + i);
    float4 b = *(const float4*)(src + i + 4);
    o[0] = (_Float16)a.x; o[1] = (_Float16)a.y; o[2] = (_Float16)a.z; o[3] = (_Float16)a.w;
    o[4] = (_Float16)b.x; o[5] = (_Float16)b.y; o[6] = (_Float16)b.z; o[7] = (_Float16)b.w;
  } else {
#pragma unroll
    for (int j = 0; j < 8; ++j) o[j] = (_Float16)0.f;
  }
  *(f16x8*)(dst + i) = o;
}

// ---------------- stem: conv1 (7x7 s2 p3, 1->32) + bn1 ----------------
__global__ __launch_bounds__(256) void k_conv1(
    const float* __restrict__ img, const float* __restrict__ w,
    const float* __restrict__ bnp, float* __restrict__ X1) {
  int idx = blockIdx.x * 256 + threadIdx.x;
  if (idx >= B_N * 32 * 32 * 512) return;
  int j = idx & 511;
  int i = (idx >> 9) & 31;
  int co = (idx >> 14) & 31;
  int b = idx >> 19;
  float acc = 0.f;
  const float* wp = w + co * 49;
  const float* ip = img + (size_t)b * 64 * 1024;
#pragma unroll
  for (int r = 0; r < 7; ++r) {
    int y = 2 * i + r - 3;
    if (y < 0 || y >= 64) continue;
#pragma unroll
    for (int s = 0; s < 7; ++s) {
      int x = 2 * j + s - 3;
      if (x < 0 || x >= 1024) continue;
      acc = fmaf(ip[y * 1024 + x], wp[r * 7 + s], acc);
    }
  }
  float g = bnp[co], be = bnp[32 + co], mm = bnp[64 + co], vv = bnp[96 + co];
  X1[idx] = (acc - mm) * rsqrtf(vv + EPSF) * g + be;
}

// ------- stem: conv2 (7x7 s2 p3, 32->64)+bn2 + ds(1x1 s4)+bn + relu -> Tok (+fp16 mirror) -------
__global__ __launch_bounds__(256) void k_conv2(
    const float* __restrict__ X1, const float* __restrict__ w2,
    const float* __restrict__ bn2p, const float* __restrict__ img,
    const float* __restrict__ dsw, const float* __restrict__ dsbnp,
    float* __restrict__ Tok, _Float16* __restrict__ Tok16) {
  __shared__ float sIn[13 * 70];
  __shared__ float sW[64 * 49];
  int b = blockIdx.x, ht = blockIdx.y, wt = blockIdx.z;
  int ho0 = ht * 4, wo0 = wt * 32;
  int t = threadIdx.x;
  int wo = t & 31, cg = t >> 5;
  float acc[4][8];
#pragma unroll
  for (int a = 0; a < 4; ++a)
#pragma unroll
    for (int c = 0; c < 8; ++c) acc[a][c] = 0.f;
  for (int ci = 0; ci < 32; ++ci) {
    __syncthreads();
    for (int p = t; p < 13 * 70; p += 256) {
      int rr = p / 70, cc = p % 70;
      int y = 2 * ho0 - 3 + rr, x = 2 * wo0 - 3 + cc;
      float v = 0.f;
      if (y >= 0 && y < 32 && x >= 0 && x < 512)
        v = X1[((size_t)(b * 32 + ci) * 32 + y) * 512 + x];
      sIn[p] = v;
    }
    for (int p = t; p < 64 * 49; p += 256) {
      int co = p / 49, rs = p % 49;
      sW[p] = w2[(size_t)(co * 32 + ci) * 49 + rs];
    }
    __syncthreads();
    for (int r = 0; r < 7; ++r) {
#pragma unroll
      for (int s = 0; s < 7; ++s) {
        float iv[4];
#pragma unroll
        for (int ho = 0; ho < 4; ++ho)
          iv[ho] = sIn[(2 * ho + r) * 70 + 2 * wo + s];
#pragma unroll
        for (int c8 = 0; c8 < 8; ++c8) {
          float wv = sW[(cg * 8 + c8) * 49 + r * 7 + s];
#pragma unroll
          for (int ho = 0; ho < 4; ++ho)
            acc[ho][c8] = fmaf(iv[ho], wv, acc[ho][c8]);
        }
      }
    }
  }
#pragma unroll
  for (int c8 = 0; c8 < 8; ++c8) {
    int co = cg * 8 + c8;
    float g = bn2p[co], be = bn2p[64 + co], mm = bn2p[128 + co], vv = bn2p[192 + co];
    float sc = rsqrtf(vv + EPSF) * g, sh = be - mm * sc;
    float dg = dsbnp[co], dbe = dsbnp[64 + co], dmm = dsbnp[128 + co], dvv = dsbnp[192 + co];
    float dsc = rsqrtf(dvv + EPSF) * dg, dsh = dbe - dmm * dsc;
    float wv = dsw[co];
#pragma unroll
    for (int ho = 0; ho < 4; ++ho) {
      int i = ho0 + ho, j = wo0 + wo;
      float dval = fmaf(img[(size_t)(b * 64 + 4 * i) * 1024 + 4 * j] * wv, dsc, dsh);
      float v = fmaf(acc[ho][c8], sc, sh) + dval;
      v = v > 0.f ? v : 0.f;
      size_t o = (size_t)(b * 256 + j) * DM_N + co * 16 + i;
      Tok[o] = v;
      Tok16[o] = (_Float16)v;
    }
  }
}

// ---------------- MFMA fp16 GEMM: C[M,N] = A[M,K] * W[N,K]^T + fused epilogue ----------------
// MODE 0: C32 = v.                    (in_proj -> ZX)
// MODE 1: v=bn(v)+res; C32,C16.       (out_proj -> Tok,Tok16)
// MODE 2: v=relu(bn(v+bias)); C16.    (ff1 -> H116)
// MODE 3: v=bn(v+bias)+res; C32,C16.  (ff2 -> Tok,Tok16)
template <int MODE, int BM>
__global__ __launch_bounds__(256) void k_mgemm(
    const _Float16* __restrict__ A, const _Float16* __restrict__ W,
    int M, int N, int K,
    const float* __restrict__ bias, const float* __restrict__ bnp,
    const float* __restrict__ res, float* __restrict__ C32,
    _Float16* __restrict__ C16) {
  constexpr int MI = BM / 32;  // A-frags per wave
  __shared__ _Float16 As[2][BM * 32];
  __shared__ _Float16 Bs[2][128 * 32];
  const int t = threadIdx.x;
  const int w = t >> 6, lane = t & 63;
  const int lr = lane & 15, kh = lane >> 4;
  const int wm = w >> 1, wn = w & 1;
  const int m0 = blockIdx.y * BM, n0 = blockIdx.x * 128;
  f32x4 acc[MI][4];
#pragma unroll
  for (int i = 0; i < MI; ++i)
#pragma unroll
    for (int j = 0; j < 4; ++j) acc[i][j] = (f32x4)(0.f);

  const int nt = K >> 5;
  auto STAGE = [&](int bb, int kt) {
    const int k0 = kt << 5;
#pragma unroll
    for (int it = 0; it < BM / 64; ++it) {  // A: BM*4 chunks of 16B
      int c = it * 256 + w * 64 + lane;
      int row = c >> 2, kq = c & 3;
      gll16(A + (size_t)(m0 + row) * K + k0 + kq * 8,
            &As[bb][(size_t)(it * 256 + w * 64) * 8]);
    }
#pragma unroll
    for (int it = 0; it < 2; ++it) {  // B: 512 chunks
      int c = it * 256 + w * 64 + lane;
      int row = c >> 2, kq = c & 3;
      gll16(W + (size_t)(n0 + row) * K + k0 + kq * 8,
            &Bs[bb][(size_t)(it * 256 + w * 64) * 8]);
    }
  };

  STAGE(0, 0);
  __syncthreads();
  int bb = 0;
  for (int kt = 0; kt < nt; ++kt) {
    if (kt + 1 < nt) STAGE(bb ^ 1, kt + 1);
    f16x8 af[MI], bf[4];
#pragma unroll
    for (int i = 0; i < MI; ++i)
      af[i] = *(const f16x8*)&As[bb][(size_t)((wm * (BM / 2) + i * 16 + lr) * 32 + kh * 8)];
#pragma unroll
    for (int j = 0; j < 4; ++j)
      bf[j] = *(const f16x8*)&Bs[bb][(size_t)((wn * 64 + j * 16 + lr) * 32 + kh * 8)];
#pragma unroll
    for (int i = 0; i < MI; ++i)
#pragma unroll
      for (int j = 0; j < 4; ++j)
        acc[i][j] = __builtin_amdgcn_mfma_f32_16x16x32_f16(af[i], bf[j], acc[i][j], 0, 0, 0);
    __syncthreads();
    bb ^= 1;
  }

#pragma unroll
  for (int j = 0; j < 4; ++j) {
    int cn = n0 + wn * 64 + j * 16 + lr;
    if (cn >= N) continue;
    float g = 1.f, be = 0.f, sc = 1.f, sh = 0.f, bs = 0.f;
    if (MODE >= 1) {
      g = bnp[cn]; be = bnp[N + cn];
      float mm = bnp[2 * N + cn], vv = bnp[3 * N + cn];
      sc = rsqrtf(vv + EPSF) * g;
      sh = be - mm * sc;
    }
    if (MODE == 2 || MODE == 3) bs = bias[cn];
#pragma unroll
    for (int i = 0; i < MI; ++i) {
#pragma unroll
      for (int rr = 0; rr < 4; ++rr) {
        int r = m0 + wm * (BM / 2) + i * 16 + kh * 4 + rr;
        float v = acc[i][j][rr];
        if (MODE == 2 || MODE == 3) v += bs;
        if (MODE >= 1) v = fmaf(v, sc, sh);
        if (MODE == 2) v = v > 0.f ? v : 0.f;
        if (MODE == 1 || MODE == 3) v += res[(size_t)r * N + cn];
        size_t o = (size_t)r * N + cn;
        if (MODE != 2) C32[o] = v;
        if (MODE >= 1) C16[o] = (_Float16)v;
      }
    }
  }
}

// ------- causal depthwise conv1d + silu on xBC; softplus dt; dA -------
__global__ __launch_bounds__(256) void k_convprep(
    const float* __restrict__ ZX, const float* __restrict__ cw,
    const float* __restrict__ cb, const float* __restrict__ dtb,
    const float* __restrict__ Alog, float* __restrict__ XBC,
    float* __restrict__ DT, float* __restrict__ DA) {
  int m = blockIdx.x;
  int c = blockIdx.y * 256 + threadIdx.x;
  int l = m & 255;
  if (c < DCONV_N) {
    const float* cwp = cw + c * 4;
    float acc = cb[c];
#pragma unroll
    for (int k = 0; k < 4; ++k) {
      int dl = l + k - 3;
      if (dl >= 0)
        acc = fmaf(ZX[(size_t)(m + k - 3) * DPROJ_N + DI_N + c], cwp[k], acc);
    }
    XBC[(size_t)m * DCONV_N + c] = acc * sigf(acc);
  } else if (c < DCONV_N + NH_N) {
    int h = c - DCONV_N;
    float xx = ZX[(size_t)m * DPROJ_N + DI_N + DCONV_N + h] + dtb[h];
    float dt = xx > 20.f ? xx : log1pf(__expf(xx));
    DT[m * NH_N + h] = dt;
    DA[m * NH_N + h] = __expf(-dt * __expf(Alog[h]));
  }
}

// ------- selective scan: grid 256 = (b,h); 256 thr; thread owns (p = t>>2, 16 n) -------
__global__ __launch_bounds__(256) void k_scan(
    const float* __restrict__ XBC, const float* __restrict__ DT,
    const float* __restrict__ DA, const float* __restrict__ Dp,
    float* __restrict__ Y) {
  int b = blockIdx.x >> 5, h = blockIdx.x & 31;
  int t = threadIdx.x;
  int p = t >> 2, nq = t & 3, n0 = nq * 16;
  float hs[16];
#pragma unroll
  for (int j = 0; j < 16; ++j) hs[j] = 0.f;
  float Dh = Dp[h];
  for (int l = 0; l < L_N; ++l) {
    int m = b * L_N + l;
    const float* row = XBC + (size_t)m * DCONV_N;
    float xv = row[h * HD_N + p];
    float dt = DT[m * NH_N + h];
    float da = DA[m * NH_N + h];
    float dtx = dt * xv;
    float py = 0.f;
#pragma unroll
    for (int q = 0; q < 4; ++q) {
      float4 Bv = *(const float4*)(row + DI_N + n0 + 4 * q);
      float4 Cv = *(const float4*)(row + DI_N + DS_N + n0 + 4 * q);
      hs[4 * q + 0] = fmaf(hs[4 * q + 0], da, dtx * Bv.x); py = fmaf(hs[4 * q + 0], Cv.x, py);
      hs[4 * q + 1] = fmaf(hs[4 * q + 1], da, dtx * Bv.y); py = fmaf(hs[4 * q + 1], Cv.y, py);
      hs[4 * q + 2] = fmaf(hs[4 * q + 2], da, dtx * Bv.z); py = fmaf(hs[4 * q + 2], Cv.z, py);
      hs[4 * q + 3] = fmaf(hs[4 * q + 3], da, dtx * Bv.w); py = fmaf(hs[4 * q + 3], Cv.w, py);
    }
    py += __shfl_xor(py, 1);
    py += __shfl_xor(py, 2);
    if (nq == 0) Y[(size_t)m * DI_N + h * HD_N + p] = fmaf(Dh, xv, py);
  }
}

// ------- gate with silu(z) + RMSNorm (over DI) -> fp16 -------
__global__ __launch_bounds__(256) void k_gatenorm(
    const float* __restrict__ Y, const float* __restrict__ ZX,
    const float* __restrict__ nw, _Float16* __restrict__ YN16) {
  int m = blockIdx.x, t = threadIdx.x;
  const float* y = Y + (size_t)m * DI_N;
  const float* z = ZX + (size_t)m * DPROJ_N;
  float vals[8];
  float ss = 0.f;
#pragma unroll
  for (int j = 0; j < 8; ++j) {
    int c = t + 256 * j;
    float zz = z[c];
    float vv = y[c] * zz * sigf(zz);
    vals[j] = vv;
    ss = fmaf(vv, vv, ss);
  }
#pragma unroll
  for (int o = 1; o < 64; o <<= 1) ss += __shfl_xor(ss, o);
  __shared__ float sred[4];
  if ((t & 63) == 0) sred[t >> 6] = ss;
  __syncthreads();
  float tot = sred[0] + sred[1] + sred[2] + sred[3];
  float scale = rsqrtf(tot * (1.f / DI_N) + EPSF);
#pragma unroll
  for (int j = 0; j < 8; ++j) {
    int c = t + 256 * j;
    YN16[(size_t)m * DI_N + c] = (_Float16)(vals[j] * scale * nw[c]);
  }
}

// ------- final transpose: Tok[m][d] -> out[b][d][l] -------
__global__ __launch_bounds__(256) void k_transpose(
    const float* __restrict__ Tok, float* __restrict__ out) {
  __shared__ float tile[32][33];
  int d0 = blockIdx.x * 32, m0 = blockIdx.y * 32;
  int tx = threadIdx.x & 31, ty = threadIdx.x >> 5;
  for (int i = ty; i < 32; i += 8)
    tile[i][tx] = Tok[(size_t)(m0 + i) * DM_N + d0 + tx];
  __syncthreads();
  int b = m0 >> 8, l0 = m0 & 255;
  for (int i = ty; i < 32; i += 8)
    out[((size_t)b * DM_N + d0 + i) * L_N + l0 + tx] = tile[tx][i];
}

extern "C" void kernel_launch(void* const* d_in, const int* in_sizes, int n_in,
                              void* d_out, int out_size, void* d_ws, size_t ws_size,
                              hipStream_t stream) {
  const float* image = (const float*)d_in[0];
  const float* conv1_w = (const float*)d_in[1];
  const float* bn1 = (const float*)d_in[2];
  const float* conv2_w = (const float*)d_in[3];
  const float* bn2 = (const float*)d_in[4];
  const float* ds_w = (const float*)d_in[5];
  const float* ds_bn = (const float*)d_in[6];
  const float* in_proj_w = (const float*)d_in[7];
  const float* conv1d_w = (const float*)d_in[8];
  const float* conv1d_b = (const float*)d_in[9];
  const float* dt_bias = (const float*)d_in[10];
  const float* A_log = (const float*)d_in[11];
  const float* Dpar = (const float*)d_in[12];
  const float* norm_w = (const float*)d_in[13];
  const float* out_proj_w = (const float*)d_in[14];
  const float* blk_bn = (const float*)d_in[15];
  const float* ff_w1 = (const float*)d_in[16];
  const float* ff_b1 = (const float*)d_in[17];
  const float* ff_bn1 = (const float*)d_in[18];
  const float* ff_w2 = (const float*)d_in[19];
  const float* ff_b2 = (const float*)d_in[20];
  const float* ff_bn2 = (const float*)d_in[21];

  // workspace layout: fp32 region then fp16 region (~103 MB total)
  float* ws = (float*)d_ws;
  float* Tok = ws;                        // 2048*1024
  float* ZX = Tok + (size_t)NTOK * DM_N;  // 2048*4256
  float* XBC = ZX + (size_t)NTOK * DPROJ_N;
  float* DTb = XBC + (size_t)NTOK * DCONV_N;
  float* DAb = DTb + (size_t)NTOK * NH_N;
  float* YR = DAb + (size_t)NTOK * NH_N;  // 2048*2048, stem X1 aliases this
  _Float16* Tok16 = (_Float16*)(YR + (size_t)NTOK * DI_N);  // 2048*1024
  _Float16* YN16 = Tok16 + (size_t)NTOK * DM_N;             // 2048*2048
  _Float16* H116 = YN16 + (size_t)NTOK * DI_N;              // 2048*2048
  _Float16* W16 = H116 + (size_t)NTOK * DI_N;               // 4352*1024
  float* X1 = YR;

  k_conv1<<<(B_N * 32 * 32 * 512) / 256, 256, 0, stream>>>(image, conv1_w, bn1, X1);
  k_conv2<<<dim3(8, 4, 8), 256, 0, stream>>>(X1, conv2_w, bn2, image, ds_w, ds_bn, Tok, Tok16);

  for (int i = 0; i < 4; ++i) {
    const float* Wi = in_proj_w + (size_t)i * DPROJ_N * DM_N;
    const float* cw = conv1d_w + (size_t)i * DCONV_N * 4;
    const float* cb = conv1d_b + (size_t)i * DCONV_N;
    const float* dtb = dt_bias + i * NH_N;
    const float* al = A_log + i * NH_N;
    const float* dd = Dpar + i * NH_N;
    const float* nw = norm_w + i * DI_N;
    const float* Wo = out_proj_w + (size_t)i * DM_N * DI_N;
    const float* bbn = blk_bn + (size_t)i * 4 * DM_N;
    const float* w1 = ff_w1 + (size_t)i * FFH_N * DM_N;
    const float* b1 = ff_b1 + i * FFH_N;
    const float* fbn1 = ff_bn1 + (size_t)i * 4 * FFH_N;
    const float* w2 = ff_w2 + (size_t)i * DM_N * FFH_N;
    const float* b2 = ff_b2 + i * DM_N;
    const float* fbn2 = ff_bn2 + (size_t)i * 4 * DM_N;

    // in_proj: [2048,4256] = Tok16[2048,1024] x Wi^T
    k_tohalf8<<<(NPAD_INPROJ * 1024 / 8 + 255) / 256, 256, 0, stream>>>(
        Wi, W16, DPROJ_N * DM_N, NPAD_INPROJ * DM_N);
    k_mgemm<0, 128><<<dim3(34, 16), 256, 0, stream>>>(
        Tok16, W16, NTOK, DPROJ_N, DM_N, nullptr, nullptr, nullptr, ZX, nullptr);
    k_convprep<<<dim3(NTOK, 9), 256, 0, stream>>>(ZX, cw, cb, dtb, al, XBC, DTb, DAb);
    k_scan<<<256, 256, 0, stream>>>(XBC, DTb, DAb, dd, YR);
    k_gatenorm<<<NTOK, 256, 0, stream>>>(YR, ZX, nw, YN16);
    // out_proj: [2048,1024] = YN16[2048,2048] x Wo^T, +bn+res -> Tok/Tok16
    k_tohalf8<<<(DM_N * DI_N / 8 + 255) / 256, 256, 0, stream>>>(
        Wo, W16, DM_N * DI_N, DM_N * DI_N);
    k_mgemm<1, 64><<<dim3(8, 32), 256, 0, stream>>>(
        YN16, W16, NTOK, DM_N, DI_N, nullptr, bbn, Tok, Tok, Tok16);
    // ff1: [2048,2048] = Tok16 x w1^T, +bias+bn+relu -> H116
    k_tohalf8<<<(FFH_N * DM_N / 8 + 255) / 256, 256, 0, stream>>>(
        w1, W16, FFH_N * DM_N, FFH_N * DM_N);
    k_mgemm<2, 128><<<dim3(16, 16), 256, 0, stream>>>(
        Tok16, W16, NTOK, FFH_N, DM_N, b1, fbn1, nullptr, nullptr, H116);
    // ff2: [2048,1024] = H116 x w2^T, +bias+bn+res -> Tok/Tok16
    k_tohalf8<<<(DM_N * FFH_N / 8 + 255) / 256, 256, 0, stream>>>(
        w2, W16, DM_N * FFH_N, DM_N * FFH_N);
    k_mgemm<3, 64><<<dim3(8, 32), 256, 0, stream>>>(
        H116, W16, NTOK, DM_N, FFH_N, b2, fbn2, Tok, Tok, Tok16);
  }
  k_transpose<<<dim3(32, 64), 256, 0, stream>>>(Tok, (float*)d_out);
}

// Round 5
// 1324.724 us; speedup vs baseline: 3.8585x; 1.2087x over previous
//
#include <hip/hip_runtime.h>
#include <hip/hip_bf16.h>
#include <hip/hip_fp16.h>
#include <math.h>

#define EPSF 1e-5f
#define B_N 8
#define L_N 256
#define DM_N 1024
#define DI_N 2048
#define DS_N 64
#define NH_N 32
#define HD_N 64
#define DCONV_N 2176
#define DPROJ_N 4256
#define NTOK 2048
#define FFH_N 2048
#define NPAD_INPROJ 4352  // 4256 padded to multiple of 128

typedef _Float16 f16x8 __attribute__((ext_vector_type(8)));
typedef float f32x4 __attribute__((ext_vector_type(4)));

__device__ __forceinline__ float sigf(float x) { return 1.f / (1.f + __expf(-x)); }

__device__ __forceinline__ void gll16(const void* g, void* l) {
  typedef __attribute__((address_space(1))) const void gv;
  typedef __attribute__((address_space(3))) void lv;
  __builtin_amdgcn_global_load_lds((gv*)g, (lv*)l, 16, 0, 0);
}

// ---------------- fp32 -> fp16 converter (8 elems/thread), zero-pads to ntot ----------------
__global__ __launch_bounds__(256) void k_tohalf8(
    const float* __restrict__ src, _Float16* __restrict__ dst, int n, int ntot) {
  int i = (blockIdx.x * 256 + threadIdx.x) * 8;
  if (i >= ntot) return;
  f16x8 o;
  if (i < n) {
    float4 a = *(const float4*)(src + i);
    float4 b = *(const float4*)(src + i + 4);
    o[0] = (_Float16)a.x; o[1] = (_Float16)a.y; o[2] = (_Float16)a.z; o[3] = (_Float16)a.w;
    o[4] = (_Float16)b.x; o[5] = (_Float16)b.y; o[6] = (_Float16)b.z; o[7] = (_Float16)b.w;
  } else {
#pragma unroll
    for (int j = 0; j < 8; ++j) o[j] = (_Float16)0.f;
  }
  *(f16x8*)(dst + i) = o;
}

// ---- stem conv1 (7x7 s2 p3, 1->32)+bn1 -> channels-last fp16 X1h[b][y][x][ci] ----
// lane&31 = co; 8 pixels per 256-thread block; coalesced 64B writes.
__global__ __launch_bounds__(256) void k_conv1(
    const float* __restrict__ img, const float* __restrict__ w,
    const float* __restrict__ bnp, _Float16* __restrict__ X1h) {
  __shared__ float sW[32 * 49];
  int t = threadIdx.x;
  for (int p = t; p < 32 * 49; p += 256) sW[p] = w[p];
  __syncthreads();
  int co = t & 31;
  int p = blockIdx.x * 8 + (t >> 5);
  int x = p & 511, y = (p >> 9) & 31, b = p >> 14;
  const float* ip = img + (size_t)b * 64 * 1024;
  const float* wp = sW + co * 49;
  float acc = 0.f;
#pragma unroll
  for (int r = 0; r < 7; ++r) {
    int yy = 2 * y + r - 3;
    if (yy < 0 || yy >= 64) continue;
#pragma unroll
    for (int s = 0; s < 7; ++s) {
      int xx = 2 * x + s - 3;
      if (xx < 0 || xx >= 1024) continue;
      acc = fmaf(ip[yy * 1024 + xx], wp[r * 7 + s], acc);
    }
  }
  float g = bnp[co], be = bnp[32 + co], mm = bnp[64 + co], vv = bnp[96 + co];
  float v = (acc - mm) * rsqrtf(vv + EPSF) * g + be;
  X1h[((size_t)(b * 32 + y) * 512 + x) * 32 + co] = (_Float16)v;
}

// ---- w2[co][ci][r][s] -> W2t[rs][co][ci] fp16 ----
__global__ __launch_bounds__(256) void k_w2t(
    const float* __restrict__ w2, _Float16* __restrict__ W2t) {
  int i = blockIdx.x * 256 + threadIdx.x;
  if (i >= 49 * 64 * 32) return;
  int ci = i & 31, co = (i >> 5) & 63, rs = i >> 11;
  W2t[rs * 2048 + co * 32 + ci] = (_Float16)w2[co * 1568 + ci * 49 + rs];
}

// ---- conv2 as MFMA implicit GEMM: M=(b,ho,wo)=32768, N=co=64, K=(rs,ci)=49x32 ----
// grid (8, 16, 2); 512 thr (8 waves, 2/SIMD). Fused bn2 + ds-residual + relu -> Tok/Tok16.
__global__ __launch_bounds__(512) void k_conv2m(
    const _Float16* __restrict__ X1h, const _Float16* __restrict__ W2t,
    const float* __restrict__ bn2p, const float* __restrict__ img,
    const float* __restrict__ dsw, const float* __restrict__ dsbnp,
    float* __restrict__ Tok, _Float16* __restrict__ Tok16) {
  __shared__ _Float16 As[2][128 * 40];  // 80B row stride: 2-way bank alias only
  __shared__ _Float16 Bs[2][64 * 40];
  int b = blockIdx.x, ho = blockIdx.y, wo0 = blockIdx.z * 128;
  int t = threadIdx.x;
  int w = t >> 6, lane = t & 63;
  int lr = lane & 15, kh = lane >> 4;
  int wm = w >> 1, wn = w & 1;
  f32x4 acc[2][2];
#pragma unroll
  for (int i = 0; i < 2; ++i)
#pragma unroll
    for (int j = 0; j < 2; ++j) acc[i][j] = (f32x4)(0.f);

  int arow = t >> 2, achk = t & 3;
  const _Float16* xb = X1h + (size_t)b * 32 * 512 * 32;

  auto LOADA = [&](int rs, f16x8& ra) {
    int r = rs / 7, s = rs - 7 * r;
    int y = 2 * ho + r - 3;
    int xx = 2 * (wo0 + arow) + s - 3;
    if (y >= 0 && y < 32 && xx >= 0 && xx < 512)
      ra = *(const f16x8*)(xb + ((size_t)(y * 512 + xx)) * 32 + achk * 8);
    else
      ra = (f16x8)(_Float16)0.f;
  };

  f16x8 ra, rb;
  LOADA(0, ra);
  if (t < 256) rb = *(const f16x8*)(W2t + (t >> 2) * 32 + (t & 3) * 8);
  *(f16x8*)&As[0][arow * 40 + achk * 8] = ra;
  if (t < 256) *(f16x8*)&Bs[0][(t >> 2) * 40 + (t & 3) * 8] = rb;
  __syncthreads();

  int cur = 0;
  for (int rs = 0; rs < 49; ++rs) {
    f16x8 na, nb;
    if (rs + 1 < 49) {
      LOADA(rs + 1, na);
      if (t < 256)
        nb = *(const f16x8*)(W2t + (rs + 1) * 2048 + (t >> 2) * 32 + (t & 3) * 8);
    }
    f16x8 af[2], bf[2];
#pragma unroll
    for (int i = 0; i < 2; ++i)
      af[i] = *(const f16x8*)&As[cur][(wm * 32 + i * 16 + lr) * 40 + kh * 8];
#pragma unroll
    for (int j = 0; j < 2; ++j)
      bf[j] = *(const f16x8*)&Bs[cur][(wn * 32 + j * 16 + lr) * 40 + kh * 8];
#pragma unroll
    for (int i = 0; i < 2; ++i)
#pragma unroll
      for (int j = 0; j < 2; ++j)
        acc[i][j] = __builtin_amdgcn_mfma_f32_16x16x32_f16(af[i], bf[j], acc[i][j], 0, 0, 0);
    if (rs + 1 < 49) {
      *(f16x8*)&As[cur ^ 1][arow * 40 + achk * 8] = na;
      if (t < 256) *(f16x8*)&Bs[cur ^ 1][(t >> 2) * 40 + (t & 3) * 8] = nb;
      __syncthreads();
      cur ^= 1;
    }
  }

#pragma unroll
  for (int j = 0; j < 2; ++j) {
    int co = wn * 32 + j * 16 + lr;
    float g = bn2p[co], be = bn2p[64 + co], mm = bn2p[128 + co], vv = bn2p[192 + co];
    float sc = rsqrtf(vv + EPSF) * g, sh = be - mm * sc;
    float dg = dsbnp[co], dbe = dsbnp[64 + co], dmm = dsbnp[128 + co], dvv = dsbnp[192 + co];
    float dsc = rsqrtf(dvv + EPSF) * dg, dsh = dbe - dmm * dsc;
    float wv = dsw[co];
#pragma unroll
    for (int i = 0; i < 2; ++i) {
#pragma unroll
      for (int rr = 0; rr < 4; ++rr) {
        int row = wm * 32 + i * 16 + kh * 4 + rr;
        int wo = wo0 + row;
        float dval = fmaf(img[((size_t)(b * 64 + 4 * ho)) * 1024 + 4 * wo] * wv, dsc, dsh);
        float v = fmaf(acc[i][j][rr], sc, sh) + dval;
        v = v > 0.f ? v : 0.f;
        size_t o = ((size_t)(b * 256 + wo)) * DM_N + co * 16 + ho;
        Tok[o] = v;
        Tok16[o] = (_Float16)v;
      }
    }
  }
}

// ---------------- MFMA fp16 GEMM: C[M,N] = A[M,K] * W[N,K]^T + fused epilogue ----------------
// MODE 0: C32 = v.                    (in_proj -> ZX)
// MODE 1: v=bn(v)+res; C32,C16.       (out_proj -> Tok,Tok16)
// MODE 2: v=relu(bn(v+bias)); C16.    (ff1 -> H116)
// MODE 3: v=bn(v+bias)+res; C32,C16.  (ff2 -> Tok,Tok16)
template <int MODE, int BM>
__global__ __launch_bounds__(256) void k_mgemm(
    const _Float16* __restrict__ A, const _Float16* __restrict__ W,
    int M, int N, int K,
    const float* __restrict__ bias, const float* __restrict__ bnp,
    const float* __restrict__ res, float* __restrict__ C32,
    _Float16* __restrict__ C16) {
  constexpr int MI = BM / 32;  // A-frags per wave
  __shared__ _Float16 As[2][BM * 32];
  __shared__ _Float16 Bs[2][128 * 32];
  const int t = threadIdx.x;
  const int w = t >> 6, lane = t & 63;
  const int lr = lane & 15, kh = lane >> 4;
  const int wm = w >> 1, wn = w & 1;
  const int m0 = blockIdx.y * BM, n0 = blockIdx.x * 128;
  f32x4 acc[MI][4];
#pragma unroll
  for (int i = 0; i < MI; ++i)
#pragma unroll
    for (int j = 0; j < 4; ++j) acc[i][j] = (f32x4)(0.f);

  const int nt = K >> 5;
  auto STAGE = [&](int bb, int kt) {
    const int k0 = kt << 5;
#pragma unroll
    for (int it = 0; it < BM / 64; ++it) {  // A: BM*4 chunks of 16B
      int c = it * 256 + w * 64 + lane;
      int row = c >> 2, kq = c & 3;
      gll16(A + (size_t)(m0 + row) * K + k0 + kq * 8,
            &As[bb][(size_t)(it * 256 + w * 64) * 8]);
    }
#pragma unroll
    for (int it = 0; it < 2; ++it) {  // B: 512 chunks
      int c = it * 256 + w * 64 + lane;
      int row = c >> 2, kq = c & 3;
      gll16(W + (size_t)(n0 + row) * K + k0 + kq * 8,
            &Bs[bb][(size_t)(it * 256 + w * 64) * 8]);
    }
  };

  STAGE(0, 0);
  __syncthreads();
  int bb = 0;
  for (int kt = 0; kt < nt; ++kt) {
    if (kt + 1 < nt) STAGE(bb ^ 1, kt + 1);
    f16x8 af[MI], bf[4];
#pragma unroll
    for (int i = 0; i < MI; ++i)
      af[i] = *(const f16x8*)&As[bb][(size_t)((wm * (BM / 2) + i * 16 + lr) * 32 + kh * 8)];
#pragma unroll
    for (int j = 0; j < 4; ++j)
      bf[j] = *(const f16x8*)&Bs[bb][(size_t)((wn * 64 + j * 16 + lr) * 32 + kh * 8)];
#pragma unroll
    for (int i = 0; i < MI; ++i)
#pragma unroll
      for (int j = 0; j < 4; ++j)
        acc[i][j] = __builtin_amdgcn_mfma_f32_16x16x32_f16(af[i], bf[j], acc[i][j], 0, 0, 0);
    __syncthreads();
    bb ^= 1;
  }

#pragma unroll
  for (int j = 0; j < 4; ++j) {
    int cn = n0 + wn * 64 + j * 16 + lr;
    if (cn >= N) continue;
    float g = 1.f, be = 0.f, sc = 1.f, sh = 0.f, bs = 0.f;
    if (MODE >= 1) {
      g = bnp[cn]; be = bnp[N + cn];
      float mm = bnp[2 * N + cn], vv = bnp[3 * N + cn];
      sc = rsqrtf(vv + EPSF) * g;
      sh = be - mm * sc;
    }
    if (MODE == 2 || MODE == 3) bs = bias[cn];
#pragma unroll
    for (int i = 0; i < MI; ++i) {
#pragma unroll
      for (int rr = 0; rr < 4; ++rr) {
        int r = m0 + wm * (BM / 2) + i * 16 + kh * 4 + rr;
        float v = acc[i][j][rr];
        if (MODE == 2 || MODE == 3) v += bs;
        if (MODE >= 1) v = fmaf(v, sc, sh);
        if (MODE == 2) v = v > 0.f ? v : 0.f;
        if (MODE == 1 || MODE == 3) v += res[(size_t)r * N + cn];
        size_t o = (size_t)r * N + cn;
        if (MODE != 2) C32[o] = v;
        if (MODE >= 1) C16[o] = (_Float16)v;
      }
    }
  }
}

// ------- causal depthwise conv1d + silu on xBC; softplus dt; dA -------
__global__ __launch_bounds__(256) void k_convprep(
    const float* __restrict__ ZX, const float* __restrict__ cw,
    const float* __restrict__ cb, const float* __restrict__ dtb,
    const float* __restrict__ Alog, float* __restrict__ XBC,
    float* __restrict__ DT, float* __restrict__ DA) {
  int m = blockIdx.x;
  int c = blockIdx.y * 256 + threadIdx.x;
  int l = m & 255;
  if (c < DCONV_N) {
    const float* cwp = cw + c * 4;
    float acc = cb[c];
#pragma unroll
    for (int k = 0; k < 4; ++k) {
      int dl = l + k - 3;
      if (dl >= 0)
        acc = fmaf(ZX[(size_t)(m + k - 3) * DPROJ_N + DI_N + c], cwp[k], acc);
    }
    XBC[(size_t)m * DCONV_N + c] = acc * sigf(acc);
  } else if (c < DCONV_N + NH_N) {
    int h = c - DCONV_N;
    float xx = ZX[(size_t)m * DPROJ_N + DI_N + DCONV_N + h] + dtb[h];
    float dt = xx > 20.f ? xx : log1pf(__expf(xx));
    DT[m * NH_N + h] = dt;
    DA[m * NH_N + h] = __expf(-dt * __expf(Alog[h]));
  }
}

// ------- selective scan: grid 256 = (b,h); 256 thr; thread owns (p = t>>2, 16 n) -------
__global__ __launch_bounds__(256) void k_scan(
    const float* __restrict__ XBC, const float* __restrict__ DT,
    const float* __restrict__ DA, const float* __restrict__ Dp,
    float* __restrict__ Y) {
  int b = blockIdx.x >> 5, h = blockIdx.x & 31;
  int t = threadIdx.x;
  int p = t >> 2, nq = t & 3, n0 = nq * 16;
  float hs[16];
#pragma unroll
  for (int j = 0; j < 16; ++j) hs[j] = 0.f;
  float Dh = Dp[h];
  for (int l = 0; l < L_N; ++l) {
    int m = b * L_N + l;
    const float* row = XBC + (size_t)m * DCONV_N;
    float xv = row[h * HD_N + p];
    float dt = DT[m * NH_N + h];
    float da = DA[m * NH_N + h];
    float dtx = dt * xv;
    float py = 0.f;
#pragma unroll
    for (int q = 0; q < 4; ++q) {
      float4 Bv = *(const float4*)(row + DI_N + n0 + 4 * q);
      float4 Cv = *(const float4*)(row + DI_N + DS_N + n0 + 4 * q);
      hs[4 * q + 0] = fmaf(hs[4 * q + 0], da, dtx * Bv.x); py = fmaf(hs[4 * q + 0], Cv.x, py);
      hs[4 * q + 1] = fmaf(hs[4 * q + 1], da, dtx * Bv.y); py = fmaf(hs[4 * q + 1], Cv.y, py);
      hs[4 * q + 2] = fmaf(hs[4 * q + 2], da, dtx * Bv.z); py = fmaf(hs[4 * q + 2], Cv.z, py);
      hs[4 * q + 3] = fmaf(hs[4 * q + 3], da, dtx * Bv.w); py = fmaf(hs[4 * q + 3], Cv.w, py);
    }
    py += __shfl_xor(py, 1);
    py += __shfl_xor(py, 2);
    if (nq == 0) Y[(size_t)m * DI_N + h * HD_N + p] = fmaf(Dh, xv, py);
  }
}

// ------- gate with silu(z) + RMSNorm (over DI) -> fp16 -------
__global__ __launch_bounds__(256) void k_gatenorm(
    const float* __restrict__ Y, const float* __restrict__ ZX,
    const float* __restrict__ nw, _Float16* __restrict__ YN16) {
  int m = blockIdx.x, t = threadIdx.x;
  const float* y = Y + (size_t)m * DI_N;
  const float* z = ZX + (size_t)m * DPROJ_N;
  float vals[8];
  float ss = 0.f;
#pragma unroll
  for (int j = 0; j < 8; ++j) {
    int c = t + 256 * j;
    float zz = z[c];
    float vv = y[c] * zz * sigf(zz);
    vals[j] = vv;
    ss = fmaf(vv, vv, ss);
  }
#pragma unroll
  for (int o = 1; o < 64; o <<= 1) ss += __shfl_xor(ss, o);
  __shared__ float sred[4];
  if ((t & 63) == 0) sred[t >> 6] = ss;
  __syncthreads();
  float tot = sred[0] + sred[1] + sred[2] + sred[3];
  float scale = rsqrtf(tot * (1.f / DI_N) + EPSF);
#pragma unroll
  for (int j = 0; j < 8; ++j) {
    int c = t + 256 * j;
    YN16[(size_t)m * DI_N + c] = (_Float16)(vals[j] * scale * nw[c]);
  }
}

// ------- final transpose: Tok[m][d] -> out[b][d][l] -------
__global__ __launch_bounds__(256) void k_transpose(
    const float* __restrict__ Tok, float* __restrict__ out) {
  __shared__ float tile[32][33];
  int d0 = blockIdx.x * 32, m0 = blockIdx.y * 32;
  int tx = threadIdx.x & 31, ty = threadIdx.x >> 5;
  for (int i = ty; i < 32; i += 8)
    tile[i][tx] = Tok[(size_t)(m0 + i) * DM_N + d0 + tx];
  __syncthreads();
  int b = m0 >> 8, l0 = m0 & 255;
  for (int i = ty; i < 32; i += 8)
    out[((size_t)b * DM_N + d0 + i) * L_N + l0 + tx] = tile[tx][i];
}

extern "C" void kernel_launch(void* const* d_in, const int* in_sizes, int n_in,
                              void* d_out, int out_size, void* d_ws, size_t ws_size,
                              hipStream_t stream) {
  const float* image = (const float*)d_in[0];
  const float* conv1_w = (const float*)d_in[1];
  const float* bn1 = (const float*)d_in[2];
  const float* conv2_w = (const float*)d_in[3];
  const float* bn2 = (const float*)d_in[4];
  const float* ds_w = (const float*)d_in[5];
  const float* ds_bn = (const float*)d_in[6];
  const float* in_proj_w = (const float*)d_in[7];
  const float* conv1d_w = (const float*)d_in[8];
  const float* conv1d_b = (const float*)d_in[9];
  const float* dt_bias = (const float*)d_in[10];
  const float* A_log = (const float*)d_in[11];
  const float* Dpar = (const float*)d_in[12];
  const float* norm_w = (const float*)d_in[13];
  const float* out_proj_w = (const float*)d_in[14];
  const float* blk_bn = (const float*)d_in[15];
  const float* ff_w1 = (const float*)d_in[16];
  const float* ff_b1 = (const float*)d_in[17];
  const float* ff_bn1 = (const float*)d_in[18];
  const float* ff_w2 = (const float*)d_in[19];
  const float* ff_b2 = (const float*)d_in[20];
  const float* ff_bn2 = (const float*)d_in[21];

  // workspace layout: fp32 region then fp16 region (~108 MB total)
  float* ws = (float*)d_ws;
  float* Tok = ws;                        // 2048*1024
  float* ZX = Tok + (size_t)NTOK * DM_N;  // 2048*4256
  float* XBC = ZX + (size_t)NTOK * DPROJ_N;
  float* DTb = XBC + (size_t)NTOK * DCONV_N;
  float* DAb = DTb + (size_t)NTOK * NH_N;
  float* YR = DAb + (size_t)NTOK * NH_N;  // 2048*2048; stem X1h aliases this (16.8MB)
  _Float16* Tok16 = (_Float16*)(YR + (size_t)NTOK * DI_N);  // 2048*1024
  _Float16* YN16 = Tok16 + (size_t)NTOK * DM_N;             // 2048*2048
  _Float16* H116 = YN16 + (size_t)NTOK * DI_N;              // 2048*2048
  _Float16* W16 = H116 + (size_t)NTOK * DI_N;               // 4352*1024
  _Float16* W2t = W16 + (size_t)NPAD_INPROJ * DM_N;         // 49*64*32
  _Float16* X1h = (_Float16*)YR;

  k_conv1<<<16384, 256, 0, stream>>>(image, conv1_w, bn1, X1h);
  k_w2t<<<(49 * 64 * 32 + 255) / 256, 256, 0, stream>>>(conv2_w, W2t);
  k_conv2m<<<dim3(8, 16, 2), 512, 0, stream>>>(X1h, W2t, bn2, image, ds_w, ds_bn, Tok, Tok16);

  for (int i = 0; i < 4; ++i) {
    const float* Wi = in_proj_w + (size_t)i * DPROJ_N * DM_N;
    const float* cw = conv1d_w + (size_t)i * DCONV_N * 4;
    const float* cb = conv1d_b + (size_t)i * DCONV_N;
    const float* dtb = dt_bias + i * NH_N;
    const float* al = A_log + i * NH_N;
    const float* dd = Dpar + i * NH_N;
    const float* nw = norm_w + i * DI_N;
    const float* Wo = out_proj_w + (size_t)i * DM_N * DI_N;
    const float* bbn = blk_bn + (size_t)i * 4 * DM_N;
    const float* w1 = ff_w1 + (size_t)i * FFH_N * DM_N;
    const float* b1 = ff_b1 + i * FFH_N;
    const float* fbn1 = ff_bn1 + (size_t)i * 4 * FFH_N;
    const float* w2 = ff_w2 + (size_t)i * DM_N * FFH_N;
    const float* b2 = ff_b2 + i * DM_N;
    const float* fbn2 = ff_bn2 + (size_t)i * 4 * DM_N;

    // in_proj: [2048,4256] = Tok16[2048,1024] x Wi^T
    k_tohalf8<<<(NPAD_INPROJ * 1024 / 8 + 255) / 256, 256, 0, stream>>>(
        Wi, W16, DPROJ_N * DM_N, NPAD_INPROJ * DM_N);
    k_mgemm<0, 128><<<dim3(34, 16), 256, 0, stream>>>(
        Tok16, W16, NTOK, DPROJ_N, DM_N, nullptr, nullptr, nullptr, ZX, nullptr);
    k_convprep<<<dim3(NTOK, 9), 256, 0, stream>>>(ZX, cw, cb, dtb, al, XBC, DTb, DAb);
    k_scan<<<256, 256, 0, stream>>>(XBC, DTb, DAb, dd, YR);
    k_gatenorm<<<NTOK, 256, 0, stream>>>(YR, ZX, nw, YN16);
    // out_proj: [2048,1024] = YN16[2048,2048] x Wo^T, +bn+res -> Tok/Tok16
    k_tohalf8<<<(DM_N * DI_N / 8 + 255) / 256, 256, 0, stream>>>(
        Wo, W16, DM_N * DI_N, DM_N * DI_N);
    k_mgemm<1, 64><<<dim3(8, 32), 256, 0, stream>>>(
        YN16, W16, NTOK, DM_N, DI_N, nullptr, bbn, Tok, Tok, Tok16);
    // ff1: [2048,2048] = Tok16 x w1^T, +bias+bn+relu -> H116
    k_tohalf8<<<(FFH_N * DM_N / 8 + 255) / 256, 256, 0, stream>>>(
        w1, W16, FFH_N * DM_N, FFH_N * DM_N);
    k_mgemm<2, 128><<<dim3(16, 16), 256, 0, stream>>>(
        Tok16, W16, NTOK, FFH_N, DM_N, b1, fbn1, nullptr, nullptr, H116);
    // ff2: [2048,1024] = H116 x w2^T, +bias+bn+res -> Tok/Tok16
    k_tohalf8<<<(DM_N * FFH_N / 8 + 255) / 256, 256, 0, stream>>>(
        w2, W16, DM_N * FFH_N, DM_N * FFH_N);
    k_mgemm<3, 64><<<dim3(8, 32), 256, 0, stream>>>(
        H116, W16, NTOK, DM_N, FFH_N, b2, fbn2, Tok, Tok, Tok16);
  }
  k_transpose<<<dim3(32, 64), 256, 0, stream>>>(Tok, (float*)d_out);
}

// Round 6
// 1053.975 us; speedup vs baseline: 4.8496x; 1.2569x over previous
//
#include <hip/hip_runtime.h>
#include <hip/hip_bf16.h>
#include <hip/hip_fp16.h>
#include <math.h>

#define EPSF 1e-5f
#define B_N 8
#define L_N 256
#define DM_N 1024
#define DI_N 2048
#define DS_N 64
#define NH_N 32
#define HD_N 64
#define DCONV_N 2176
#define DPROJ_N 4256
#define NTOK 2048
#define FFH_N 2048
#define NPAD_INPROJ 4352  // 4256 padded to multiple of 128

typedef _Float16 f16x8 __attribute__((ext_vector_type(8)));
typedef float f32x4 __attribute__((ext_vector_type(4)));

__device__ __forceinline__ float sigf(float x) { return 1.f / (1.f + __expf(-x)); }

__device__ __forceinline__ void gll16(const void* g, void* l) {
  typedef __attribute__((address_space(1))) const void gv;
  typedef __attribute__((address_space(3))) void lv;
  __builtin_amdgcn_global_load_lds((gv*)g, (lv*)l, 16, 0, 0);
}

// ---------------- fp32 -> fp16 converter (8 elems/thread), zero-pads to ntot ----------------
__global__ __launch_bounds__(256) void k_tohalf8(
    const float* __restrict__ src, _Float16* __restrict__ dst, int n, int ntot) {
  int i = (blockIdx.x * 256 + threadIdx.x) * 8;
  if (i >= ntot) return;
  f16x8 o;
  if (i < n) {
    float4 a = *(const float4*)(src + i);
    float4 b = *(const float4*)(src + i + 4);
    o[0] = (_Float16)a.x; o[1] = (_Float16)a.y; o[2] = (_Float16)a.z; o[3] = (_Float16)a.w;
    o[4] = (_Float16)b.x; o[5] = (_Float16)b.y; o[6] = (_Float16)b.z; o[7] = (_Float16)b.w;
  } else {
#pragma unroll
    for (int j = 0; j < 8; ++j) o[j] = (_Float16)0.f;
  }
  *(f16x8*)(dst + i) = o;
}

// ---- stem conv1 (7x7 s2 p3, 1->32)+bn1 -> channels-last fp16 X1h[b][y][x][ci] ----
__global__ __launch_bounds__(256) void k_conv1(
    const float* __restrict__ img, const float* __restrict__ w,
    const float* __restrict__ bnp, _Float16* __restrict__ X1h) {
  __shared__ float sW[32 * 49];
  int t = threadIdx.x;
  for (int p = t; p < 32 * 49; p += 256) sW[p] = w[p];
  __syncthreads();
  int co = t & 31;
  int p = blockIdx.x * 8 + (t >> 5);
  int x = p & 511, y = (p >> 9) & 31, b = p >> 14;
  const float* ip = img + (size_t)b * 64 * 1024;
  const float* wp = sW + co * 49;
  float acc = 0.f;
#pragma unroll
  for (int r = 0; r < 7; ++r) {
    int yy = 2 * y + r - 3;
    if (yy < 0 || yy >= 64) continue;
#pragma unroll
    for (int s = 0; s < 7; ++s) {
      int xx = 2 * x + s - 3;
      if (xx < 0 || xx >= 1024) continue;
      acc = fmaf(ip[yy * 1024 + xx], wp[r * 7 + s], acc);
    }
  }
  float g = bnp[co], be = bnp[32 + co], mm = bnp[64 + co], vv = bnp[96 + co];
  float v = (acc - mm) * rsqrtf(vv + EPSF) * g + be;
  X1h[((size_t)(b * 32 + y) * 512 + x) * 32 + co] = (_Float16)v;
}

// ---- w2[co][ci][r][s] -> W2t[rs][co][ci] fp16 ----
__global__ __launch_bounds__(256) void k_w2t(
    const float* __restrict__ w2, _Float16* __restrict__ W2t) {
  int i = blockIdx.x * 256 + threadIdx.x;
  if (i >= 49 * 64 * 32) return;
  int ci = i & 31, co = (i >> 5) & 63, rs = i >> 11;
  W2t[rs * 2048 + co * 32 + ci] = (_Float16)w2[co * 1568 + ci * 49 + rs];
}

// ---- conv2 as MFMA implicit GEMM: M=(b,ho,wo)=32768, N=co=64, K=(rs,ci)=49x32 ----
__global__ __launch_bounds__(512) void k_conv2m(
    const _Float16* __restrict__ X1h, const _Float16* __restrict__ W2t,
    const float* __restrict__ bn2p, const float* __restrict__ img,
    const float* __restrict__ dsw, const float* __restrict__ dsbnp,
    float* __restrict__ Tok, _Float16* __restrict__ Tok16) {
  __shared__ _Float16 As[2][128 * 40];  // 80B row stride: 2-way bank alias only
  __shared__ _Float16 Bs[2][64 * 40];
  int b = blockIdx.x, ho = blockIdx.y, wo0 = blockIdx.z * 128;
  int t = threadIdx.x;
  int w = t >> 6, lane = t & 63;
  int lr = lane & 15, kh = lane >> 4;
  int wm = w >> 1, wn = w & 1;
  f32x4 acc[2][2];
#pragma unroll
  for (int i = 0; i < 2; ++i)
#pragma unroll
    for (int j = 0; j < 2; ++j) acc[i][j] = (f32x4)(0.f);

  int arow = t >> 2, achk = t & 3;
  const _Float16* xb = X1h + (size_t)b * 32 * 512 * 32;

  auto LOADA = [&](int rs, f16x8& ra) {
    int r = rs / 7, s = rs - 7 * r;
    int y = 2 * ho + r - 3;
    int xx = 2 * (wo0 + arow) + s - 3;
    if (y >= 0 && y < 32 && xx >= 0 && xx < 512)
      ra = *(const f16x8*)(xb + ((size_t)(y * 512 + xx)) * 32 + achk * 8);
    else
      ra = (f16x8)(_Float16)0.f;
  };

  f16x8 ra, rb;
  LOADA(0, ra);
  if (t < 256) rb = *(const f16x8*)(W2t + (t >> 2) * 32 + (t & 3) * 8);
  *(f16x8*)&As[0][arow * 40 + achk * 8] = ra;
  if (t < 256) *(f16x8*)&Bs[0][(t >> 2) * 40 + (t & 3) * 8] = rb;
  __syncthreads();

  int cur = 0;
  for (int rs = 0; rs < 49; ++rs) {
    f16x8 na, nb;
    if (rs + 1 < 49) {
      LOADA(rs + 1, na);
      if (t < 256)
        nb = *(const f16x8*)(W2t + (rs + 1) * 2048 + (t >> 2) * 32 + (t & 3) * 8);
    }
    f16x8 af[2], bf[2];
#pragma unroll
    for (int i = 0; i < 2; ++i)
      af[i] = *(const f16x8*)&As[cur][(wm * 32 + i * 16 + lr) * 40 + kh * 8];
#pragma unroll
    for (int j = 0; j < 2; ++j)
      bf[j] = *(const f16x8*)&Bs[cur][(wn * 32 + j * 16 + lr) * 40 + kh * 8];
#pragma unroll
    for (int i = 0; i < 2; ++i)
#pragma unroll
      for (int j = 0; j < 2; ++j)
        acc[i][j] = __builtin_amdgcn_mfma_f32_16x16x32_f16(af[i], bf[j], acc[i][j], 0, 0, 0);
    if (rs + 1 < 49) {
      *(f16x8*)&As[cur ^ 1][arow * 40 + achk * 8] = na;
      if (t < 256) *(f16x8*)&Bs[cur ^ 1][(t >> 2) * 40 + (t & 3) * 8] = nb;
      __syncthreads();
      cur ^= 1;
    }
  }

#pragma unroll
  for (int j = 0; j < 2; ++j) {
    int co = wn * 32 + j * 16 + lr;
    float g = bn2p[co], be = bn2p[64 + co], mm = bn2p[128 + co], vv = bn2p[192 + co];
    float sc = rsqrtf(vv + EPSF) * g, sh = be - mm * sc;
    float dg = dsbnp[co], dbe = dsbnp[64 + co], dmm = dsbnp[128 + co], dvv = dsbnp[192 + co];
    float dsc = rsqrtf(dvv + EPSF) * dg, dsh = dbe - dmm * dsc;
    float wv = dsw[co];
#pragma unroll
    for (int i = 0; i < 2; ++i) {
#pragma unroll
      for (int rr = 0; rr < 4; ++rr) {
        int row = wm * 32 + i * 16 + kh * 4 + rr;
        int wo = wo0 + row;
        float dval = fmaf(img[((size_t)(b * 64 + 4 * ho)) * 1024 + 4 * wo] * wv, dsc, dsh);
        float v = fmaf(acc[i][j][rr], sc, sh) + dval;
        v = v > 0.f ? v : 0.f;
        size_t o = ((size_t)(b * 256 + wo)) * DM_N + co * 16 + ho;
        Tok[o] = v;
        Tok16[o] = (_Float16)v;
      }
    }
  }
}

// ---------------- MFMA fp16 GEMM: C[M,N] = A[M,K] * W[N,K]^T + fused epilogue ----------------
template <int MODE, int BM>
__global__ __launch_bounds__(256) void k_mgemm(
    const _Float16* __restrict__ A, const _Float16* __restrict__ W,
    int M, int N, int K,
    const float* __restrict__ bias, const float* __restrict__ bnp,
    const float* __restrict__ res, float* __restrict__ C32,
    _Float16* __restrict__ C16) {
  constexpr int MI = BM / 32;  // A-frags per wave
  __shared__ _Float16 As[2][BM * 32];
  __shared__ _Float16 Bs[2][128 * 32];
  const int t = threadIdx.x;
  const int w = t >> 6, lane = t & 63;
  const int lr = lane & 15, kh = lane >> 4;
  const int wm = w >> 1, wn = w & 1;
  const int m0 = blockIdx.y * BM, n0 = blockIdx.x * 128;
  f32x4 acc[MI][4];
#pragma unroll
  for (int i = 0; i < MI; ++i)
#pragma unroll
    for (int j = 0; j < 4; ++j) acc[i][j] = (f32x4)(0.f);

  const int nt = K >> 5;
  auto STAGE = [&](int bb, int kt) {
    const int k0 = kt << 5;
#pragma unroll
    for (int it = 0; it < BM / 64; ++it) {
      int c = it * 256 + w * 64 + lane;
      int row = c >> 2, kq = c & 3;
      gll16(A + (size_t)(m0 + row) * K + k0 + kq * 8,
            &As[bb][(size_t)(it * 256 + w * 64) * 8]);
    }
#pragma unroll
    for (int it = 0; it < 2; ++it) {
      int c = it * 256 + w * 64 + lane;
      int row = c >> 2, kq = c & 3;
      gll16(W + (size_t)(n0 + row) * K + k0 + kq * 8,
            &Bs[bb][(size_t)(it * 256 + w * 64) * 8]);
    }
  };

  STAGE(0, 0);
  __syncthreads();
  int bb = 0;
  for (int kt = 0; kt < nt; ++kt) {
    if (kt + 1 < nt) STAGE(bb ^ 1, kt + 1);
    f16x8 af[MI], bf[4];
#pragma unroll
    for (int i = 0; i < MI; ++i)
      af[i] = *(const f16x8*)&As[bb][(size_t)((wm * (BM / 2) + i * 16 + lr) * 32 + kh * 8)];
#pragma unroll
    for (int j = 0; j < 4; ++j)
      bf[j] = *(const f16x8*)&Bs[bb][(size_t)((wn * 64 + j * 16 + lr) * 32 + kh * 8)];
#pragma unroll
    for (int i = 0; i < MI; ++i)
#pragma unroll
      for (int j = 0; j < 4; ++j)
        acc[i][j] = __builtin_amdgcn_mfma_f32_16x16x32_f16(af[i], bf[j], acc[i][j], 0, 0, 0);
    __syncthreads();
    bb ^= 1;
  }

#pragma unroll
  for (int j = 0; j < 4; ++j) {
    int cn = n0 + wn * 64 + j * 16 + lr;
    if (cn >= N) continue;
    float g = 1.f, be = 0.f, sc = 1.f, sh = 0.f, bs = 0.f;
    if (MODE >= 1) {
      g = bnp[cn]; be = bnp[N + cn];
      float mm = bnp[2 * N + cn], vv = bnp[3 * N + cn];
      sc = rsqrtf(vv + EPSF) * g;
      sh = be - mm * sc;
    }
    if (MODE == 2 || MODE == 3) bs = bias[cn];
#pragma unroll
    for (int i = 0; i < MI; ++i) {
#pragma unroll
      for (int rr = 0; rr < 4; ++rr) {
        int r = m0 + wm * (BM / 2) + i * 16 + kh * 4 + rr;
        float v = acc[i][j][rr];
        if (MODE == 2 || MODE == 3) v += bs;
        if (MODE >= 1) v = fmaf(v, sc, sh);
        if (MODE == 2) v = v > 0.f ? v : 0.f;
        if (MODE == 1 || MODE == 3) v += res[(size_t)r * N + cn];
        size_t o = (size_t)r * N + cn;
        if (MODE != 2) C32[o] = v;
        if (MODE >= 1) C16[o] = (_Float16)v;
      }
    }
  }
}

// ------- causal depthwise conv1d + silu on xBC; softplus dt; dA -------
__global__ __launch_bounds__(256) void k_convprep(
    const float* __restrict__ ZX, const float* __restrict__ cw,
    const float* __restrict__ cb, const float* __restrict__ dtb,
    const float* __restrict__ Alog, float* __restrict__ XBC,
    float* __restrict__ DT, float* __restrict__ DA) {
  int m = blockIdx.x;
  int c = blockIdx.y * 256 + threadIdx.x;
  int l = m & 255;
  if (c < DCONV_N) {
    const float* cwp = cw + c * 4;
    float acc = cb[c];
#pragma unroll
    for (int k = 0; k < 4; ++k) {
      int dl = l + k - 3;
      if (dl >= 0)
        acc = fmaf(ZX[(size_t)(m + k - 3) * DPROJ_N + DI_N + c], cwp[k], acc);
    }
    XBC[(size_t)m * DCONV_N + c] = acc * sigf(acc);
  } else if (c < DCONV_N + NH_N) {
    int h = c - DCONV_N;
    float xx = ZX[(size_t)m * DPROJ_N + DI_N + DCONV_N + h] + dtb[h];
    float dt = xx > 20.f ? xx : log1pf(__expf(xx));
    DT[m * NH_N + h] = dt;
    DA[m * NH_N + h] = __expf(-dt * __expf(Alog[h]));
  }
}

// ------- selective scan v2: grid 256=(b,h), 512 thr (8 waves); thread owns (p=t>>3, 8 n) -------
// B/C/x tiles (16 timesteps) double-buffered in LDS; dt/dA preloaded per block.
__global__ __launch_bounds__(512) void k_scan(
    const float* __restrict__ XBC, const float* __restrict__ DT,
    const float* __restrict__ DA, const float* __restrict__ Dp,
    float* __restrict__ Y) {
  __shared__ float sBC[2][16][128];  // [l][0:64)=B, [64:128)=C
  __shared__ float sX[2][16][64];
  __shared__ float sDT[256], sDA[256];
  int b = blockIdx.x >> 5, h = blockIdx.x & 31;
  int t = threadIdx.x;
  int p = t >> 3, nq = t & 7, n0 = nq * 8;

  for (int i = t; i < 256; i += 512) {
    int m = b * L_N + i;
    sDT[i] = DT[m * NH_N + h];
    sDA[i] = DA[m * NH_N + h];
  }

  const int bcrow = t >> 5, bcoff = (t & 31) * 4;   // 512 thr cover 16x128
  const int xrow = t >> 4, xoff = (t & 15) * 4;     // 256 thr cover 16x64
  auto LOADT = [&](int tile, float4& rbc, float4& rx) {
    int m0 = b * L_N + tile * 16;
    rbc = *(const float4*)&XBC[(size_t)(m0 + bcrow) * DCONV_N + DI_N + bcoff];
    if (t < 256)
      rx = *(const float4*)&XBC[(size_t)(m0 + xrow) * DCONV_N + h * HD_N + xoff];
  };

  float4 rbc, rx;
  LOADT(0, rbc, rx);
  *(float4*)&sBC[0][bcrow][bcoff] = rbc;
  if (t < 256) *(float4*)&sX[0][xrow][xoff] = rx;
  __syncthreads();

  float hs[8];
#pragma unroll
  for (int j = 0; j < 8; ++j) hs[j] = 0.f;
  float Dh = Dp[h];
  float* yb = Y + ((size_t)b * L_N) * DI_N + h * HD_N + p;

  int cur = 0;
  for (int tile = 0; tile < 16; ++tile) {
    if (tile + 1 < 16) LOADT(tile + 1, rbc, rx);
#pragma unroll
    for (int l = 0; l < 16; ++l) {
      int ll = tile * 16 + l;
      float da = sDA[ll];
      float xv = sX[cur][l][p];
      float dtx = sDT[ll] * xv;
      float4 B0 = *(const float4*)&sBC[cur][l][n0];
      float4 B1 = *(const float4*)&sBC[cur][l][n0 + 4];
      float4 C0 = *(const float4*)&sBC[cur][l][64 + n0];
      float4 C1 = *(const float4*)&sBC[cur][l][64 + n0 + 4];
      float py = 0.f;
      hs[0] = fmaf(hs[0], da, dtx * B0.x); py = fmaf(hs[0], C0.x, py);
      hs[1] = fmaf(hs[1], da, dtx * B0.y); py = fmaf(hs[1], C0.y, py);
      hs[2] = fmaf(hs[2], da, dtx * B0.z); py = fmaf(hs[2], C0.z, py);
      hs[3] = fmaf(hs[3], da, dtx * B0.w); py = fmaf(hs[3], C0.w, py);
      hs[4] = fmaf(hs[4], da, dtx * B1.x); py = fmaf(hs[4], C1.x, py);
      hs[5] = fmaf(hs[5], da, dtx * B1.y); py = fmaf(hs[5], C1.y, py);
      hs[6] = fmaf(hs[6], da, dtx * B1.z); py = fmaf(hs[6], C1.z, py);
      hs[7] = fmaf(hs[7], da, dtx * B1.w); py = fmaf(hs[7], C1.w, py);
      py += __shfl_xor(py, 1);
      py += __shfl_xor(py, 2);
      py += __shfl_xor(py, 4);
      if (nq == 0) yb[(size_t)ll * DI_N] = fmaf(Dh, xv, py);
    }
    if (tile + 1 < 16) {
      *(float4*)&sBC[cur ^ 1][bcrow][bcoff] = rbc;
      if (t < 256) *(float4*)&sX[cur ^ 1][xrow][xoff] = rx;
      __syncthreads();
      cur ^= 1;
    }
  }
}

// ------- gate with silu(z) + RMSNorm (over DI) -> fp16 -------
__global__ __launch_bounds__(256) void k_gatenorm(
    const float* __restrict__ Y, const float* __restrict__ ZX,
    const float* __restrict__ nw, _Float16* __restrict__ YN16) {
  int m = blockIdx.x, t = threadIdx.x;
  const float* y = Y + (size_t)m * DI_N;
  const float* z = ZX + (size_t)m * DPROJ_N;
  float vals[8];
  float ss = 0.f;
#pragma unroll
  for (int j = 0; j < 8; ++j) {
    int c = t + 256 * j;
    float zz = z[c];
    float vv = y[c] * zz * sigf(zz);
    vals[j] = vv;
    ss = fmaf(vv, vv, ss);
  }
#pragma unroll
  for (int o = 1; o < 64; o <<= 1) ss += __shfl_xor(ss, o);
  __shared__ float sred[4];
  if ((t & 63) == 0) sred[t >> 6] = ss;
  __syncthreads();
  float tot = sred[0] + sred[1] + sred[2] + sred[3];
  float scale = rsqrtf(tot * (1.f / DI_N) + EPSF);
#pragma unroll
  for (int j = 0; j < 8; ++j) {
    int c = t + 256 * j;
    YN16[(size_t)m * DI_N + c] = (_Float16)(vals[j] * scale * nw[c]);
  }
}

// ------- final transpose: Tok[m][d] -> out[b][d][l] -------
__global__ __launch_bounds__(256) void k_transpose(
    const float* __restrict__ Tok, float* __restrict__ out) {
  __shared__ float tile[32][33];
  int d0 = blockIdx.x * 32, m0 = blockIdx.y * 32;
  int tx = threadIdx.x & 31, ty = threadIdx.x >> 5;
  for (int i = ty; i < 32; i += 8)
    tile[i][tx] = Tok[(size_t)(m0 + i) * DM_N + d0 + tx];
  __syncthreads();
  int b = m0 >> 8, l0 = m0 & 255;
  for (int i = ty; i < 32; i += 8)
    out[((size_t)b * DM_N + d0 + i) * L_N + l0 + tx] = tile[tx][i];
}

extern "C" void kernel_launch(void* const* d_in, const int* in_sizes, int n_in,
                              void* d_out, int out_size, void* d_ws, size_t ws_size,
                              hipStream_t stream) {
  const float* image = (const float*)d_in[0];
  const float* conv1_w = (const float*)d_in[1];
  const float* bn1 = (const float*)d_in[2];
  const float* conv2_w = (const float*)d_in[3];
  const float* bn2 = (const float*)d_in[4];
  const float* ds_w = (const float*)d_in[5];
  const float* ds_bn = (const float*)d_in[6];
  const float* in_proj_w = (const float*)d_in[7];
  const float* conv1d_w = (const float*)d_in[8];
  const float* conv1d_b = (const float*)d_in[9];
  const float* dt_bias = (const float*)d_in[10];
  const float* A_log = (const float*)d_in[11];
  const float* Dpar = (const float*)d_in[12];
  const float* norm_w = (const float*)d_in[13];
  const float* out_proj_w = (const float*)d_in[14];
  const float* blk_bn = (const float*)d_in[15];
  const float* ff_w1 = (const float*)d_in[16];
  const float* ff_b1 = (const float*)d_in[17];
  const float* ff_bn1 = (const float*)d_in[18];
  const float* ff_w2 = (const float*)d_in[19];
  const float* ff_b2 = (const float*)d_in[20];
  const float* ff_bn2 = (const float*)d_in[21];

  // workspace layout: fp32 region then fp16 region (~108 MB total)
  float* ws = (float*)d_ws;
  float* Tok = ws;                        // 2048*1024
  float* ZX = Tok + (size_t)NTOK * DM_N;  // 2048*4256
  float* XBC = ZX + (size_t)NTOK * DPROJ_N;
  float* DTb = XBC + (size_t)NTOK * DCONV_N;
  float* DAb = DTb + (size_t)NTOK * NH_N;
  float* YR = DAb + (size_t)NTOK * NH_N;  // 2048*2048; stem X1h aliases this
  _Float16* Tok16 = (_Float16*)(YR + (size_t)NTOK * DI_N);  // 2048*1024
  _Float16* YN16 = Tok16 + (size_t)NTOK * DM_N;             // 2048*2048
  _Float16* H116 = YN16 + (size_t)NTOK * DI_N;              // 2048*2048
  _Float16* W16 = H116 + (size_t)NTOK * DI_N;               // 4352*1024
  _Float16* W2t = W16 + (size_t)NPAD_INPROJ * DM_N;         // 49*64*32
  _Float16* X1h = (_Float16*)YR;

  k_conv1<<<16384, 256, 0, stream>>>(image, conv1_w, bn1, X1h);
  k_w2t<<<(49 * 64 * 32 + 255) / 256, 256, 0, stream>>>(conv2_w, W2t);
  k_conv2m<<<dim3(8, 16, 2), 512, 0, stream>>>(X1h, W2t, bn2, image, ds_w, ds_bn, Tok, Tok16);

  for (int i = 0; i < 4; ++i) {
    const float* Wi = in_proj_w + (size_t)i * DPROJ_N * DM_N;
    const float* cw = conv1d_w + (size_t)i * DCONV_N * 4;
    const float* cb = conv1d_b + (size_t)i * DCONV_N;
    const float* dtb = dt_bias + i * NH_N;
    const float* al = A_log + i * NH_N;
    const float* dd = Dpar + i * NH_N;
    const float* nw = norm_w + i * DI_N;
    const float* Wo = out_proj_w + (size_t)i * DM_N * DI_N;
    const float* bbn = blk_bn + (size_t)i * 4 * DM_N;
    const float* w1 = ff_w1 + (size_t)i * FFH_N * DM_N;
    const float* b1 = ff_b1 + i * FFH_N;
    const float* fbn1 = ff_bn1 + (size_t)i * 4 * FFH_N;
    const float* w2 = ff_w2 + (size_t)i * DM_N * FFH_N;
    const float* b2 = ff_b2 + i * DM_N;
    const float* fbn2 = ff_bn2 + (size_t)i * 4 * DM_N;

    // in_proj: [2048,4256] = Tok16[2048,1024] x Wi^T
    k_tohalf8<<<(NPAD_INPROJ * 1024 / 8 + 255) / 256, 256, 0, stream>>>(
        Wi, W16, DPROJ_N * DM_N, NPAD_INPROJ * DM_N);
    k_mgemm<0, 128><<<dim3(34, 16), 256, 0, stream>>>(
        Tok16, W16, NTOK, DPROJ_N, DM_N, nullptr, nullptr, nullptr, ZX, nullptr);
    k_convprep<<<dim3(NTOK, 9), 256, 0, stream>>>(ZX, cw, cb, dtb, al, XBC, DTb, DAb);
    k_scan<<<256, 512, 0, stream>>>(XBC, DTb, DAb, dd, YR);
    k_gatenorm<<<NTOK, 256, 0, stream>>>(YR, ZX, nw, YN16);
    // out_proj: [2048,1024] = YN16[2048,2048] x Wo^T, +bn+res -> Tok/Tok16
    k_tohalf8<<<(DM_N * DI_N / 8 + 255) / 256, 256, 0, stream>>>(
        Wo, W16, DM_N * DI_N, DM_N * DI_N);
    k_mgemm<1, 64><<<dim3(8, 32), 256, 0, stream>>>(
        YN16, W16, NTOK, DM_N, DI_N, nullptr, bbn, Tok, Tok, Tok16);
    // ff1: [2048,2048] = Tok16 x w1^T, +bias+bn+relu -> H116
    k_tohalf8<<<(FFH_N * DM_N / 8 + 255) / 256, 256, 0, stream>>>(
        w1, W16, FFH_N * DM_N, FFH_N * DM_N);
    k_mgemm<2, 128><<<dim3(16, 16), 256, 0, stream>>>(
        Tok16, W16, NTOK, FFH_N, DM_N, b1, fbn1, nullptr, nullptr, H116);
    // ff2: [2048,1024] = H116 x w2^T, +bias+bn+res -> Tok/Tok16
    k_tohalf8<<<(DM_N * FFH_N / 8 + 255) / 256, 256, 0, stream>>>(
        w2, W16, DM_N * FFH_N, DM_N * FFH_N);
    k_mgemm<3, 64><<<dim3(8, 32), 256, 0, stream>>>(
        H116, W16, NTOK, DM_N, FFH_N, b2, fbn2, Tok, Tok, Tok16);
  }
  k_transpose<<<dim3(32, 64), 256, 0, stream>>>(Tok, (float*)d_out);
}

// Round 7
// 1012.935 us; speedup vs baseline: 5.0461x; 1.0405x over previous
//
#include <hip/hip_runtime.h>
#include <hip/hip_bf16.h>
#include <hip/hip_fp16.h>
#include <math.h>

#define EPSF 1e-5f
#define B_N 8
#define L_N 256
#define DM_N 1024
#define DI_N 2048
#define DS_N 64
#define NH_N 32
#define HD_N 64
#define DCONV_N 2176
#define DPROJ_N 4256
#define NTOK 2048
#define FFH_N 2048
#define NPAD_INPROJ 4352  // 4256 padded to multiple of 128

typedef _Float16 f16x8 __attribute__((ext_vector_type(8)));
typedef float f32x4 __attribute__((ext_vector_type(4)));

__device__ __forceinline__ float sigf(float x) { return 1.f / (1.f + __expf(-x)); }

__device__ __forceinline__ void gll16(const void* g, void* l) {
  typedef __attribute__((address_space(1))) const void gv;
  typedef __attribute__((address_space(3))) void lv;
  __builtin_amdgcn_global_load_lds((gv*)g, (lv*)l, 16, 0, 0);
}

// ---------------- fp32 -> fp16 converter (8 elems/thread), zero-pads to ntot ----------------
__global__ __launch_bounds__(256) void k_tohalf8(
    const float* __restrict__ src, _Float16* __restrict__ dst, int n, int ntot) {
  int i = (blockIdx.x * 256 + threadIdx.x) * 8;
  if (i >= ntot) return;
  f16x8 o;
  if (i < n) {
    float4 a = *(const float4*)(src + i);
    float4 b = *(const float4*)(src + i + 4);
    o[0] = (_Float16)a.x; o[1] = (_Float16)a.y; o[2] = (_Float16)a.z; o[3] = (_Float16)a.w;
    o[4] = (_Float16)b.x; o[5] = (_Float16)b.y; o[6] = (_Float16)b.z; o[7] = (_Float16)b.w;
  } else {
#pragma unroll
    for (int j = 0; j < 8; ++j) o[j] = (_Float16)0.f;
  }
  *(f16x8*)(dst + i) = o;
}

// ---- stem conv1 v2: LDS-staged image row, thread = 1 pixel x 32 co, scalar weights ----
// grid (b=8, y=32, xtile=2); 256 thr. Output channels-last fp16 X1h[b][y][x][co].
__global__ __launch_bounds__(256) void k_conv1(
    const float* __restrict__ img, const float* __restrict__ w,
    const float* __restrict__ bnp, _Float16* __restrict__ X1h) {
  __shared__ float sIn[7][520];
  int b = blockIdx.x, y = blockIdx.y, x0 = blockIdx.z * 256;
  int t = threadIdx.x;
  const float* ip = img + (size_t)b * 64 * 1024;
#pragma unroll
  for (int r = 0; r < 7; ++r) {
    int yy = 2 * y - 3 + r;
    for (int c = t; c < 517; c += 256) {
      int xx = 2 * x0 - 3 + c;
      float v = 0.f;
      if (yy >= 0 && yy < 64 && xx >= 0 && xx < 1024) v = ip[yy * 1024 + xx];
      sIn[r][c] = v;
    }
  }
  __syncthreads();
  float patch[49];
#pragma unroll
  for (int r = 0; r < 7; ++r)
#pragma unroll
    for (int s = 0; s < 7; ++s)
      patch[r * 7 + s] = sIn[r][2 * t + s];
  int x = x0 + t;
  _Float16 ov[32];
#pragma unroll
  for (int co = 0; co < 32; ++co) {
    float acc = 0.f;
    const float* wp = w + co * 49;  // uniform address -> s_load path
#pragma unroll
    for (int k = 0; k < 49; ++k) acc = fmaf(patch[k], wp[k], acc);
    float g = bnp[co], be = bnp[32 + co], mm = bnp[64 + co], vv = bnp[96 + co];
    ov[co] = (_Float16)((acc - mm) * rsqrtf(vv + EPSF) * g + be);
  }
  _Float16* op = X1h + ((size_t)(b * 32 + y) * 512 + x) * 32;
  *(f16x8*)(op) = *(f16x8*)&ov[0];
  *(f16x8*)(op + 8) = *(f16x8*)&ov[8];
  *(f16x8*)(op + 16) = *(f16x8*)&ov[16];
  *(f16x8*)(op + 24) = *(f16x8*)&ov[24];
}

// ---- w2[co][ci][r][s] -> W2t[rs][co][ci] fp16 ----
__global__ __launch_bounds__(256) void k_w2t(
    const float* __restrict__ w2, _Float16* __restrict__ W2t) {
  int i = blockIdx.x * 256 + threadIdx.x;
  if (i >= 49 * 64 * 32) return;
  int ci = i & 31, co = (i >> 5) & 63, rs = i >> 11;
  W2t[rs * 2048 + co * 32 + ci] = (_Float16)w2[co * 1568 + ci * 49 + rs];
}

// ---- conv2 as MFMA implicit GEMM: M=(b,ho,wo)=32768, N=co=64, K=(rs,ci)=49x32 ----
__global__ __launch_bounds__(512) void k_conv2m(
    const _Float16* __restrict__ X1h, const _Float16* __restrict__ W2t,
    const float* __restrict__ bn2p, const float* __restrict__ img,
    const float* __restrict__ dsw, const float* __restrict__ dsbnp,
    float* __restrict__ Tok, _Float16* __restrict__ Tok16) {
  __shared__ _Float16 As[2][128 * 40];  // 80B row stride: 2-way bank alias only
  __shared__ _Float16 Bs[2][64 * 40];
  int b = blockIdx.x, ho = blockIdx.y, wo0 = blockIdx.z * 128;
  int t = threadIdx.x;
  int w = t >> 6, lane = t & 63;
  int lr = lane & 15, kh = lane >> 4;
  int wm = w >> 1, wn = w & 1;
  f32x4 acc[2][2];
#pragma unroll
  for (int i = 0; i < 2; ++i)
#pragma unroll
    for (int j = 0; j < 2; ++j) acc[i][j] = (f32x4)(0.f);

  int arow = t >> 2, achk = t & 3;
  const _Float16* xb = X1h + (size_t)b * 32 * 512 * 32;

  auto LOADA = [&](int rs, f16x8& ra) {
    int r = rs / 7, s = rs - 7 * r;
    int y = 2 * ho + r - 3;
    int xx = 2 * (wo0 + arow) + s - 3;
    if (y >= 0 && y < 32 && xx >= 0 && xx < 512)
      ra = *(const f16x8*)(xb + ((size_t)(y * 512 + xx)) * 32 + achk * 8);
    else
      ra = (f16x8)(_Float16)0.f;
  };

  f16x8 ra, rb;
  LOADA(0, ra);
  if (t < 256) rb = *(const f16x8*)(W2t + (t >> 2) * 32 + (t & 3) * 8);
  *(f16x8*)&As[0][arow * 40 + achk * 8] = ra;
  if (t < 256) *(f16x8*)&Bs[0][(t >> 2) * 40 + (t & 3) * 8] = rb;
  __syncthreads();

  int cur = 0;
  for (int rs = 0; rs < 49; ++rs) {
    f16x8 na, nb;
    if (rs + 1 < 49) {
      LOADA(rs + 1, na);
      if (t < 256)
        nb = *(const f16x8*)(W2t + (rs + 1) * 2048 + (t >> 2) * 32 + (t & 3) * 8);
    }
    f16x8 af[2], bf[2];
#pragma unroll
    for (int i = 0; i < 2; ++i)
      af[i] = *(const f16x8*)&As[cur][(wm * 32 + i * 16 + lr) * 40 + kh * 8];
#pragma unroll
    for (int j = 0; j < 2; ++j)
      bf[j] = *(const f16x8*)&Bs[cur][(wn * 32 + j * 16 + lr) * 40 + kh * 8];
#pragma unroll
    for (int i = 0; i < 2; ++i)
#pragma unroll
      for (int j = 0; j < 2; ++j)
        acc[i][j] = __builtin_amdgcn_mfma_f32_16x16x32_f16(af[i], bf[j], acc[i][j], 0, 0, 0);
    if (rs + 1 < 49) {
      *(f16x8*)&As[cur ^ 1][arow * 40 + achk * 8] = na;
      if (t < 256) *(f16x8*)&Bs[cur ^ 1][(t >> 2) * 40 + (t & 3) * 8] = nb;
      __syncthreads();
      cur ^= 1;
    }
  }

#pragma unroll
  for (int j = 0; j < 2; ++j) {
    int co = wn * 32 + j * 16 + lr;
    float g = bn2p[co], be = bn2p[64 + co], mm = bn2p[128 + co], vv = bn2p[192 + co];
    float sc = rsqrtf(vv + EPSF) * g, sh = be - mm * sc;
    float dg = dsbnp[co], dbe = dsbnp[64 + co], dmm = dsbnp[128 + co], dvv = dsbnp[192 + co];
    float dsc = rsqrtf(dvv + EPSF) * dg, dsh = dbe - dmm * dsc;
    float wv = dsw[co];
#pragma unroll
    for (int i = 0; i < 2; ++i) {
#pragma unroll
      for (int rr = 0; rr < 4; ++rr) {
        int row = wm * 32 + i * 16 + kh * 4 + rr;
        int wo = wo0 + row;
        float dval = fmaf(img[((size_t)(b * 64 + 4 * ho)) * 1024 + 4 * wo] * wv, dsc, dsh);
        float v = fmaf(acc[i][j][rr], sc, sh) + dval;
        v = v > 0.f ? v : 0.f;
        size_t o = ((size_t)(b * 256 + wo)) * DM_N + co * 16 + ho;
        Tok[o] = v;
        Tok16[o] = (_Float16)v;
      }
    }
  }
}

// ---------------- MFMA fp16 GEMM: C[M,N] = A[M,K] * W[N,K]^T + fused epilogue ----------------
template <int MODE, int BM>
__global__ __launch_bounds__(256) void k_mgemm(
    const _Float16* __restrict__ A, const _Float16* __restrict__ W,
    int M, int N, int K,
    const float* __restrict__ bias, const float* __restrict__ bnp,
    const float* __restrict__ res, float* __restrict__ C32,
    _Float16* __restrict__ C16) {
  constexpr int MI = BM / 32;  // A-frags per wave
  __shared__ _Float16 As[2][BM * 32];
  __shared__ _Float16 Bs[2][128 * 32];
  const int t = threadIdx.x;
  const int w = t >> 6, lane = t & 63;
  const int lr = lane & 15, kh = lane >> 4;
  const int wm = w >> 1, wn = w & 1;
  const int m0 = blockIdx.y * BM, n0 = blockIdx.x * 128;
  f32x4 acc[MI][4];
#pragma unroll
  for (int i = 0; i < MI; ++i)
#pragma unroll
    for (int j = 0; j < 4; ++j) acc[i][j] = (f32x4)(0.f);

  const int nt = K >> 5;
  auto STAGE = [&](int bb, int kt) {
    const int k0 = kt << 5;
#pragma unroll
    for (int it = 0; it < BM / 64; ++it) {
      int c = it * 256 + w * 64 + lane;
      int row = c >> 2, kq = c & 3;
      gll16(A + (size_t)(m0 + row) * K + k0 + kq * 8,
            &As[bb][(size_t)(it * 256 + w * 64) * 8]);
    }
#pragma unroll
    for (int it = 0; it < 2; ++it) {
      int c = it * 256 + w * 64 + lane;
      int row = c >> 2, kq = c & 3;
      gll16(W + (size_t)(n0 + row) * K + k0 + kq * 8,
            &Bs[bb][(size_t)(it * 256 + w * 64) * 8]);
    }
  };

  STAGE(0, 0);
  __syncthreads();
  int bb = 0;
  for (int kt = 0; kt < nt; ++kt) {
    if (kt + 1 < nt) STAGE(bb ^ 1, kt + 1);
    f16x8 af[MI], bf[4];
#pragma unroll
    for (int i = 0; i < MI; ++i)
      af[i] = *(const f16x8*)&As[bb][(size_t)((wm * (BM / 2) + i * 16 + lr) * 32 + kh * 8)];
#pragma unroll
    for (int j = 0; j < 4; ++j)
      bf[j] = *(const f16x8*)&Bs[bb][(size_t)((wn * 64 + j * 16 + lr) * 32 + kh * 8)];
#pragma unroll
    for (int i = 0; i < MI; ++i)
#pragma unroll
      for (int j = 0; j < 4; ++j)
        acc[i][j] = __builtin_amdgcn_mfma_f32_16x16x32_f16(af[i], bf[j], acc[i][j], 0, 0, 0);
    __syncthreads();
    bb ^= 1;
  }

#pragma unroll
  for (int j = 0; j < 4; ++j) {
    int cn = n0 + wn * 64 + j * 16 + lr;
    if (cn >= N) continue;
    float g = 1.f, be = 0.f, sc = 1.f, sh = 0.f, bs = 0.f;
    if (MODE >= 1) {
      g = bnp[cn]; be = bnp[N + cn];
      float mm = bnp[2 * N + cn], vv = bnp[3 * N + cn];
      sc = rsqrtf(vv + EPSF) * g;
      sh = be - mm * sc;
    }
    if (MODE == 2 || MODE == 3) bs = bias[cn];
#pragma unroll
    for (int i = 0; i < MI; ++i) {
#pragma unroll
      for (int rr = 0; rr < 4; ++rr) {
        int r = m0 + wm * (BM / 2) + i * 16 + kh * 4 + rr;
        float v = acc[i][j][rr];
        if (MODE == 2 || MODE == 3) v += bs;
        if (MODE >= 1) v = fmaf(v, sc, sh);
        if (MODE == 2) v = v > 0.f ? v : 0.f;
        if (MODE == 1 || MODE == 3) v += res[(size_t)r * N + cn];
        size_t o = (size_t)r * N + cn;
        if (MODE != 2) C32[o] = v;
        if (MODE >= 1) C16[o] = (_Float16)v;
      }
    }
  }
}

// ------- causal depthwise conv1d + silu on xBC; softplus dt; dA -------
__global__ __launch_bounds__(256) void k_convprep(
    const float* __restrict__ ZX, const float* __restrict__ cw,
    const float* __restrict__ cb, const float* __restrict__ dtb,
    const float* __restrict__ Alog, float* __restrict__ XBC,
    float* __restrict__ DT, float* __restrict__ DA) {
  int m = blockIdx.x;
  int c = blockIdx.y * 256 + threadIdx.x;
  int l = m & 255;
  if (c < DCONV_N) {
    const float* cwp = cw + c * 4;
    float acc = cb[c];
#pragma unroll
    for (int k = 0; k < 4; ++k) {
      int dl = l + k - 3;
      if (dl >= 0)
        acc = fmaf(ZX[(size_t)(m + k - 3) * DPROJ_N + DI_N + c], cwp[k], acc);
    }
    XBC[(size_t)m * DCONV_N + c] = acc * sigf(acc);
  } else if (c < DCONV_N + NH_N) {
    int h = c - DCONV_N;
    float xx = ZX[(size_t)m * DPROJ_N + DI_N + DCONV_N + h] + dtb[h];
    float dt = xx > 20.f ? xx : log1pf(__expf(xx));
    DT[m * NH_N + h] = dt;
    DA[m * NH_N + h] = __expf(-dt * __expf(Alog[h]));
  }
}

// ------- selective scan v2: grid 256=(b,h), 512 thr (8 waves); thread owns (p=t>>3, 8 n) -------
__global__ __launch_bounds__(512) void k_scan(
    const float* __restrict__ XBC, const float* __restrict__ DT,
    const float* __restrict__ DA, const float* __restrict__ Dp,
    float* __restrict__ Y) {
  __shared__ float sBC[2][16][128];  // [l][0:64)=B, [64:128)=C
  __shared__ float sX[2][16][64];
  __shared__ float sDT[256], sDA[256];
  int b = blockIdx.x >> 5, h = blockIdx.x & 31;
  int t = threadIdx.x;
  int p = t >> 3, nq = t & 7, n0 = nq * 8;

  for (int i = t; i < 256; i += 512) {
    int m = b * L_N + i;
    sDT[i] = DT[m * NH_N + h];
    sDA[i] = DA[m * NH_N + h];
  }

  const int bcrow = t >> 5, bcoff = (t & 31) * 4;   // 512 thr cover 16x128
  const int xrow = t >> 4, xoff = (t & 15) * 4;     // 256 thr cover 16x64
  auto LOADT = [&](int tile, float4& rbc, float4& rx) {
    int m0 = b * L_N + tile * 16;
    rbc = *(const float4*)&XBC[(size_t)(m0 + bcrow) * DCONV_N + DI_N + bcoff];
    if (t < 256)
      rx = *(const float4*)&XBC[(size_t)(m0 + xrow) * DCONV_N + h * HD_N + xoff];
  };

  float4 rbc, rx;
  LOADT(0, rbc, rx);
  *(float4*)&sBC[0][bcrow][bcoff] = rbc;
  if (t < 256) *(float4*)&sX[0][xrow][xoff] = rx;
  __syncthreads();

  float hs[8];
#pragma unroll
  for (int j = 0; j < 8; ++j) hs[j] = 0.f;
  float Dh = Dp[h];
  float* yb = Y + ((size_t)b * L_N) * DI_N + h * HD_N + p;

  int cur = 0;
  for (int tile = 0; tile < 16; ++tile) {
    if (tile + 1 < 16) LOADT(tile + 1, rbc, rx);
#pragma unroll
    for (int l = 0; l < 16; ++l) {
      int ll = tile * 16 + l;
      float da = sDA[ll];
      float xv = sX[cur][l][p];
      float dtx = sDT[ll] * xv;
      float4 B0 = *(const float4*)&sBC[cur][l][n0];
      float4 B1 = *(const float4*)&sBC[cur][l][n0 + 4];
      float4 C0 = *(const float4*)&sBC[cur][l][64 + n0];
      float4 C1 = *(const float4*)&sBC[cur][l][64 + n0 + 4];
      float py = 0.f;
      hs[0] = fmaf(hs[0], da, dtx * B0.x); py = fmaf(hs[0], C0.x, py);
      hs[1] = fmaf(hs[1], da, dtx * B0.y); py = fmaf(hs[1], C0.y, py);
      hs[2] = fmaf(hs[2], da, dtx * B0.z); py = fmaf(hs[2], C0.z, py);
      hs[3] = fmaf(hs[3], da, dtx * B0.w); py = fmaf(hs[3], C0.w, py);
      hs[4] = fmaf(hs[4], da, dtx * B1.x); py = fmaf(hs[4], C1.x, py);
      hs[5] = fmaf(hs[5], da, dtx * B1.y); py = fmaf(hs[5], C1.y, py);
      hs[6] = fmaf(hs[6], da, dtx * B1.z); py = fmaf(hs[6], C1.z, py);
      hs[7] = fmaf(hs[7], da, dtx * B1.w); py = fmaf(hs[7], C1.w, py);
      py += __shfl_xor(py, 1);
      py += __shfl_xor(py, 2);
      py += __shfl_xor(py, 4);
      if (nq == 0) yb[(size_t)ll * DI_N] = fmaf(Dh, xv, py);
    }
    if (tile + 1 < 16) {
      *(float4*)&sBC[cur ^ 1][bcrow][bcoff] = rbc;
      if (t < 256) *(float4*)&sX[cur ^ 1][xrow][xoff] = rx;
      __syncthreads();
      cur ^= 1;
    }
  }
}

// ------- gate with silu(z) + RMSNorm (over DI) -> fp16 -------
__global__ __launch_bounds__(256) void k_gatenorm(
    const float* __restrict__ Y, const float* __restrict__ ZX,
    const float* __restrict__ nw, _Float16* __restrict__ YN16) {
  int m = blockIdx.x, t = threadIdx.x;
  const float* y = Y + (size_t)m * DI_N;
  const float* z = ZX + (size_t)m * DPROJ_N;
  float vals[8];
  float ss = 0.f;
#pragma unroll
  for (int j = 0; j < 8; ++j) {
    int c = t + 256 * j;
    float zz = z[c];
    float vv = y[c] * zz * sigf(zz);
    vals[j] = vv;
    ss = fmaf(vv, vv, ss);
  }
#pragma unroll
  for (int o = 1; o < 64; o <<= 1) ss += __shfl_xor(ss, o);
  __shared__ float sred[4];
  if ((t & 63) == 0) sred[t >> 6] = ss;
  __syncthreads();
  float tot = sred[0] + sred[1] + sred[2] + sred[3];
  float scale = rsqrtf(tot * (1.f / DI_N) + EPSF);
#pragma unroll
  for (int j = 0; j < 8; ++j) {
    int c = t + 256 * j;
    YN16[(size_t)m * DI_N + c] = (_Float16)(vals[j] * scale * nw[c]);
  }
}

// ------- final transpose: Tok[m][d] -> out[b][d][l] -------
__global__ __launch_bounds__(256) void k_transpose(
    const float* __restrict__ Tok, float* __restrict__ out) {
  __shared__ float tile[32][33];
  int d0 = blockIdx.x * 32, m0 = blockIdx.y * 32;
  int tx = threadIdx.x & 31, ty = threadIdx.x >> 5;
  for (int i = ty; i < 32; i += 8)
    tile[i][tx] = Tok[(size_t)(m0 + i) * DM_N + d0 + tx];
  __syncthreads();
  int b = m0 >> 8, l0 = m0 & 255;
  for (int i = ty; i < 32; i += 8)
    out[((size_t)b * DM_N + d0 + i) * L_N + l0 + tx] = tile[tx][i];
}

extern "C" void kernel_launch(void* const* d_in, const int* in_sizes, int n_in,
                              void* d_out, int out_size, void* d_ws, size_t ws_size,
                              hipStream_t stream) {
  const float* image = (const float*)d_in[0];
  const float* conv1_w = (const float*)d_in[1];
  const float* bn1 = (const float*)d_in[2];
  const float* conv2_w = (const float*)d_in[3];
  const float* bn2 = (const float*)d_in[4];
  const float* ds_w = (const float*)d_in[5];
  const float* ds_bn = (const float*)d_in[6];
  const float* in_proj_w = (const float*)d_in[7];
  const float* conv1d_w = (const float*)d_in[8];
  const float* conv1d_b = (const float*)d_in[9];
  const float* dt_bias = (const float*)d_in[10];
  const float* A_log = (const float*)d_in[11];
  const float* Dpar = (const float*)d_in[12];
  const float* norm_w = (const float*)d_in[13];
  const float* out_proj_w = (const float*)d_in[14];
  const float* blk_bn = (const float*)d_in[15];
  const float* ff_w1 = (const float*)d_in[16];
  const float* ff_b1 = (const float*)d_in[17];
  const float* ff_bn1 = (const float*)d_in[18];
  const float* ff_w2 = (const float*)d_in[19];
  const float* ff_b2 = (const float*)d_in[20];
  const float* ff_bn2 = (const float*)d_in[21];

  // workspace layout: fp32 region then fp16 region (~108 MB total)
  float* ws = (float*)d_ws;
  float* Tok = ws;                        // 2048*1024
  float* ZX = Tok + (size_t)NTOK * DM_N;  // 2048*4256
  float* XBC = ZX + (size_t)NTOK * DPROJ_N;
  float* DTb = XBC + (size_t)NTOK * DCONV_N;
  float* DAb = DTb + (size_t)NTOK * NH_N;
  float* YR = DAb + (size_t)NTOK * NH_N;  // 2048*2048; stem X1h aliases this
  _Float16* Tok16 = (_Float16*)(YR + (size_t)NTOK * DI_N);  // 2048*1024
  _Float16* YN16 = Tok16 + (size_t)NTOK * DM_N;             // 2048*2048
  _Float16* H116 = YN16 + (size_t)NTOK * DI_N;              // 2048*2048
  _Float16* W16 = H116 + (size_t)NTOK * DI_N;               // 4352*1024
  _Float16* W2t = W16 + (size_t)NPAD_INPROJ * DM_N;         // 49*64*32
  _Float16* X1h = (_Float16*)YR;

  k_conv1<<<dim3(8, 32, 2), 256, 0, stream>>>(image, conv1_w, bn1, X1h);
  k_w2t<<<(49 * 64 * 32 + 255) / 256, 256, 0, stream>>>(conv2_w, W2t);
  k_conv2m<<<dim3(8, 16, 2), 512, 0, stream>>>(X1h, W2t, bn2, image, ds_w, ds_bn, Tok, Tok16);

  for (int i = 0; i < 4; ++i) {
    const float* Wi = in_proj_w + (size_t)i * DPROJ_N * DM_N;
    const float* cw = conv1d_w + (size_t)i * DCONV_N * 4;
    const float* cb = conv1d_b + (size_t)i * DCONV_N;
    const float* dtb = dt_bias + i * NH_N;
    const float* al = A_log + i * NH_N;
    const float* dd = Dpar + i * NH_N;
    const float* nw = norm_w + i * DI_N;
    const float* Wo = out_proj_w + (size_t)i * DM_N * DI_N;
    const float* bbn = blk_bn + (size_t)i * 4 * DM_N;
    const float* w1 = ff_w1 + (size_t)i * FFH_N * DM_N;
    const float* b1 = ff_b1 + i * FFH_N;
    const float* fbn1 = ff_bn1 + (size_t)i * 4 * FFH_N;
    const float* w2 = ff_w2 + (size_t)i * DM_N * FFH_N;
    const float* b2 = ff_b2 + i * DM_N;
    const float* fbn2 = ff_bn2 + (size_t)i * 4 * DM_N;

    // in_proj: [2048,4256] = Tok16[2048,1024] x Wi^T
    k_tohalf8<<<(NPAD_INPROJ * 1024 / 8 + 255) / 256, 256, 0, stream>>>(
        Wi, W16, DPROJ_N * DM_N, NPAD_INPROJ * DM_N);
    k_mgemm<0, 128><<<dim3(34, 16), 256, 0, stream>>>(
        Tok16, W16, NTOK, DPROJ_N, DM_N, nullptr, nullptr, nullptr, ZX, nullptr);
    k_convprep<<<dim3(NTOK, 9), 256, 0, stream>>>(ZX, cw, cb, dtb, al, XBC, DTb, DAb);
    k_scan<<<256, 512, 0, stream>>>(XBC, DTb, DAb, dd, YR);
    k_gatenorm<<<NTOK, 256, 0, stream>>>(YR, ZX, nw, YN16);
    // out_proj: [2048,1024] = YN16[2048,2048] x Wo^T, +bn+res -> Tok/Tok16
    k_tohalf8<<<(DM_N * DI_N / 8 + 255) / 256, 256, 0, stream>>>(
        Wo, W16, DM_N * DI_N, DM_N * DI_N);
    k_mgemm<1, 64><<<dim3(8, 32), 256, 0, stream>>>(
        YN16, W16, NTOK, DM_N, DI_N, nullptr, bbn, Tok, Tok, Tok16);
    // ff1: [2048,2048] = Tok16 x w1^T, +bias+bn+relu -> H116
    k_tohalf8<<<(FFH_N * DM_N / 8 + 255) / 256, 256, 0, stream>>>(
        w1, W16, FFH_N * DM_N, FFH_N * DM_N);
    k_mgemm<2, 128><<<dim3(16, 16), 256, 0, stream>>>(
        Tok16, W16, NTOK, FFH_N, DM_N, b1, fbn1, nullptr, nullptr, H116);
    // ff2: [2048,1024] = H116 x w2^T, +bias+bn+res -> Tok/Tok16
    k_tohalf8<<<(DM_N * FFH_N / 8 + 255) / 256, 256, 0, stream>>>(
        w2, W16, DM_N * FFH_N, DM_N * FFH_N);
    k_mgemm<3, 64><<<dim3(8, 32), 256, 0, stream>>>(
        H116, W16, NTOK, DM_N, FFH_N, b2, fbn2, Tok, Tok, Tok16);
  }
  k_transpose<<<dim3(32, 64), 256, 0, stream>>>(Tok, (float*)d_out);
}

// Round 8
// 865.451 us; speedup vs baseline: 5.9060x; 1.1704x over previous
//
#include <hip/hip_runtime.h>
#include <hip/hip_bf16.h>
#include <hip/hip_fp16.h>
#include <math.h>

#define EPSF 1e-5f
#define B_N 8
#define L_N 256
#define DM_N 1024
#define DI_N 2048
#define DS_N 64
#define NH_N 32
#define HD_N 64
#define DCONV_N 2176
#define DPROJ_N 4256
#define NTOK 2048
#define FFH_N 2048
#define NPAD_INPROJ 4352  // 4256 padded to multiple of 128

typedef _Float16 f16x8 __attribute__((ext_vector_type(8)));
typedef float f32x4 __attribute__((ext_vector_type(4)));

__device__ __forceinline__ float sigf(float x) { return 1.f / (1.f + __expf(-x)); }

__device__ __forceinline__ void gll16(const void* g, void* l) {
  typedef __attribute__((address_space(1))) const void gv;
  typedef __attribute__((address_space(3))) void lv;
  __builtin_amdgcn_global_load_lds((gv*)g, (lv*)l, 16, 0, 0);
}

__device__ __forceinline__ f16x8 cvt8(float4 a, float4 b) {
  f16x8 o;
  o[0] = (_Float16)a.x; o[1] = (_Float16)a.y; o[2] = (_Float16)a.z; o[3] = (_Float16)a.w;
  o[4] = (_Float16)b.x; o[5] = (_Float16)b.y; o[6] = (_Float16)b.z; o[7] = (_Float16)b.w;
  return o;
}

// ---------------- fp32 -> fp16 converter (8 elems/thread), zero-pads to ntot ----------------
__global__ __launch_bounds__(256) void k_tohalf8(
    const float* __restrict__ src, _Float16* __restrict__ dst, int n, int ntot) {
  int i = (blockIdx.x * 256 + threadIdx.x) * 8;
  if (i >= ntot) return;
  f16x8 o;
  if (i < n) {
    float4 a = *(const float4*)(src + i);
    float4 b = *(const float4*)(src + i + 4);
    o = cvt8(a, b);
  } else {
#pragma unroll
    for (int j = 0; j < 8; ++j) o[j] = (_Float16)0.f;
  }
  *(f16x8*)(dst + i) = o;
}

// ---- stem conv1 v2: LDS-staged image row, thread = 1 pixel x 32 co, scalar weights ----
__global__ __launch_bounds__(256) void k_conv1(
    const float* __restrict__ img, const float* __restrict__ w,
    const float* __restrict__ bnp, _Float16* __restrict__ X1h) {
  __shared__ float sIn[7][520];
  int b = blockIdx.x, y = blockIdx.y, x0 = blockIdx.z * 256;
  int t = threadIdx.x;
  const float* ip = img + (size_t)b * 64 * 1024;
#pragma unroll
  for (int r = 0; r < 7; ++r) {
    int yy = 2 * y - 3 + r;
    for (int c = t; c < 517; c += 256) {
      int xx = 2 * x0 - 3 + c;
      float v = 0.f;
      if (yy >= 0 && yy < 64 && xx >= 0 && xx < 1024) v = ip[yy * 1024 + xx];
      sIn[r][c] = v;
    }
  }
  __syncthreads();
  float patch[49];
#pragma unroll
  for (int r = 0; r < 7; ++r)
#pragma unroll
    for (int s = 0; s < 7; ++s)
      patch[r * 7 + s] = sIn[r][2 * t + s];
  int x = x0 + t;
  _Float16 ov[32];
#pragma unroll
  for (int co = 0; co < 32; ++co) {
    float acc = 0.f;
    const float* wp = w + co * 49;  // uniform address -> s_load path
#pragma unroll
    for (int k = 0; k < 49; ++k) acc = fmaf(patch[k], wp[k], acc);
    float g = bnp[co], be = bnp[32 + co], mm = bnp[64 + co], vv = bnp[96 + co];
    ov[co] = (_Float16)((acc - mm) * rsqrtf(vv + EPSF) * g + be);
  }
  _Float16* op = X1h + ((size_t)(b * 32 + y) * 512 + x) * 32;
  *(f16x8*)(op) = *(f16x8*)&ov[0];
  *(f16x8*)(op + 8) = *(f16x8*)&ov[8];
  *(f16x8*)(op + 16) = *(f16x8*)&ov[16];
  *(f16x8*)(op + 24) = *(f16x8*)&ov[24];
}

// ---- w2[co][ci][r][s] -> W2t[rs][co][ci] fp16 ----
__global__ __launch_bounds__(256) void k_w2t(
    const float* __restrict__ w2, _Float16* __restrict__ W2t) {
  int i = blockIdx.x * 256 + threadIdx.x;
  if (i >= 49 * 64 * 32) return;
  int ci = i & 31, co = (i >> 5) & 63, rs = i >> 11;
  W2t[rs * 2048 + co * 32 + ci] = (_Float16)w2[co * 1568 + ci * 49 + rs];
}

// ---- conv2 as MFMA implicit GEMM: M=(b,ho,wo)=32768, N=co=64, K=(rs,ci)=49x32 ----
__global__ __launch_bounds__(512) void k_conv2m(
    const _Float16* __restrict__ X1h, const _Float16* __restrict__ W2t,
    const float* __restrict__ bn2p, const float* __restrict__ img,
    const float* __restrict__ dsw, const float* __restrict__ dsbnp,
    float* __restrict__ Tok, _Float16* __restrict__ Tok16) {
  __shared__ _Float16 As[2][128 * 40];  // 80B row stride: 2-way bank alias only
  __shared__ _Float16 Bs[2][64 * 40];
  int b = blockIdx.x, ho = blockIdx.y, wo0 = blockIdx.z * 128;
  int t = threadIdx.x;
  int w = t >> 6, lane = t & 63;
  int lr = lane & 15, kh = lane >> 4;
  int wm = w >> 1, wn = w & 1;
  f32x4 acc[2][2];
#pragma unroll
  for (int i = 0; i < 2; ++i)
#pragma unroll
    for (int j = 0; j < 2; ++j) acc[i][j] = (f32x4)(0.f);

  int arow = t >> 2, achk = t & 3;
  const _Float16* xb = X1h + (size_t)b * 32 * 512 * 32;

  auto LOADA = [&](int rs, f16x8& ra) {
    int r = rs / 7, s = rs - 7 * r;
    int y = 2 * ho + r - 3;
    int xx = 2 * (wo0 + arow) + s - 3;
    if (y >= 0 && y < 32 && xx >= 0 && xx < 512)
      ra = *(const f16x8*)(xb + ((size_t)(y * 512 + xx)) * 32 + achk * 8);
    else
      ra = (f16x8)(_Float16)0.f;
  };

  f16x8 ra, rb;
  LOADA(0, ra);
  if (t < 256) rb = *(const f16x8*)(W2t + (t >> 2) * 32 + (t & 3) * 8);
  *(f16x8*)&As[0][arow * 40 + achk * 8] = ra;
  if (t < 256) *(f16x8*)&Bs[0][(t >> 2) * 40 + (t & 3) * 8] = rb;
  __syncthreads();

  int cur = 0;
  for (int rs = 0; rs < 49; ++rs) {
    f16x8 na, nb;
    if (rs + 1 < 49) {
      LOADA(rs + 1, na);
      if (t < 256)
        nb = *(const f16x8*)(W2t + (rs + 1) * 2048 + (t >> 2) * 32 + (t & 3) * 8);
    }
    f16x8 af[2], bf[2];
#pragma unroll
    for (int i = 0; i < 2; ++i)
      af[i] = *(const f16x8*)&As[cur][(wm * 32 + i * 16 + lr) * 40 + kh * 8];
#pragma unroll
    for (int j = 0; j < 2; ++j)
      bf[j] = *(const f16x8*)&Bs[cur][(wn * 32 + j * 16 + lr) * 40 + kh * 8];
#pragma unroll
    for (int i = 0; i < 2; ++i)
#pragma unroll
      for (int j = 0; j < 2; ++j)
        acc[i][j] = __builtin_amdgcn_mfma_f32_16x16x32_f16(af[i], bf[j], acc[i][j], 0, 0, 0);
    if (rs + 1 < 49) {
      *(f16x8*)&As[cur ^ 1][arow * 40 + achk * 8] = na;
      if (t < 256) *(f16x8*)&Bs[cur ^ 1][(t >> 2) * 40 + (t & 3) * 8] = nb;
      __syncthreads();
      cur ^= 1;
    }
  }

#pragma unroll
  for (int j = 0; j < 2; ++j) {
    int co = wn * 32 + j * 16 + lr;
    float g = bn2p[co], be = bn2p[64 + co], mm = bn2p[128 + co], vv = bn2p[192 + co];
    float sc = rsqrtf(vv + EPSF) * g, sh = be - mm * sc;
    float dg = dsbnp[co], dbe = dsbnp[64 + co], dmm = dsbnp[128 + co], dvv = dsbnp[192 + co];
    float dsc = rsqrtf(dvv + EPSF) * dg, dsh = dbe - dmm * dsc;
    float wv = dsw[co];
#pragma unroll
    for (int i = 0; i < 2; ++i) {
#pragma unroll
      for (int rr = 0; rr < 4; ++rr) {
        int row = wm * 32 + i * 16 + kh * 4 + rr;
        int wo = wo0 + row;
        float dval = fmaf(img[((size_t)(b * 64 + 4 * ho)) * 1024 + 4 * wo] * wv, dsc, dsh);
        float v = fmaf(acc[i][j][rr], sc, sh) + dval;
        v = v > 0.f ? v : 0.f;
        size_t o = ((size_t)(b * 256 + wo)) * DM_N + co * 16 + ho;
        Tok[o] = v;
        Tok16[o] = (_Float16)v;
      }
    }
  }
}

// ---------------- MFMA fp16 GEMM: C[M,N] = A[M,K] * W[N,K]^T + fused epilogue ----------------
template <int MODE, int BM>
__global__ __launch_bounds__(256) void k_mgemm(
    const _Float16* __restrict__ A, const _Float16* __restrict__ W,
    int M, int N, int K,
    const float* __restrict__ bias, const float* __restrict__ bnp,
    const float* __restrict__ res, float* __restrict__ C32,
    _Float16* __restrict__ C16) {
  constexpr int MI = BM / 32;  // A-frags per wave
  __shared__ _Float16 As[2][BM * 32];
  __shared__ _Float16 Bs[2][128 * 32];
  const int t = threadIdx.x;
  const int w = t >> 6, lane = t & 63;
  const int lr = lane & 15, kh = lane >> 4;
  const int wm = w >> 1, wn = w & 1;
  const int m0 = blockIdx.y * BM, n0 = blockIdx.x * 128;
  f32x4 acc[MI][4];
#pragma unroll
  for (int i = 0; i < MI; ++i)
#pragma unroll
    for (int j = 0; j < 4; ++j) acc[i][j] = (f32x4)(0.f);

  const int nt = K >> 5;
  auto STAGE = [&](int bb, int kt) {
    const int k0 = kt << 5;
#pragma unroll
    for (int it = 0; it < BM / 64; ++it) {
      int c = it * 256 + w * 64 + lane;
      int row = c >> 2, kq = c & 3;
      gll16(A + (size_t)(m0 + row) * K + k0 + kq * 8,
            &As[bb][(size_t)(it * 256 + w * 64) * 8]);
    }
#pragma unroll
    for (int it = 0; it < 2; ++it) {
      int c = it * 256 + w * 64 + lane;
      int row = c >> 2, kq = c & 3;
      gll16(W + (size_t)(n0 + row) * K + k0 + kq * 8,
            &Bs[bb][(size_t)(it * 256 + w * 64) * 8]);
    }
  };

  STAGE(0, 0);
  __syncthreads();
  int bb = 0;
  for (int kt = 0; kt < nt; ++kt) {
    if (kt + 1 < nt) STAGE(bb ^ 1, kt + 1);
    f16x8 af[MI], bf[4];
#pragma unroll
    for (int i = 0; i < MI; ++i)
      af[i] = *(const f16x8*)&As[bb][(size_t)((wm * (BM / 2) + i * 16 + lr) * 32 + kh * 8)];
#pragma unroll
    for (int j = 0; j < 4; ++j)
      bf[j] = *(const f16x8*)&Bs[bb][(size_t)((wn * 64 + j * 16 + lr) * 32 + kh * 8)];
#pragma unroll
    for (int i = 0; i < MI; ++i)
#pragma unroll
      for (int j = 0; j < 4; ++j)
        acc[i][j] = __builtin_amdgcn_mfma_f32_16x16x32_f16(af[i], bf[j], acc[i][j], 0, 0, 0);
    __syncthreads();
    bb ^= 1;
  }

#pragma unroll
  for (int j = 0; j < 4; ++j) {
    int cn = n0 + wn * 64 + j * 16 + lr;
    if (cn >= N) continue;
    float g = 1.f, be = 0.f, sc = 1.f, sh = 0.f, bs = 0.f;
    if (MODE >= 1) {
      g = bnp[cn]; be = bnp[N + cn];
      float mm = bnp[2 * N + cn], vv = bnp[3 * N + cn];
      sc = rsqrtf(vv + EPSF) * g;
      sh = be - mm * sc;
    }
    if (MODE == 2 || MODE == 3) bs = bias[cn];
#pragma unroll
    for (int i = 0; i < MI; ++i) {
#pragma unroll
      for (int rr = 0; rr < 4; ++rr) {
        int r = m0 + wm * (BM / 2) + i * 16 + kh * 4 + rr;
        float v = acc[i][j][rr];
        if (MODE == 2 || MODE == 3) v += bs;
        if (MODE >= 1) v = fmaf(v, sc, sh);
        if (MODE == 2) v = v > 0.f ? v : 0.f;
        if (MODE == 1 || MODE == 3) v += res[(size_t)r * N + cn];
        size_t o = (size_t)r * N + cn;
        if (MODE != 2) C32[o] = v;
        if (MODE >= 1) C16[o] = (_Float16)v;
      }
    }
  }
}

// ------- causal depthwise conv1d + silu on xBC; softplus dt; LOG-decay -------
__global__ __launch_bounds__(256) void k_convprep(
    const float* __restrict__ ZX, const float* __restrict__ cw,
    const float* __restrict__ cb, const float* __restrict__ dtb,
    const float* __restrict__ Alog, float* __restrict__ XBC,
    float* __restrict__ DT, float* __restrict__ DLA) {
  int m = blockIdx.x;
  int c = blockIdx.y * 256 + threadIdx.x;
  int l = m & 255;
  if (c < DCONV_N) {
    const float* cwp = cw + c * 4;
    float acc = cb[c];
#pragma unroll
    for (int k = 0; k < 4; ++k) {
      int dl = l + k - 3;
      if (dl >= 0)
        acc = fmaf(ZX[(size_t)(m + k - 3) * DPROJ_N + DI_N + c], cwp[k], acc);
    }
    XBC[(size_t)m * DCONV_N + c] = acc * sigf(acc);
  } else if (c < DCONV_N + NH_N) {
    int h = c - DCONV_N;
    float xx = ZX[(size_t)m * DPROJ_N + DI_N + DCONV_N + h] + dtb[h];
    float dt = xx > 20.f ? xx : log1pf(__expf(xx));
    DT[m * NH_N + h] = dt;
    DLA[m * NH_N + h] = -dt * __expf(Alog[h]);  // log(dA), always finite, <= 0
  }
}

// ------- selective scan v3: Mamba2 SSD chunked, MFMA. grid 256=(b,h), 256 thr (4 waves) -------
// Per chunk (Lc=64): S=C@B^T; P=S*exp(s_l-s_j) masked; Y=el*(C@h^T)+P@Xd^T; h'=cpt*h+Xd^T@Bs^T.
__global__ __launch_bounds__(256) void k_scan(
    const float* __restrict__ XBC, const float* __restrict__ DT,
    const float* __restrict__ DLA, const float* __restrict__ Dp,
    float* __restrict__ Y) {
  __shared__ _Float16 sC[64][72];    // C[l][n]
  __shared__ _Float16 sB[64][72];    // B[l][n]
  __shared__ _Float16 sBts[64][72];  // [n][j] = B[j][n]*es[j]
  __shared__ _Float16 sXt[64][72];   // [p][l] = dt[l]*x[l][p]
  __shared__ _Float16 sP[64][72];    // P[l][j]
  __shared__ _Float16 sH[64][72];    // h[p][n] fp16 mirror
  __shared__ float sH32[64][68];     // h[p][n] fp32 master
  __shared__ float sS[64], sEl[64], sEs[64], sDt[64];
  __shared__ float sCpt;

  const int b = blockIdx.x >> 5, h = blockIdx.x & 31;
  const int t = threadIdx.x;
  const int w = t >> 6, lane = t & 63;
  const int lr = lane & 15, kh = lane >> 4;
  const float Dh = Dp[h];

  {  // zero h
    _Float16* hp = &sH[0][0];
    float* h32p = &sH32[0][0];
    for (int i = t; i < 64 * 72; i += 256) hp[i] = (_Float16)0.f;
    for (int i = t; i < 64 * 68; i += 256) h32p[i] = 0.f;
  }

  for (int c = 0; c < 4; ++c) {
    const int mbase = b * L_N + c * 64;
    __syncthreads();  // A: protect LDS reuse across chunks (incl. h16 writes)

    if (t < 64) {  // B: segsum in wave 0
      int l = t;
      float v = DLA[(mbase + l) * NH_N + h];
#pragma unroll
      for (int o = 1; o < 64; o <<= 1) {
        float u = __shfl_up(v, o);
        v += (l >= o) ? u : 0.f;
      }
      sS[l] = v;
      sEl[l] = __expf(v);
      float s63 = __shfl(v, 63);
      sEs[l] = __expf(s63 - v);
      if (l == 63) sCpt = __expf(s63);
      sDt[l] = DT[(mbase + l) * NH_N + h];
    }
    __syncthreads();  // B -> C

    {  // C: build tiles. thread = (row l = t>>2, col quarter q = t&3)
      int l = t >> 2, q = t & 3;
      const float* row = XBC + (size_t)(mbase + l) * DCONV_N;
      float dt_l = sDt[l], es_l = sEs[l];
      // B
      float4 b0 = *(const float4*)&row[DI_N + q * 16];
      float4 b1 = *(const float4*)&row[DI_N + q * 16 + 4];
      float4 b2 = *(const float4*)&row[DI_N + q * 16 + 8];
      float4 b3 = *(const float4*)&row[DI_N + q * 16 + 12];
      *(f16x8*)&sB[l][q * 16] = cvt8(b0, b1);
      *(f16x8*)&sB[l][q * 16 + 8] = cvt8(b2, b3);
      float bv[16] = {b0.x, b0.y, b0.z, b0.w, b1.x, b1.y, b1.z, b1.w,
                      b2.x, b2.y, b2.z, b2.w, b3.x, b3.y, b3.z, b3.w};
#pragma unroll
      for (int i = 0; i < 16; ++i) sBts[q * 16 + i][l] = (_Float16)(bv[i] * es_l);
      // C
      float4 c0 = *(const float4*)&row[DI_N + DS_N + q * 16];
      float4 c1 = *(const float4*)&row[DI_N + DS_N + q * 16 + 4];
      float4 c2 = *(const float4*)&row[DI_N + DS_N + q * 16 + 8];
      float4 c3 = *(const float4*)&row[DI_N + DS_N + q * 16 + 12];
      *(f16x8*)&sC[l][q * 16] = cvt8(c0, c1);
      *(f16x8*)&sC[l][q * 16 + 8] = cvt8(c2, c3);
      // x -> Xd^T
      float4 x0 = *(const float4*)&row[h * HD_N + q * 16];
      float4 x1 = *(const float4*)&row[h * HD_N + q * 16 + 4];
      float4 x2 = *(const float4*)&row[h * HD_N + q * 16 + 8];
      float4 x3 = *(const float4*)&row[h * HD_N + q * 16 + 12];
      float xv[16] = {x0.x, x0.y, x0.z, x0.w, x1.x, x1.y, x1.z, x1.w,
                      x2.x, x2.y, x2.z, x2.w, x3.x, x3.y, x3.z, x3.w};
#pragma unroll
      for (int i = 0; i < 16; ++i) sXt[q * 16 + i][l] = (_Float16)(xv[i] * dt_l);
    }
    __syncthreads();  // C -> D

    // D: S = C@B^T ; Yinter = C@h^T (both M-rows = 16w..)
    f32x4 Sacc[4], Yacc[4];
#pragma unroll
    for (int j = 0; j < 4; ++j) { Sacc[j] = (f32x4)(0.f); Yacc[j] = (f32x4)(0.f); }
    {
      f16x8 aC[2];
#pragma unroll
      for (int kk = 0; kk < 2; ++kk)
        aC[kk] = *(const f16x8*)&sC[16 * w + lr][kk * 32 + kh * 8];
#pragma unroll
      for (int kk = 0; kk < 2; ++kk)
#pragma unroll
        for (int jt = 0; jt < 4; ++jt) {
          f16x8 bB = *(const f16x8*)&sB[jt * 16 + lr][kk * 32 + kh * 8];
          f16x8 bH = *(const f16x8*)&sH[jt * 16 + lr][kk * 32 + kh * 8];
          Sacc[jt] = __builtin_amdgcn_mfma_f32_16x16x32_f16(aC[kk], bB, Sacc[jt], 0, 0, 0);
          Yacc[jt] = __builtin_amdgcn_mfma_f32_16x16x32_f16(aC[kk], bH, Yacc[jt], 0, 0, 0);
        }
    }

    // E: mask P, scale Yinter rows by el
#pragma unroll
    for (int rr = 0; rr < 4; ++rr) {
      int l = 16 * w + kh * 4 + rr;
      float sl = sS[l], el = sEl[l];
#pragma unroll
      for (int jt = 0; jt < 4; ++jt) {
        int j = jt * 16 + lr;
        float pv = (j <= l) ? Sacc[jt][rr] * __expf(sl - sS[j]) : 0.f;
        sP[l][j] = (_Float16)pv;
        Yacc[jt][rr] *= el;
      }
    }
    __syncthreads();  // E -> F

    // F: Y += P@Xd^T ; Hacc = Xd^T-rows @ Bts^T
    f32x4 Hacc[4];
#pragma unroll
    for (int j = 0; j < 4; ++j) Hacc[j] = (f32x4)(0.f);
    {
      f16x8 aP[2], aX[2];
#pragma unroll
      for (int kk = 0; kk < 2; ++kk) {
        aP[kk] = *(const f16x8*)&sP[16 * w + lr][kk * 32 + kh * 8];
        aX[kk] = *(const f16x8*)&sXt[16 * w + lr][kk * 32 + kh * 8];
      }
#pragma unroll
      for (int kk = 0; kk < 2; ++kk)
#pragma unroll
        for (int jt = 0; jt < 4; ++jt) {
          f16x8 bX = *(const f16x8*)&sXt[jt * 16 + lr][kk * 32 + kh * 8];
          f16x8 bBt = *(const f16x8*)&sBts[jt * 16 + lr][kk * 32 + kh * 8];
          Yacc[jt] = __builtin_amdgcn_mfma_f32_16x16x32_f16(aP[kk], bX, Yacc[jt], 0, 0, 0);
          Hacc[jt] = __builtin_amdgcn_mfma_f32_16x16x32_f16(aX[kk], bBt, Hacc[jt], 0, 0, 0);
        }
    }

    // G: epilogue — Y out (+D skip), h update
    float cpt = sCpt;
#pragma unroll
    for (int rr = 0; rr < 4; ++rr) {
      int lrow = 16 * w + kh * 4 + rr;
      int m = mbase + lrow;
#pragma unroll
      for (int jt = 0; jt < 4; ++jt) {
        int p = jt * 16 + lr;
        float xr = XBC[(size_t)m * DCONV_N + h * HD_N + p];
        Y[(size_t)m * DI_N + h * HD_N + p] = fmaf(Dh, xr, Yacc[jt][rr]);
        float hv = fmaf(cpt, sH32[lrow][p == p ? (jt * 16 + lr) : 0], Hacc[jt][rr]);
        // (note: Hacc rows are p'=lrow here since A=Xt rows; cols n=jt*16+lr)
        sH32[lrow][jt * 16 + lr] = hv;
        sH[lrow][jt * 16 + lr] = (_Float16)hv;
      }
    }
  }
}

// ------- gate with silu(z) + RMSNorm (over DI) -> fp16 -------
__global__ __launch_bounds__(256) void k_gatenorm(
    const float* __restrict__ Y, const float* __restrict__ ZX,
    const float* __restrict__ nw, _Float16* __restrict__ YN16) {
  int m = blockIdx.x, t = threadIdx.x;
  const float* y = Y + (size_t)m * DI_N;
  const float* z = ZX + (size_t)m * DPROJ_N;
  float vals[8];
  float ss = 0.f;
#pragma unroll
  for (int j = 0; j < 8; ++j) {
    int c = t + 256 * j;
    float zz = z[c];
    float vv = y[c] * zz * sigf(zz);
    vals[j] = vv;
    ss = fmaf(vv, vv, ss);
  }
#pragma unroll
  for (int o = 1; o < 64; o <<= 1) ss += __shfl_xor(ss, o);
  __shared__ float sred[4];
  if ((t & 63) == 0) sred[t >> 6] = ss;
  __syncthreads();
  float tot = sred[0] + sred[1] + sred[2] + sred[3];
  float scale = rsqrtf(tot * (1.f / DI_N) + EPSF);
#pragma unroll
  for (int j = 0; j < 8; ++j) {
    int c = t + 256 * j;
    YN16[(size_t)m * DI_N + c] = (_Float16)(vals[j] * scale * nw[c]);
  }
}

// ------- final transpose: Tok[m][d] -> out[b][d][l] -------
__global__ __launch_bounds__(256) void k_transpose(
    const float* __restrict__ Tok, float* __restrict__ out) {
  __shared__ float tile[32][33];
  int d0 = blockIdx.x * 32, m0 = blockIdx.y * 32;
  int tx = threadIdx.x & 31, ty = threadIdx.x >> 5;
  for (int i = ty; i < 32; i += 8)
    tile[i][tx] = Tok[(size_t)(m0 + i) * DM_N + d0 + tx];
  __syncthreads();
  int b = m0 >> 8, l0 = m0 & 255;
  for (int i = ty; i < 32; i += 8)
    out[((size_t)b * DM_N + d0 + i) * L_N + l0 + tx] = tile[tx][i];
}

extern "C" void kernel_launch(void* const* d_in, const int* in_sizes, int n_in,
                              void* d_out, int out_size, void* d_ws, size_t ws_size,
                              hipStream_t stream) {
  const float* image = (const float*)d_in[0];
  const float* conv1_w = (const float*)d_in[1];
  const float* bn1 = (const float*)d_in[2];
  const float* conv2_w = (const float*)d_in[3];
  const float* bn2 = (const float*)d_in[4];
  const float* ds_w = (const float*)d_in[5];
  const float* ds_bn = (const float*)d_in[6];
  const float* in_proj_w = (const float*)d_in[7];
  const float* conv1d_w = (const float*)d_in[8];
  const float* conv1d_b = (const float*)d_in[9];
  const float* dt_bias = (const float*)d_in[10];
  const float* A_log = (const float*)d_in[11];
  const float* Dpar = (const float*)d_in[12];
  const float* norm_w = (const float*)d_in[13];
  const float* out_proj_w = (const float*)d_in[14];
  const float* blk_bn = (const float*)d_in[15];
  const float* ff_w1 = (const float*)d_in[16];
  const float* ff_b1 = (const float*)d_in[17];
  const float* ff_bn1 = (const float*)d_in[18];
  const float* ff_w2 = (const float*)d_in[19];
  const float* ff_b2 = (const float*)d_in[20];
  const float* ff_bn2 = (const float*)d_in[21];

  // workspace layout: fp32 region then fp16 region (~108 MB total)
  float* ws = (float*)d_ws;
  float* Tok = ws;                        // 2048*1024
  float* ZX = Tok + (size_t)NTOK * DM_N;  // 2048*4256
  float* XBC = ZX + (size_t)NTOK * DPROJ_N;
  float* DTb = XBC + (size_t)NTOK * DCONV_N;
  float* DLAb = DTb + (size_t)NTOK * NH_N;
  float* YR = DLAb + (size_t)NTOK * NH_N;  // 2048*2048; stem X1h aliases this
  _Float16* Tok16 = (_Float16*)(YR + (size_t)NTOK * DI_N);  // 2048*1024
  _Float16* YN16 = Tok16 + (size_t)NTOK * DM_N;             // 2048*2048
  _Float16* H116 = YN16 + (size_t)NTOK * DI_N;              // 2048*2048
  _Float16* W16 = H116 + (size_t)NTOK * DI_N;               // 4352*1024
  _Float16* W2t = W16 + (size_t)NPAD_INPROJ * DM_N;         // 49*64*32
  _Float16* X1h = (_Float16*)YR;

  k_conv1<<<dim3(8, 32, 2), 256, 0, stream>>>(image, conv1_w, bn1, X1h);
  k_w2t<<<(49 * 64 * 32 + 255) / 256, 256, 0, stream>>>(conv2_w, W2t);
  k_conv2m<<<dim3(8, 16, 2), 512, 0, stream>>>(X1h, W2t, bn2, image, ds_w, ds_bn, Tok, Tok16);

  for (int i = 0; i < 4; ++i) {
    const float* Wi = in_proj_w + (size_t)i * DPROJ_N * DM_N;
    const float* cw = conv1d_w + (size_t)i * DCONV_N * 4;
    const float* cb = conv1d_b + (size_t)i * DCONV_N;
    const float* dtb = dt_bias + i * NH_N;
    const float* al = A_log + i * NH_N;
    const float* dd = Dpar + i * NH_N;
    const float* nw = norm_w + i * DI_N;
    const float* Wo = out_proj_w + (size_t)i * DM_N * DI_N;
    const float* bbn = blk_bn + (size_t)i * 4 * DM_N;
    const float* w1 = ff_w1 + (size_t)i * FFH_N * DM_N;
    const float* b1 = ff_b1 + i * FFH_N;
    const float* fbn1 = ff_bn1 + (size_t)i * 4 * FFH_N;
    const float* w2 = ff_w2 + (size_t)i * DM_N * FFH_N;
    const float* b2 = ff_b2 + i * DM_N;
    const float* fbn2 = ff_bn2 + (size_t)i * 4 * DM_N;

    // in_proj: [2048,4256] = Tok16[2048,1024] x Wi^T
    k_tohalf8<<<(NPAD_INPROJ * 1024 / 8 + 255) / 256, 256, 0, stream>>>(
        Wi, W16, DPROJ_N * DM_N, NPAD_INPROJ * DM_N);
    k_mgemm<0, 128><<<dim3(34, 16), 256, 0, stream>>>(
        Tok16, W16, NTOK, DPROJ_N, DM_N, nullptr, nullptr, nullptr, ZX, nullptr);
    k_convprep<<<dim3(NTOK, 9), 256, 0, stream>>>(ZX, cw, cb, dtb, al, XBC, DTb, DLAb);
    k_scan<<<256, 256, 0, stream>>>(XBC, DTb, DLAb, dd, YR);
    k_gatenorm<<<NTOK, 256, 0, stream>>>(YR, ZX, nw, YN16);
    // out_proj: [2048,1024] = YN16[2048,2048] x Wo^T, +bn+res -> Tok/Tok16
    k_tohalf8<<<(DM_N * DI_N / 8 + 255) / 256, 256, 0, stream>>>(
        Wo, W16, DM_N * DI_N, DM_N * DI_N);
    k_mgemm<1, 64><<<dim3(8, 32), 256, 0, stream>>>(
        YN16, W16, NTOK, DM_N, DI_N, nullptr, bbn, Tok, Tok, Tok16);
    // ff1: [2048,2048] = Tok16 x w1^T, +bias+bn+relu -> H116
    k_tohalf8<<<(FFH_N * DM_N / 8 + 255) / 256, 256, 0, stream>>>(
        w1, W16, FFH_N * DM_N, FFH_N * DM_N);
    k_mgemm<2, 128><<<dim3(16, 16), 256, 0, stream>>>(
        Tok16, W16, NTOK, FFH_N, DM_N, b1, fbn1, nullptr, nullptr, H116);
    // ff2: [2048,1024] = H116 x w2^T, +bias+bn+res -> Tok/Tok16
    k_tohalf8<<<(DM_N * FFH_N / 8 + 255) / 256, 256, 0, stream>>>(
        w2, W16, DM_N * FFH_N, DM_N * FFH_N);
    k_mgemm<3, 64><<<dim3(8, 32), 256, 0, stream>>>(
        H116, W16, NTOK, DM_N, FFH_N, b2, fbn2, Tok, Tok, Tok16);
  }
  k_transpose<<<dim3(32, 64), 256, 0, stream>>>(Tok, (float*)d_out);
}

// Round 9
// 850.468 us; speedup vs baseline: 6.0101x; 1.0176x over previous
//
#include <hip/hip_runtime.h>
#include <hip/hip_bf16.h>
#include <hip/hip_fp16.h>
#include <math.h>

#define EPSF 1e-5f
#define B_N 8
#define L_N 256
#define DM_N 1024
#define DI_N 2048
#define DS_N 64
#define NH_N 32
#define HD_N 64
#define DCONV_N 2176
#define DPROJ_N 4256
#define NTOK 2048
#define FFH_N 2048
#define NPAD_INPROJ 4352  // 4256 padded to multiple of 128

typedef _Float16 f16x8 __attribute__((ext_vector_type(8)));
typedef float f32x4 __attribute__((ext_vector_type(4)));

__device__ __forceinline__ float sigf(float x) { return 1.f / (1.f + __expf(-x)); }

__device__ __forceinline__ void gll16(const void* g, void* l) {
  typedef __attribute__((address_space(1))) const void gv;
  typedef __attribute__((address_space(3))) void lv;
  __builtin_amdgcn_global_load_lds((gv*)g, (lv*)l, 16, 0, 0);
}

__device__ __forceinline__ f16x8 cvt8(float4 a, float4 b) {
  f16x8 o;
  o[0] = (_Float16)a.x; o[1] = (_Float16)a.y; o[2] = (_Float16)a.z; o[3] = (_Float16)a.w;
  o[4] = (_Float16)b.x; o[5] = (_Float16)b.y; o[6] = (_Float16)b.z; o[7] = (_Float16)b.w;
  return o;
}

// ---------------- fp32 -> fp16 converter (8 elems/thread), zero-pads to ntot ----------------
__global__ __launch_bounds__(256) void k_tohalf8(
    const float* __restrict__ src, _Float16* __restrict__ dst, int n, int ntot) {
  int i = (blockIdx.x * 256 + threadIdx.x) * 8;
  if (i >= ntot) return;
  f16x8 o;
  if (i < n) {
    float4 a = *(const float4*)(src + i);
    float4 b = *(const float4*)(src + i + 4);
    o = cvt8(a, b);
  } else {
#pragma unroll
    for (int j = 0; j < 8; ++j) o[j] = (_Float16)0.f;
  }
  *(f16x8*)(dst + i) = o;
}

// ---- conv1 weights: w[32][49] fp32 -> W1t[32][64] fp16, K zero-padded ----
__global__ __launch_bounds__(256) void k_w1t(
    const float* __restrict__ w1, _Float16* __restrict__ W1t) {
  int i = blockIdx.x * 256 + threadIdx.x;
  if (i >= 32 * 64) return;
  int co = i >> 6, k = i & 63;
  W1t[i] = (k < 49) ? (_Float16)w1[co * 49 + k] : (_Float16)0.f;
}

// ---- conv1 as MFMA implicit GEMM: M=pixels(131072), N=co(32), K=49->64 ----
// grid (b=8, y=32, xtile=4); 256 thr (4 waves). Tile: 128 x-pixels x 32 co. Fused bn1.
__global__ __launch_bounds__(256) void k_conv1m(
    const float* __restrict__ img, const _Float16* __restrict__ W1t,
    const float* __restrict__ bnp, _Float16* __restrict__ X1h) {
  __shared__ float sIn[7][264];     // x-window [2*x0-3 .. +262)
  __shared__ _Float16 sA[128][72];  // im2col rows, 144B stride
  __shared__ _Float16 sB[32][72];
  int b = blockIdx.x, y = blockIdx.y, x0 = blockIdx.z * 128;
  int t = threadIdx.x;
  {  // stage B: 32 rows x 64 k = 256 chunks of 8
    int r = t >> 3, c = (t & 7) * 8;
    *(f16x8*)&sB[r][c] = *(const f16x8*)&W1t[r * 64 + c];
  }
  const float* ip = img + (size_t)b * 64 * 1024;
#pragma unroll
  for (int r = 0; r < 7; ++r) {
    int yy = 2 * y - 3 + r;
    for (int c = t; c < 262; c += 256) {
      int xx = 2 * x0 - 3 + c;
      float v = 0.f;
      if (yy >= 0 && yy < 64 && xx >= 0 && xx < 1024) v = ip[yy * 1024 + xx];
      sIn[r][c] = v;
    }
  }
  __syncthreads();
  {  // im2col: thread -> (pixel p = t>>1, k-half = t&1)
    int p = t >> 1, half = t & 1;
    _Float16 av[32];
    if (half == 0) {
#pragma unroll
      for (int k = 0; k < 32; ++k)
        av[k] = (_Float16)sIn[k / 7][2 * p + (k % 7)];
    } else {
#pragma unroll
      for (int k = 32; k < 64; ++k)
        av[k - 32] = (k < 49) ? (_Float16)sIn[k / 7][2 * p + (k % 7)] : (_Float16)0.f;
    }
    *(f16x8*)&sA[p][half * 32 + 0] = *(f16x8*)&av[0];
    *(f16x8*)&sA[p][half * 32 + 8] = *(f16x8*)&av[8];
    *(f16x8*)&sA[p][half * 32 + 16] = *(f16x8*)&av[16];
    *(f16x8*)&sA[p][half * 32 + 24] = *(f16x8*)&av[24];
  }
  __syncthreads();
  int w = t >> 6, lane = t & 63, lr = lane & 15, kh = lane >> 4;
  f32x4 acc[2][2];
#pragma unroll
  for (int i = 0; i < 2; ++i)
#pragma unroll
    for (int j = 0; j < 2; ++j) acc[i][j] = (f32x4)(0.f);
#pragma unroll
  for (int ks = 0; ks < 2; ++ks) {
    f16x8 af[2], bf[2];
#pragma unroll
    for (int i = 0; i < 2; ++i)
      af[i] = *(const f16x8*)&sA[w * 32 + i * 16 + lr][ks * 32 + kh * 8];
#pragma unroll
    for (int j = 0; j < 2; ++j)
      bf[j] = *(const f16x8*)&sB[j * 16 + lr][ks * 32 + kh * 8];
#pragma unroll
    for (int i = 0; i < 2; ++i)
#pragma unroll
      for (int j = 0; j < 2; ++j)
        acc[i][j] = __builtin_amdgcn_mfma_f32_16x16x32_f16(af[i], bf[j], acc[i][j], 0, 0, 0);
  }
#pragma unroll
  for (int j = 0; j < 2; ++j) {
    int co = j * 16 + lr;
    float g = bnp[co], be = bnp[32 + co], mm = bnp[64 + co], vv = bnp[96 + co];
    float sc = rsqrtf(vv + EPSF) * g, sh = be - mm * sc;
#pragma unroll
    for (int i = 0; i < 2; ++i) {
#pragma unroll
      for (int rr = 0; rr < 4; ++rr) {
        int pix = w * 32 + i * 16 + kh * 4 + rr;
        int x = x0 + pix;
        X1h[((size_t)(b * 32 + y) * 512 + x) * 32 + co] =
            (_Float16)fmaf(acc[i][j][rr], sc, sh);
      }
    }
  }
}

// ---- w2[co][ci][r][s] -> W2t[rs][co][ci] fp16 ----
__global__ __launch_bounds__(256) void k_w2t(
    const float* __restrict__ w2, _Float16* __restrict__ W2t) {
  int i = blockIdx.x * 256 + threadIdx.x;
  if (i >= 49 * 64 * 32) return;
  int ci = i & 31, co = (i >> 5) & 63, rs = i >> 11;
  W2t[rs * 2048 + co * 32 + ci] = (_Float16)w2[co * 1568 + ci * 49 + rs];
}

// ---- conv2 as MFMA implicit GEMM: M=(b,ho,wo)=32768, N=co=64, K=(rs,ci)=49x32 ----
__global__ __launch_bounds__(512) void k_conv2m(
    const _Float16* __restrict__ X1h, const _Float16* __restrict__ W2t,
    const float* __restrict__ bn2p, const float* __restrict__ img,
    const float* __restrict__ dsw, const float* __restrict__ dsbnp,
    float* __restrict__ Tok, _Float16* __restrict__ Tok16) {
  __shared__ _Float16 As[2][128 * 40];  // 80B row stride: 2-way bank alias only
  __shared__ _Float16 Bs[2][64 * 40];
  int b = blockIdx.x, ho = blockIdx.y, wo0 = blockIdx.z * 128;
  int t = threadIdx.x;
  int w = t >> 6, lane = t & 63;
  int lr = lane & 15, kh = lane >> 4;
  int wm = w >> 1, wn = w & 1;
  f32x4 acc[2][2];
#pragma unroll
  for (int i = 0; i < 2; ++i)
#pragma unroll
    for (int j = 0; j < 2; ++j) acc[i][j] = (f32x4)(0.f);

  int arow = t >> 2, achk = t & 3;
  const _Float16* xb = X1h + (size_t)b * 32 * 512 * 32;

  auto LOADA = [&](int rs, f16x8& ra) {
    int r = rs / 7, s = rs - 7 * r;
    int y = 2 * ho + r - 3;
    int xx = 2 * (wo0 + arow) + s - 3;
    if (y >= 0 && y < 32 && xx >= 0 && xx < 512)
      ra = *(const f16x8*)(xb + ((size_t)(y * 512 + xx)) * 32 + achk * 8);
    else
      ra = (f16x8)(_Float16)0.f;
  };

  f16x8 ra, rb;
  LOADA(0, ra);
  if (t < 256) rb = *(const f16x8*)(W2t + (t >> 2) * 32 + (t & 3) * 8);
  *(f16x8*)&As[0][arow * 40 + achk * 8] = ra;
  if (t < 256) *(f16x8*)&Bs[0][(t >> 2) * 40 + (t & 3) * 8] = rb;
  __syncthreads();

  int cur = 0;
  for (int rs = 0; rs < 49; ++rs) {
    f16x8 na, nb;
    if (rs + 1 < 49) {
      LOADA(rs + 1, na);
      if (t < 256)
        nb = *(const f16x8*)(W2t + (rs + 1) * 2048 + (t >> 2) * 32 + (t & 3) * 8);
    }
    f16x8 af[2], bf[2];
#pragma unroll
    for (int i = 0; i < 2; ++i)
      af[i] = *(const f16x8*)&As[cur][(wm * 32 + i * 16 + lr) * 40 + kh * 8];
#pragma unroll
    for (int j = 0; j < 2; ++j)
      bf[j] = *(const f16x8*)&Bs[cur][(wn * 32 + j * 16 + lr) * 40 + kh * 8];
#pragma unroll
    for (int i = 0; i < 2; ++i)
#pragma unroll
      for (int j = 0; j < 2; ++j)
        acc[i][j] = __builtin_amdgcn_mfma_f32_16x16x32_f16(af[i], bf[j], acc[i][j], 0, 0, 0);
    if (rs + 1 < 49) {
      *(f16x8*)&As[cur ^ 1][arow * 40 + achk * 8] = na;
      if (t < 256) *(f16x8*)&Bs[cur ^ 1][(t >> 2) * 40 + (t & 3) * 8] = nb;
      __syncthreads();
      cur ^= 1;
    }
  }

#pragma unroll
  for (int j = 0; j < 2; ++j) {
    int co = wn * 32 + j * 16 + lr;
    float g = bn2p[co], be = bn2p[64 + co], mm = bn2p[128 + co], vv = bn2p[192 + co];
    float sc = rsqrtf(vv + EPSF) * g, sh = be - mm * sc;
    float dg = dsbnp[co], dbe = dsbnp[64 + co], dmm = dsbnp[128 + co], dvv = dsbnp[192 + co];
    float dsc = rsqrtf(dvv + EPSF) * dg, dsh = dbe - dmm * dsc;
    float wv = dsw[co];
#pragma unroll
    for (int i = 0; i < 2; ++i) {
#pragma unroll
      for (int rr = 0; rr < 4; ++rr) {
        int row = wm * 32 + i * 16 + kh * 4 + rr;
        int wo = wo0 + row;
        float dval = fmaf(img[((size_t)(b * 64 + 4 * ho)) * 1024 + 4 * wo] * wv, dsc, dsh);
        float v = fmaf(acc[i][j][rr], sc, sh) + dval;
        v = v > 0.f ? v : 0.f;
        size_t o = ((size_t)(b * 256 + wo)) * DM_N + co * 16 + ho;
        Tok[o] = v;
        Tok16[o] = (_Float16)v;
      }
    }
  }
}

// ---------------- MFMA fp16 GEMM: C[M,N] = A[M,K] * W[N,K]^T + fused epilogue ----------------
template <int MODE, int BM>
__global__ __launch_bounds__(256) void k_mgemm(
    const _Float16* __restrict__ A, const _Float16* __restrict__ W,
    int M, int N, int K,
    const float* __restrict__ bias, const float* __restrict__ bnp,
    const float* __restrict__ res, float* __restrict__ C32,
    _Float16* __restrict__ C16) {
  constexpr int MI = BM / 32;  // A-frags per wave
  __shared__ _Float16 As[2][BM * 32];
  __shared__ _Float16 Bs[2][128 * 32];
  const int t = threadIdx.x;
  const int w = t >> 6, lane = t & 63;
  const int lr = lane & 15, kh = lane >> 4;
  const int wm = w >> 1, wn = w & 1;
  const int m0 = blockIdx.y * BM, n0 = blockIdx.x * 128;
  f32x4 acc[MI][4];
#pragma unroll
  for (int i = 0; i < MI; ++i)
#pragma unroll
    for (int j = 0; j < 4; ++j) acc[i][j] = (f32x4)(0.f);

  const int nt = K >> 5;
  auto STAGE = [&](int bb, int kt) {
    const int k0 = kt << 5;
#pragma unroll
    for (int it = 0; it < BM / 64; ++it) {
      int c = it * 256 + w * 64 + lane;
      int row = c >> 2, kq = c & 3;
      gll16(A + (size_t)(m0 + row) * K + k0 + kq * 8,
            &As[bb][(size_t)(it * 256 + w * 64) * 8]);
    }
#pragma unroll
    for (int it = 0; it < 2; ++it) {
      int c = it * 256 + w * 64 + lane;
      int row = c >> 2, kq = c & 3;
      gll16(W + (size_t)(n0 + row) * K + k0 + kq * 8,
            &Bs[bb][(size_t)(it * 256 + w * 64) * 8]);
    }
  };

  STAGE(0, 0);
  __syncthreads();
  int bb = 0;
  for (int kt = 0; kt < nt; ++kt) {
    if (kt + 1 < nt) STAGE(bb ^ 1, kt + 1);
    f16x8 af[MI], bf[4];
#pragma unroll
    for (int i = 0; i < MI; ++i)
      af[i] = *(const f16x8*)&As[bb][(size_t)((wm * (BM / 2) + i * 16 + lr) * 32 + kh * 8)];
#pragma unroll
    for (int j = 0; j < 4; ++j)
      bf[j] = *(const f16x8*)&Bs[bb][(size_t)((wn * 64 + j * 16 + lr) * 32 + kh * 8)];
#pragma unroll
    for (int i = 0; i < MI; ++i)
#pragma unroll
      for (int j = 0; j < 4; ++j)
        acc[i][j] = __builtin_amdgcn_mfma_f32_16x16x32_f16(af[i], bf[j], acc[i][j], 0, 0, 0);
    __syncthreads();
    bb ^= 1;
  }

#pragma unroll
  for (int j = 0; j < 4; ++j) {
    int cn = n0 + wn * 64 + j * 16 + lr;
    if (cn >= N) continue;
    float g = 1.f, be = 0.f, sc = 1.f, sh = 0.f, bs = 0.f;
    if (MODE >= 1) {
      g = bnp[cn]; be = bnp[N + cn];
      float mm = bnp[2 * N + cn], vv = bnp[3 * N + cn];
      sc = rsqrtf(vv + EPSF) * g;
      sh = be - mm * sc;
    }
    if (MODE == 2 || MODE == 3) bs = bias[cn];
#pragma unroll
    for (int i = 0; i < MI; ++i) {
#pragma unroll
      for (int rr = 0; rr < 4; ++rr) {
        int r = m0 + wm * (BM / 2) + i * 16 + kh * 4 + rr;
        float v = acc[i][j][rr];
        if (MODE == 2 || MODE == 3) v += bs;
        if (MODE >= 1) v = fmaf(v, sc, sh);
        if (MODE == 2) v = v > 0.f ? v : 0.f;
        if (MODE == 1 || MODE == 3) v += res[(size_t)r * N + cn];
        size_t o = (size_t)r * N + cn;
        if (MODE != 2) C32[o] = v;
        if (MODE >= 1) C16[o] = (_Float16)v;
      }
    }
  }
}

// ------- causal depthwise conv1d + silu on xBC; softplus dt; LOG-decay -------
__global__ __launch_bounds__(256) void k_convprep(
    const float* __restrict__ ZX, const float* __restrict__ cw,
    const float* __restrict__ cb, const float* __restrict__ dtb,
    const float* __restrict__ Alog, float* __restrict__ XBC,
    float* __restrict__ DT, float* __restrict__ DLA) {
  int m = blockIdx.x;
  int c = blockIdx.y * 256 + threadIdx.x;
  int l = m & 255;
  if (c < DCONV_N) {
    const float* cwp = cw + c * 4;
    float acc = cb[c];
#pragma unroll
    for (int k = 0; k < 4; ++k) {
      int dl = l + k - 3;
      if (dl >= 0)
        acc = fmaf(ZX[(size_t)(m + k - 3) * DPROJ_N + DI_N + c], cwp[k], acc);
    }
    XBC[(size_t)m * DCONV_N + c] = acc * sigf(acc);
  } else if (c < DCONV_N + NH_N) {
    int h = c - DCONV_N;
    float xx = ZX[(size_t)m * DPROJ_N + DI_N + DCONV_N + h] + dtb[h];
    float dt = xx > 20.f ? xx : log1pf(__expf(xx));
    DT[m * NH_N + h] = dt;
    DLA[m * NH_N + h] = -dt * __expf(Alog[h]);  // log(dA), always finite, <= 0
  }
}

// ------- selective scan v3: Mamba2 SSD chunked, MFMA. grid 256=(b,h), 256 thr (4 waves) -------
__global__ __launch_bounds__(256) void k_scan(
    const float* __restrict__ XBC, const float* __restrict__ DT,
    const float* __restrict__ DLA, const float* __restrict__ Dp,
    float* __restrict__ Y) {
  __shared__ _Float16 sC[64][72];    // C[l][n]
  __shared__ _Float16 sB[64][72];    // B[l][n]
  __shared__ _Float16 sBts[64][72];  // [n][j] = B[j][n]*es[j]
  __shared__ _Float16 sXt[64][72];   // [p][l] = dt[l]*x[l][p]
  __shared__ _Float16 sP[64][72];    // P[l][j]
  __shared__ _Float16 sH[64][72];    // h[p][n] fp16 mirror
  __shared__ float sH32[64][68];     // h[p][n] fp32 master
  __shared__ float sS[64], sEl[64], sEs[64], sDt[64];
  __shared__ float sCpt;

  const int b = blockIdx.x >> 5, h = blockIdx.x & 31;
  const int t = threadIdx.x;
  const int w = t >> 6, lane = t & 63;
  const int lr = lane & 15, kh = lane >> 4;
  const float Dh = Dp[h];

  {  // zero h
    _Float16* hp = &sH[0][0];
    float* h32p = &sH32[0][0];
    for (int i = t; i < 64 * 72; i += 256) hp[i] = (_Float16)0.f;
    for (int i = t; i < 64 * 68; i += 256) h32p[i] = 0.f;
  }

  for (int c = 0; c < 4; ++c) {
    const int mbase = b * L_N + c * 64;
    __syncthreads();  // A: protect LDS reuse across chunks (incl. h16 writes)

    if (t < 64) {  // B: segsum in wave 0
      int l = t;
      float v = DLA[(mbase + l) * NH_N + h];
#pragma unroll
      for (int o = 1; o < 64; o <<= 1) {
        float u = __shfl_up(v, o);
        v += (l >= o) ? u : 0.f;
      }
      sS[l] = v;
      sEl[l] = __expf(v);
      float s63 = __shfl(v, 63);
      sEs[l] = __expf(s63 - v);
      if (l == 63) sCpt = __expf(s63);
      sDt[l] = DT[(mbase + l) * NH_N + h];
    }
    __syncthreads();  // B -> C

    {  // C: build tiles. thread = (row l = t>>2, col quarter q = t&3)
      int l = t >> 2, q = t & 3;
      const float* row = XBC + (size_t)(mbase + l) * DCONV_N;
      float dt_l = sDt[l], es_l = sEs[l];
      // B
      float4 b0 = *(const float4*)&row[DI_N + q * 16];
      float4 b1 = *(const float4*)&row[DI_N + q * 16 + 4];
      float4 b2 = *(const float4*)&row[DI_N + q * 16 + 8];
      float4 b3 = *(const float4*)&row[DI_N + q * 16 + 12];
      *(f16x8*)&sB[l][q * 16] = cvt8(b0, b1);
      *(f16x8*)&sB[l][q * 16 + 8] = cvt8(b2, b3);
      float bv[16] = {b0.x, b0.y, b0.z, b0.w, b1.x, b1.y, b1.z, b1.w,
                      b2.x, b2.y, b2.z, b2.w, b3.x, b3.y, b3.z, b3.w};
#pragma unroll
      for (int i = 0; i < 16; ++i) sBts[q * 16 + i][l] = (_Float16)(bv[i] * es_l);
      // C
      float4 c0 = *(const float4*)&row[DI_N + DS_N + q * 16];
      float4 c1 = *(const float4*)&row[DI_N + DS_N + q * 16 + 4];
      float4 c2 = *(const float4*)&row[DI_N + DS_N + q * 16 + 8];
      float4 c3 = *(const float4*)&row[DI_N + DS_N + q * 16 + 12];
      *(f16x8*)&sC[l][q * 16] = cvt8(c0, c1);
      *(f16x8*)&sC[l][q * 16 + 8] = cvt8(c2, c3);
      // x -> Xd^T
      float4 x0 = *(const float4*)&row[h * HD_N + q * 16];
      float4 x1 = *(const float4*)&row[h * HD_N + q * 16 + 4];
      float4 x2 = *(const float4*)&row[h * HD_N + q * 16 + 8];
      float4 x3 = *(const float4*)&row[h * HD_N + q * 16 + 12];
      float xv[16] = {x0.x, x0.y, x0.z, x0.w, x1.x, x1.y, x1.z, x1.w,
                      x2.x, x2.y, x2.z, x2.w, x3.x, x3.y, x3.z, x3.w};
#pragma unroll
      for (int i = 0; i < 16; ++i) sXt[q * 16 + i][l] = (_Float16)(xv[i] * dt_l);
    }
    __syncthreads();  // C -> D

    // D: S = C@B^T ; Yinter = C@h^T
    f32x4 Sacc[4], Yacc[4];
#pragma unroll
    for (int j = 0; j < 4; ++j) { Sacc[j] = (f32x4)(0.f); Yacc[j] = (f32x4)(0.f); }
    {
      f16x8 aC[2];
#pragma unroll
      for (int kk = 0; kk < 2; ++kk)
        aC[kk] = *(const f16x8*)&sC[16 * w + lr][kk * 32 + kh * 8];
#pragma unroll
      for (int kk = 0; kk < 2; ++kk)
#pragma unroll
        for (int jt = 0; jt < 4; ++jt) {
          f16x8 bB = *(const f16x8*)&sB[jt * 16 + lr][kk * 32 + kh * 8];
          f16x8 bH = *(const f16x8*)&sH[jt * 16 + lr][kk * 32 + kh * 8];
          Sacc[jt] = __builtin_amdgcn_mfma_f32_16x16x32_f16(aC[kk], bB, Sacc[jt], 0, 0, 0);
          Yacc[jt] = __builtin_amdgcn_mfma_f32_16x16x32_f16(aC[kk], bH, Yacc[jt], 0, 0, 0);
        }
    }

    // E: mask P, scale Yinter rows by el
#pragma unroll
    for (int rr = 0; rr < 4; ++rr) {
      int l = 16 * w + kh * 4 + rr;
      float sl = sS[l], el = sEl[l];
#pragma unroll
      for (int jt = 0; jt < 4; ++jt) {
        int j = jt * 16 + lr;
        float pv = (j <= l) ? Sacc[jt][rr] * __expf(sl - sS[j]) : 0.f;
        sP[l][j] = (_Float16)pv;
        Yacc[jt][rr] *= el;
      }
    }
    __syncthreads();  // E -> F

    // F: Y += P@Xd^T ; Hacc = Xd^T-rows @ Bts^T
    f32x4 Hacc[4];
#pragma unroll
    for (int j = 0; j < 4; ++j) Hacc[j] = (f32x4)(0.f);
    {
      f16x8 aP[2], aX[2];
#pragma unroll
      for (int kk = 0; kk < 2; ++kk) {
        aP[kk] = *(const f16x8*)&sP[16 * w + lr][kk * 32 + kh * 8];
        aX[kk] = *(const f16x8*)&sXt[16 * w + lr][kk * 32 + kh * 8];
      }
#pragma unroll
      for (int kk = 0; kk < 2; ++kk)
#pragma unroll
        for (int jt = 0; jt < 4; ++jt) {
          f16x8 bX = *(const f16x8*)&sXt[jt * 16 + lr][kk * 32 + kh * 8];
          f16x8 bBt = *(const f16x8*)&sBts[jt * 16 + lr][kk * 32 + kh * 8];
          Yacc[jt] = __builtin_amdgcn_mfma_f32_16x16x32_f16(aP[kk], bX, Yacc[jt], 0, 0, 0);
          Hacc[jt] = __builtin_amdgcn_mfma_f32_16x16x32_f16(aX[kk], bBt, Hacc[jt], 0, 0, 0);
        }
    }

    // G: epilogue — Y out (+D skip), h update
    float cpt = sCpt;
#pragma unroll
    for (int rr = 0; rr < 4; ++rr) {
      int lrow = 16 * w + kh * 4 + rr;
      int m = mbase + lrow;
#pragma unroll
      for (int jt = 0; jt < 4; ++jt) {
        int p = jt * 16 + lr;
        float xr = XBC[(size_t)m * DCONV_N + h * HD_N + p];
        Y[(size_t)m * DI_N + h * HD_N + p] = fmaf(Dh, xr, Yacc[jt][rr]);
        float hv = fmaf(cpt, sH32[lrow][jt * 16 + lr], Hacc[jt][rr]);
        sH32[lrow][jt * 16 + lr] = hv;
        sH[lrow][jt * 16 + lr] = (_Float16)hv;
      }
    }
  }
}

// ------- gate with silu(z) + RMSNorm (over DI) -> fp16 -------
__global__ __launch_bounds__(256) void k_gatenorm(
    const float* __restrict__ Y, const float* __restrict__ ZX,
    const float* __restrict__ nw, _Float16* __restrict__ YN16) {
  int m = blockIdx.x, t = threadIdx.x;
  const float* y = Y + (size_t)m * DI_N;
  const float* z = ZX + (size_t)m * DPROJ_N;
  float vals[8];
  float ss = 0.f;
#pragma unroll
  for (int j = 0; j < 8; ++j) {
    int c = t + 256 * j;
    float zz = z[c];
    float vv = y[c] * zz * sigf(zz);
    vals[j] = vv;
    ss = fmaf(vv, vv, ss);
  }
#pragma unroll
  for (int o = 1; o < 64; o <<= 1) ss += __shfl_xor(ss, o);
  __shared__ float sred[4];
  if ((t & 63) == 0) sred[t >> 6] = ss;
  __syncthreads();
  float tot = sred[0] + sred[1] + sred[2] + sred[3];
  float scale = rsqrtf(tot * (1.f / DI_N) + EPSF);
#pragma unroll
  for (int j = 0; j < 8; ++j) {
    int c = t + 256 * j;
    YN16[(size_t)m * DI_N + c] = (_Float16)(vals[j] * scale * nw[c]);
  }
}

// ------- final transpose: Tok[m][d] -> out[b][d][l] -------
__global__ __launch_bounds__(256) void k_transpose(
    const float* __restrict__ Tok, float* __restrict__ out) {
  __shared__ float tile[32][33];
  int d0 = blockIdx.x * 32, m0 = blockIdx.y * 32;
  int tx = threadIdx.x & 31, ty = threadIdx.x >> 5;
  for (int i = ty; i < 32; i += 8)
    tile[i][tx] = Tok[(size_t)(m0 + i) * DM_N + d0 + tx];
  __syncthreads();
  int b = m0 >> 8, l0 = m0 & 255;
  for (int i = ty; i < 32; i += 8)
    out[((size_t)b * DM_N + d0 + i) * L_N + l0 + tx] = tile[tx][i];
}

extern "C" void kernel_launch(void* const* d_in, const int* in_sizes, int n_in,
                              void* d_out, int out_size, void* d_ws, size_t ws_size,
                              hipStream_t stream) {
  const float* image = (const float*)d_in[0];
  const float* conv1_w = (const float*)d_in[1];
  const float* bn1 = (const float*)d_in[2];
  const float* conv2_w = (const float*)d_in[3];
  const float* bn2 = (const float*)d_in[4];
  const float* ds_w = (const float*)d_in[5];
  const float* ds_bn = (const float*)d_in[6];
  const float* in_proj_w = (const float*)d_in[7];
  const float* conv1d_w = (const float*)d_in[8];
  const float* conv1d_b = (const float*)d_in[9];
  const float* dt_bias = (const float*)d_in[10];
  const float* A_log = (const float*)d_in[11];
  const float* Dpar = (const float*)d_in[12];
  const float* norm_w = (const float*)d_in[13];
  const float* out_proj_w = (const float*)d_in[14];
  const float* blk_bn = (const float*)d_in[15];
  const float* ff_w1 = (const float*)d_in[16];
  const float* ff_b1 = (const float*)d_in[17];
  const float* ff_bn1 = (const float*)d_in[18];
  const float* ff_w2 = (const float*)d_in[19];
  const float* ff_b2 = (const float*)d_in[20];
  const float* ff_bn2 = (const float*)d_in[21];

  // workspace layout: fp32 region then fp16 region (~108 MB total)
  float* ws = (float*)d_ws;
  float* Tok = ws;                        // 2048*1024
  float* ZX = Tok + (size_t)NTOK * DM_N;  // 2048*4256
  float* XBC = ZX + (size_t)NTOK * DPROJ_N;
  float* DTb = XBC + (size_t)NTOK * DCONV_N;
  float* DLAb = DTb + (size_t)NTOK * NH_N;
  float* YR = DLAb + (size_t)NTOK * NH_N;  // 2048*2048; stem X1h aliases this
  _Float16* Tok16 = (_Float16*)(YR + (size_t)NTOK * DI_N);  // 2048*1024
  _Float16* YN16 = Tok16 + (size_t)NTOK * DM_N;             // 2048*2048
  _Float16* H116 = YN16 + (size_t)NTOK * DI_N;              // 2048*2048
  _Float16* W16 = H116 + (size_t)NTOK * DI_N;               // 4352*1024
  _Float16* W2t = W16 + (size_t)NPAD_INPROJ * DM_N;         // 49*64*32
  _Float16* W1t = W2t + (size_t)49 * 64 * 32;               // 32*64
  _Float16* X1h = (_Float16*)YR;

  k_w1t<<<8, 256, 0, stream>>>(conv1_w, W1t);
  k_conv1m<<<dim3(8, 32, 4), 256, 0, stream>>>(image, W1t, bn1, X1h);
  k_w2t<<<(49 * 64 * 32 + 255) / 256, 256, 0, stream>>>(conv2_w, W2t);
  k_conv2m<<<dim3(8, 16, 2), 512, 0, stream>>>(X1h, W2t, bn2, image, ds_w, ds_bn, Tok, Tok16);

  for (int i = 0; i < 4; ++i) {
    const float* Wi = in_proj_w + (size_t)i * DPROJ_N * DM_N;
    const float* cw = conv1d_w + (size_t)i * DCONV_N * 4;
    const float* cb = conv1d_b + (size_t)i * DCONV_N;
    const float* dtb = dt_bias + i * NH_N;
    const float* al = A_log + i * NH_N;
    const float* dd = Dpar + i * NH_N;
    const float* nw = norm_w + i * DI_N;
    const float* Wo = out_proj_w + (size_t)i * DM_N * DI_N;
    const float* bbn = blk_bn + (size_t)i * 4 * DM_N;
    const float* w1 = ff_w1 + (size_t)i * FFH_N * DM_N;
    const float* b1 = ff_b1 + i * FFH_N;
    const float* fbn1 = ff_bn1 + (size_t)i * 4 * FFH_N;
    const float* w2 = ff_w2 + (size_t)i * DM_N * FFH_N;
    const float* b2 = ff_b2 + i * DM_N;
    const float* fbn2 = ff_bn2 + (size_t)i * 4 * DM_N;

    // in_proj: [2048,4256] = Tok16[2048,1024] x Wi^T
    k_tohalf8<<<(NPAD_INPROJ * 1024 / 8 + 255) / 256, 256, 0, stream>>>(
        Wi, W16, DPROJ_N * DM_N, NPAD_INPROJ * DM_N);
    k_mgemm<0, 128><<<dim3(34, 16), 256, 0, stream>>>(
        Tok16, W16, NTOK, DPROJ_N, DM_N, nullptr, nullptr, nullptr, ZX, nullptr);
    k_convprep<<<dim3(NTOK, 9), 256, 0, stream>>>(ZX, cw, cb, dtb, al, XBC, DTb, DLAb);
    k_scan<<<256, 256, 0, stream>>>(XBC, DTb, DLAb, dd, YR);
    k_gatenorm<<<NTOK, 256, 0, stream>>>(YR, ZX, nw, YN16);
    // out_proj: [2048,1024] = YN16[2048,2048] x Wo^T, +bn+res -> Tok/Tok16
    k_tohalf8<<<(DM_N * DI_N / 8 + 255) / 256, 256, 0, stream>>>(
        Wo, W16, DM_N * DI_N, DM_N * DI_N);
    k_mgemm<1, 64><<<dim3(8, 32), 256, 0, stream>>>(
        YN16, W16, NTOK, DM_N, DI_N, nullptr, bbn, Tok, Tok, Tok16);
    // ff1: [2048,2048] = Tok16 x w1^T, +bias+bn+relu -> H116
    k_tohalf8<<<(FFH_N * DM_N / 8 + 255) / 256, 256, 0, stream>>>(
        w1, W16, FFH_N * DM_N, FFH_N * DM_N);
    k_mgemm<2, 128><<<dim3(16, 16), 256, 0, stream>>>(
        Tok16, W16, NTOK, FFH_N, DM_N, b1, fbn1, nullptr, nullptr, H116);
    // ff2: [2048,1024] = H116 x w2^T, +bias+bn+res -> Tok/Tok16
    k_tohalf8<<<(DM_N * FFH_N / 8 + 255) / 256, 256, 0, stream>>>(
        w2, W16, DM_N * FFH_N, DM_N * FFH_N);
    k_mgemm<3, 64><<<dim3(8, 32), 256, 0, stream>>>(
        H116, W16, NTOK, DM_N, FFH_N, b2, fbn2, Tok, Tok, Tok16);
  }
  k_transpose<<<dim3(32, 64), 256, 0, stream>>>(Tok, (float*)d_out);
}

// Round 10
// 754.136 us; speedup vs baseline: 6.7778x; 1.1277x over previous
//
#include <hip/hip_runtime.h>
#include <hip/hip_bf16.h>
#include <hip/hip_fp16.h>
#include <math.h>

#define EPSF 1e-5f
#define B_N 8
#define L_N 256
#define DM_N 1024
#define DI_N 2048
#define DS_N 64
#define NH_N 32
#define HD_N 64
#define DCONV_N 2176
#define DPROJ_N 4256
#define NTOK 2048
#define FFH_N 2048
#define NPAD_INPROJ 4352  // 4256 padded to multiple of 128

typedef _Float16 f16x8 __attribute__((ext_vector_type(8)));
typedef float f32x4 __attribute__((ext_vector_type(4)));

__device__ __forceinline__ float sigf(float x) { return 1.f / (1.f + __expf(-x)); }

__device__ __forceinline__ void gll16(const void* g, void* l) {
  typedef __attribute__((address_space(1))) const void gv;
  typedef __attribute__((address_space(3))) void lv;
  __builtin_amdgcn_global_load_lds((gv*)g, (lv*)l, 16, 0, 0);
}

__device__ __forceinline__ f16x8 cvt8(float4 a, float4 b) {
  f16x8 o;
  o[0] = (_Float16)a.x; o[1] = (_Float16)a.y; o[2] = (_Float16)a.z; o[3] = (_Float16)a.w;
  o[4] = (_Float16)b.x; o[5] = (_Float16)b.y; o[6] = (_Float16)b.z; o[7] = (_Float16)b.w;
  return o;
}

// ---------------- fp32 -> fp16 converter (8 elems/thread), zero-pads to ntot ----------------
__global__ __launch_bounds__(256) void k_tohalf8(
    const float* __restrict__ src, _Float16* __restrict__ dst, int n, int ntot) {
  int i = (blockIdx.x * 256 + threadIdx.x) * 8;
  if (i >= ntot) return;
  f16x8 o;
  if (i < n) {
    float4 a = *(const float4*)(src + i);
    float4 b = *(const float4*)(src + i + 4);
    o = cvt8(a, b);
  } else {
#pragma unroll
    for (int j = 0; j < 8; ++j) o[j] = (_Float16)0.f;
  }
  *(f16x8*)(dst + i) = o;
}

// ---- conv1 weights: w[32][49] fp32 -> W1t[32][64] fp16, K zero-padded ----
__global__ __launch_bounds__(256) void k_w1t(
    const float* __restrict__ w1, _Float16* __restrict__ W1t) {
  int i = blockIdx.x * 256 + threadIdx.x;
  if (i >= 32 * 64) return;
  int co = i >> 6, k = i & 63;
  W1t[i] = (k < 49) ? (_Float16)w1[co * 49 + k] : (_Float16)0.f;
}

// ---- conv1 as MFMA implicit GEMM: M=pixels(131072), N=co(32), K=49->64 ----
__global__ __launch_bounds__(256) void k_conv1m(
    const float* __restrict__ img, const _Float16* __restrict__ W1t,
    const float* __restrict__ bnp, _Float16* __restrict__ X1h) {
  __shared__ float sIn[7][264];     // x-window [2*x0-3 .. +262)
  __shared__ _Float16 sA[128][72];  // im2col rows, 144B stride
  __shared__ _Float16 sB[32][72];
  int b = blockIdx.x, y = blockIdx.y, x0 = blockIdx.z * 128;
  int t = threadIdx.x;
  {  // stage B: 32 rows x 64 k = 256 chunks of 8
    int r = t >> 3, c = (t & 7) * 8;
    *(f16x8*)&sB[r][c] = *(const f16x8*)&W1t[r * 64 + c];
  }
  const float* ip = img + (size_t)b * 64 * 1024;
#pragma unroll
  for (int r = 0; r < 7; ++r) {
    int yy = 2 * y - 3 + r;
    for (int c = t; c < 262; c += 256) {
      int xx = 2 * x0 - 3 + c;
      float v = 0.f;
      if (yy >= 0 && yy < 64 && xx >= 0 && xx < 1024) v = ip[yy * 1024 + xx];
      sIn[r][c] = v;
    }
  }
  __syncthreads();
  {  // im2col: thread -> (pixel p = t>>1, k-half = t&1)
    int p = t >> 1, half = t & 1;
    _Float16 av[32];
    if (half == 0) {
#pragma unroll
      for (int k = 0; k < 32; ++k)
        av[k] = (_Float16)sIn[k / 7][2 * p + (k % 7)];
    } else {
#pragma unroll
      for (int k = 32; k < 64; ++k)
        av[k - 32] = (k < 49) ? (_Float16)sIn[k / 7][2 * p + (k % 7)] : (_Float16)0.f;
    }
    *(f16x8*)&sA[p][half * 32 + 0] = *(f16x8*)&av[0];
    *(f16x8*)&sA[p][half * 32 + 8] = *(f16x8*)&av[8];
    *(f16x8*)&sA[p][half * 32 + 16] = *(f16x8*)&av[16];
    *(f16x8*)&sA[p][half * 32 + 24] = *(f16x8*)&av[24];
  }
  __syncthreads();
  int w = t >> 6, lane = t & 63, lr = lane & 15, kh = lane >> 4;
  f32x4 acc[2][2];
#pragma unroll
  for (int i = 0; i < 2; ++i)
#pragma unroll
    for (int j = 0; j < 2; ++j) acc[i][j] = (f32x4)(0.f);
#pragma unroll
  for (int ks = 0; ks < 2; ++ks) {
    f16x8 af[2], bf[2];
#pragma unroll
    for (int i = 0; i < 2; ++i)
      af[i] = *(const f16x8*)&sA[w * 32 + i * 16 + lr][ks * 32 + kh * 8];
#pragma unroll
    for (int j = 0; j < 2; ++j)
      bf[j] = *(const f16x8*)&sB[j * 16 + lr][ks * 32 + kh * 8];
#pragma unroll
    for (int i = 0; i < 2; ++i)
#pragma unroll
      for (int j = 0; j < 2; ++j)
        acc[i][j] = __builtin_amdgcn_mfma_f32_16x16x32_f16(af[i], bf[j], acc[i][j], 0, 0, 0);
  }
#pragma unroll
  for (int j = 0; j < 2; ++j) {
    int co = j * 16 + lr;
    float g = bnp[co], be = bnp[32 + co], mm = bnp[64 + co], vv = bnp[96 + co];
    float sc = rsqrtf(vv + EPSF) * g, sh = be - mm * sc;
#pragma unroll
    for (int i = 0; i < 2; ++i) {
#pragma unroll
      for (int rr = 0; rr < 4; ++rr) {
        int pix = w * 32 + i * 16 + kh * 4 + rr;
        int x = x0 + pix;
        X1h[((size_t)(b * 32 + y) * 512 + x) * 32 + co] =
            (_Float16)fmaf(acc[i][j][rr], sc, sh);
      }
    }
  }
}

// ---- w2[co][ci][r][s] -> W2t[rs][co][ci] fp16 ----
__global__ __launch_bounds__(256) void k_w2t(
    const float* __restrict__ w2, _Float16* __restrict__ W2t) {
  int i = blockIdx.x * 256 + threadIdx.x;
  if (i >= 49 * 64 * 32) return;
  int ci = i & 31, co = (i >> 5) & 63, rs = i >> 11;
  W2t[rs * 2048 + co * 32 + ci] = (_Float16)w2[co * 1568 + ci * 49 + rs];
}

// ---- conv2 as MFMA implicit GEMM: M=(b,ho,wo)=32768, N=co=64, K=(rs,ci)=49x32 ----
__global__ __launch_bounds__(512) void k_conv2m(
    const _Float16* __restrict__ X1h, const _Float16* __restrict__ W2t,
    const float* __restrict__ bn2p, const float* __restrict__ img,
    const float* __restrict__ dsw, const float* __restrict__ dsbnp,
    _Float16* __restrict__ Tok16) {
  __shared__ _Float16 As[2][128 * 40];  // 80B row stride: 2-way bank alias only
  __shared__ _Float16 Bs[2][64 * 40];
  int b = blockIdx.x, ho = blockIdx.y, wo0 = blockIdx.z * 128;
  int t = threadIdx.x;
  int w = t >> 6, lane = t & 63;
  int lr = lane & 15, kh = lane >> 4;
  int wm = w >> 1, wn = w & 1;
  f32x4 acc[2][2];
#pragma unroll
  for (int i = 0; i < 2; ++i)
#pragma unroll
    for (int j = 0; j < 2; ++j) acc[i][j] = (f32x4)(0.f);

  int arow = t >> 2, achk = t & 3;
  const _Float16* xb = X1h + (size_t)b * 32 * 512 * 32;

  auto LOADA = [&](int rs, f16x8& ra) {
    int r = rs / 7, s = rs - 7 * r;
    int y = 2 * ho + r - 3;
    int xx = 2 * (wo0 + arow) + s - 3;
    if (y >= 0 && y < 32 && xx >= 0 && xx < 512)
      ra = *(const f16x8*)(xb + ((size_t)(y * 512 + xx)) * 32 + achk * 8);
    else
      ra = (f16x8)(_Float16)0.f;
  };

  f16x8 ra, rb;
  LOADA(0, ra);
  if (t < 256) rb = *(const f16x8*)(W2t + (t >> 2) * 32 + (t & 3) * 8);
  *(f16x8*)&As[0][arow * 40 + achk * 8] = ra;
  if (t < 256) *(f16x8*)&Bs[0][(t >> 2) * 40 + (t & 3) * 8] = rb;
  __syncthreads();

  int cur = 0;
  for (int rs = 0; rs < 49; ++rs) {
    f16x8 na, nb;
    if (rs + 1 < 49) {
      LOADA(rs + 1, na);
      if (t < 256)
        nb = *(const f16x8*)(W2t + (rs + 1) * 2048 + (t >> 2) * 32 + (t & 3) * 8);
    }
    f16x8 af[2], bf[2];
#pragma unroll
    for (int i = 0; i < 2; ++i)
      af[i] = *(const f16x8*)&As[cur][(wm * 32 + i * 16 + lr) * 40 + kh * 8];
#pragma unroll
    for (int j = 0; j < 2; ++j)
      bf[j] = *(const f16x8*)&Bs[cur][(wn * 32 + j * 16 + lr) * 40 + kh * 8];
#pragma unroll
    for (int i = 0; i < 2; ++i)
#pragma unroll
      for (int j = 0; j < 2; ++j)
        acc[i][j] = __builtin_amdgcn_mfma_f32_16x16x32_f16(af[i], bf[j], acc[i][j], 0, 0, 0);
    if (rs + 1 < 49) {
      *(f16x8*)&As[cur ^ 1][arow * 40 + achk * 8] = na;
      if (t < 256) *(f16x8*)&Bs[cur ^ 1][(t >> 2) * 40 + (t & 3) * 8] = nb;
      __syncthreads();
      cur ^= 1;
    }
  }

#pragma unroll
  for (int j = 0; j < 2; ++j) {
    int co = wn * 32 + j * 16 + lr;
    float g = bn2p[co], be = bn2p[64 + co], mm = bn2p[128 + co], vv = bn2p[192 + co];
    float sc = rsqrtf(vv + EPSF) * g, sh = be - mm * sc;
    float dg = dsbnp[co], dbe = dsbnp[64 + co], dmm = dsbnp[128 + co], dvv = dsbnp[192 + co];
    float dsc = rsqrtf(dvv + EPSF) * dg, dsh = dbe - dmm * dsc;
    float wv = dsw[co];
#pragma unroll
    for (int i = 0; i < 2; ++i) {
#pragma unroll
      for (int rr = 0; rr < 4; ++rr) {
        int row = wm * 32 + i * 16 + kh * 4 + rr;
        int wo = wo0 + row;
        float dval = fmaf(img[((size_t)(b * 64 + 4 * ho)) * 1024 + 4 * wo] * wv, dsc, dsh);
        float v = fmaf(acc[i][j][rr], sc, sh) + dval;
        v = v > 0.f ? v : 0.f;
        Tok16[((size_t)(b * 256 + wo)) * DM_N + co * 16 + ho] = (_Float16)v;
      }
    }
  }
}

// ------ MFMA fp16 GEMM: C16[M,N] = A[M,K] * W[N,K]^T + fused epilogue (fp16 stream) ------
// MODE 0: store v.  MODE 1: bn(v)+res.  MODE 2: relu(bn(v+bias)).  MODE 3: bn(v+bias)+res.
template <int MODE, int BM, int BN>
__global__ __launch_bounds__(256) void k_mgemm(
    const _Float16* __restrict__ A, const _Float16* __restrict__ W,
    int M, int N, int K,
    const float* __restrict__ bias, const float* __restrict__ bnp,
    const _Float16* __restrict__ res16, _Float16* __restrict__ C16) {
  constexpr int MI = BM / 32, NJ = BN / 32;
  __shared__ _Float16 As[2][BM * 32];
  __shared__ _Float16 Bs[2][BN * 32];
  const int t = threadIdx.x;
  const int w = t >> 6, lane = t & 63;
  const int lr = lane & 15, kh = lane >> 4;
  const int wm = w >> 1, wn = w & 1;
  const int m0 = blockIdx.y * BM, n0 = blockIdx.x * BN;
  f32x4 acc[MI][NJ];
#pragma unroll
  for (int i = 0; i < MI; ++i)
#pragma unroll
    for (int j = 0; j < NJ; ++j) acc[i][j] = (f32x4)(0.f);

  const int nt = K >> 5;
  auto STAGE = [&](int bb, int kt) {
    const int k0 = kt << 5;
#pragma unroll
    for (int it = 0; it < BM / 64; ++it) {
      int c = it * 256 + w * 64 + lane;
      int row = c >> 2, kq = c & 3;
      gll16(A + (size_t)(m0 + row) * K + k0 + kq * 8,
            &As[bb][(size_t)(it * 256 + w * 64) * 8]);
    }
#pragma unroll
    for (int it = 0; it < BN / 64; ++it) {
      int c = it * 256 + w * 64 + lane;
      int row = c >> 2, kq = c & 3;
      gll16(W + (size_t)(n0 + row) * K + k0 + kq * 8,
            &Bs[bb][(size_t)(it * 256 + w * 64) * 8]);
    }
  };

  STAGE(0, 0);
  __syncthreads();
  int bb = 0;
  for (int kt = 0; kt < nt; ++kt) {
    if (kt + 1 < nt) STAGE(bb ^ 1, kt + 1);
    f16x8 af[MI], bf[NJ];
#pragma unroll
    for (int i = 0; i < MI; ++i)
      af[i] = *(const f16x8*)&As[bb][(size_t)((wm * (BM / 2) + i * 16 + lr) * 32 + kh * 8)];
#pragma unroll
    for (int j = 0; j < NJ; ++j)
      bf[j] = *(const f16x8*)&Bs[bb][(size_t)((wn * (BN / 2) + j * 16 + lr) * 32 + kh * 8)];
#pragma unroll
    for (int i = 0; i < MI; ++i)
#pragma unroll
      for (int j = 0; j < NJ; ++j)
        acc[i][j] = __builtin_amdgcn_mfma_f32_16x16x32_f16(af[i], bf[j], acc[i][j], 0, 0, 0);
    __syncthreads();
    bb ^= 1;
  }

#pragma unroll
  for (int j = 0; j < NJ; ++j) {
    int cn = n0 + wn * (BN / 2) + j * 16 + lr;
    if (cn >= N) continue;
    float sc = 1.f, sh = 0.f, bs = 0.f;
    if (MODE >= 1) {
      float g = bnp[cn], be = bnp[N + cn];
      float mm = bnp[2 * N + cn], vv = bnp[3 * N + cn];
      sc = rsqrtf(vv + EPSF) * g;
      sh = be - mm * sc;
    }
    if (MODE == 2 || MODE == 3) bs = bias[cn];
#pragma unroll
    for (int i = 0; i < MI; ++i) {
#pragma unroll
      for (int rr = 0; rr < 4; ++rr) {
        int r = m0 + wm * (BM / 2) + i * 16 + kh * 4 + rr;
        float v = acc[i][j][rr];
        if (MODE == 2 || MODE == 3) v += bs;
        if (MODE >= 1) v = fmaf(v, sc, sh);
        if (MODE == 2) v = v > 0.f ? v : 0.f;
        size_t o = (size_t)r * N + cn;
        if (MODE == 1 || MODE == 3) v += (float)res16[o];
        C16[o] = (_Float16)v;
      }
    }
  }
}

// ------- causal depthwise conv1d + silu on xBC (fp16 in/out); softplus dt; LOG-decay -------
__global__ __launch_bounds__(256) void k_convprep(
    const _Float16* __restrict__ ZX16, const float* __restrict__ cw,
    const float* __restrict__ cb, const float* __restrict__ dtb,
    const float* __restrict__ Alog, _Float16* __restrict__ XBC16,
    float* __restrict__ DT, float* __restrict__ DLA) {
  int m = blockIdx.x;
  int c = blockIdx.y * 256 + threadIdx.x;
  int l = m & 255;
  if (c < DCONV_N) {
    const float* cwp = cw + c * 4;
    float acc = cb[c];
#pragma unroll
    for (int k = 0; k < 4; ++k) {
      int dl = l + k - 3;
      if (dl >= 0)
        acc = fmaf((float)ZX16[(size_t)(m + k - 3) * DPROJ_N + DI_N + c], cwp[k], acc);
    }
    XBC16[(size_t)m * DCONV_N + c] = (_Float16)(acc * sigf(acc));
  } else if (c < DCONV_N + NH_N) {
    int h = c - DCONV_N;
    float xx = (float)ZX16[(size_t)m * DPROJ_N + DI_N + DCONV_N + h] + dtb[h];
    float dt = xx > 20.f ? xx : log1pf(__expf(xx));
    DT[m * NH_N + h] = dt;
    DLA[m * NH_N + h] = -dt * __expf(Alog[h]);  // log(dA), always finite, <= 0
  }
}

// ------- selective scan v3: Mamba2 SSD chunked, MFMA. grid 256=(b,h), 256 thr (4 waves) -------
__global__ __launch_bounds__(256) void k_scan(
    const _Float16* __restrict__ XBC16, const float* __restrict__ DT,
    const float* __restrict__ DLA, const float* __restrict__ Dp,
    float* __restrict__ Y) {
  __shared__ _Float16 sC[64][72];    // C[l][n]
  __shared__ _Float16 sB[64][72];    // B[l][n]
  __shared__ _Float16 sBts[64][72];  // [n][j] = B[j][n]*es[j]
  __shared__ _Float16 sXt[64][72];   // [p][l] = dt[l]*x[l][p]
  __shared__ _Float16 sP[64][72];    // P[l][j]
  __shared__ _Float16 sH[64][72];    // h[p][n] fp16 mirror
  __shared__ float sH32[64][68];     // h[p][n] fp32 master
  __shared__ float sS[64], sEl[64], sEs[64], sDt[64];
  __shared__ float sCpt;

  const int b = blockIdx.x >> 5, h = blockIdx.x & 31;
  const int t = threadIdx.x;
  const int w = t >> 6, lane = t & 63;
  const int lr = lane & 15, kh = lane >> 4;
  const float Dh = Dp[h];

  {  // zero h
    _Float16* hp = &sH[0][0];
    float* h32p = &sH32[0][0];
    for (int i = t; i < 64 * 72; i += 256) hp[i] = (_Float16)0.f;
    for (int i = t; i < 64 * 68; i += 256) h32p[i] = 0.f;
  }

  for (int c = 0; c < 4; ++c) {
    const int mbase = b * L_N + c * 64;
    __syncthreads();  // A: protect LDS reuse across chunks (incl. h16 writes)

    if (t < 64) {  // B: segsum in wave 0
      int l = t;
      float v = DLA[(mbase + l) * NH_N + h];
#pragma unroll
      for (int o = 1; o < 64; o <<= 1) {
        float u = __shfl_up(v, o);
        v += (l >= o) ? u : 0.f;
      }
      sS[l] = v;
      sEl[l] = __expf(v);
      float s63 = __shfl(v, 63);
      sEs[l] = __expf(s63 - v);
      if (l == 63) sCpt = __expf(s63);
      sDt[l] = DT[(mbase + l) * NH_N + h];
    }
    __syncthreads();  // B -> C

    {  // C: build tiles. thread = (row l = t>>2, col quarter q = t&3)
      int l = t >> 2, q = t & 3;
      const _Float16* row = XBC16 + (size_t)(mbase + l) * DCONV_N;
      float dt_l = sDt[l], es_l = sEs[l];
      // B
      f16x8 b0 = *(const f16x8*)&row[DI_N + q * 16];
      f16x8 b1 = *(const f16x8*)&row[DI_N + q * 16 + 8];
      *(f16x8*)&sB[l][q * 16] = b0;
      *(f16x8*)&sB[l][q * 16 + 8] = b1;
#pragma unroll
      for (int i = 0; i < 8; ++i) {
        sBts[q * 16 + i][l] = (_Float16)((float)b0[i] * es_l);
        sBts[q * 16 + 8 + i][l] = (_Float16)((float)b1[i] * es_l);
      }
      // C
      *(f16x8*)&sC[l][q * 16] = *(const f16x8*)&row[DI_N + DS_N + q * 16];
      *(f16x8*)&sC[l][q * 16 + 8] = *(const f16x8*)&row[DI_N + DS_N + q * 16 + 8];
      // x -> Xd^T
      f16x8 x0 = *(const f16x8*)&row[h * HD_N + q * 16];
      f16x8 x1 = *(const f16x8*)&row[h * HD_N + q * 16 + 8];
#pragma unroll
      for (int i = 0; i < 8; ++i) {
        sXt[q * 16 + i][l] = (_Float16)((float)x0[i] * dt_l);
        sXt[q * 16 + 8 + i][l] = (_Float16)((float)x1[i] * dt_l);
      }
    }
    __syncthreads();  // C -> D

    // D: S = C@B^T ; Yinter = C@h^T
    f32x4 Sacc[4], Yacc[4];
#pragma unroll
    for (int j = 0; j < 4; ++j) { Sacc[j] = (f32x4)(0.f); Yacc[j] = (f32x4)(0.f); }
    {
      f16x8 aC[2];
#pragma unroll
      for (int kk = 0; kk < 2; ++kk)
        aC[kk] = *(const f16x8*)&sC[16 * w + lr][kk * 32 + kh * 8];
#pragma unroll
      for (int kk = 0; kk < 2; ++kk)
#pragma unroll
        for (int jt = 0; jt < 4; ++jt) {
          f16x8 bB = *(const f16x8*)&sB[jt * 16 + lr][kk * 32 + kh * 8];
          f16x8 bH = *(const f16x8*)&sH[jt * 16 + lr][kk * 32 + kh * 8];
          Sacc[jt] = __builtin_amdgcn_mfma_f32_16x16x32_f16(aC[kk], bB, Sacc[jt], 0, 0, 0);
          Yacc[jt] = __builtin_amdgcn_mfma_f32_16x16x32_f16(aC[kk], bH, Yacc[jt], 0, 0, 0);
        }
    }

    // E: mask P, scale Yinter rows by el
#pragma unroll
    for (int rr = 0; rr < 4; ++rr) {
      int l = 16 * w + kh * 4 + rr;
      float sl = sS[l], el = sEl[l];
#pragma unroll
      for (int jt = 0; jt < 4; ++jt) {
        int j = jt * 16 + lr;
        float pv = (j <= l) ? Sacc[jt][rr] * __expf(sl - sS[j]) : 0.f;
        sP[l][j] = (_Float16)pv;
        Yacc[jt][rr] *= el;
      }
    }
    __syncthreads();  // E -> F

    // F: Y += P@Xd^T ; Hacc = Xd^T-rows @ Bts^T
    f32x4 Hacc[4];
#pragma unroll
    for (int j = 0; j < 4; ++j) Hacc[j] = (f32x4)(0.f);
    {
      f16x8 aP[2], aX[2];
#pragma unroll
      for (int kk = 0; kk < 2; ++kk) {
        aP[kk] = *(const f16x8*)&sP[16 * w + lr][kk * 32 + kh * 8];
        aX[kk] = *(const f16x8*)&sXt[16 * w + lr][kk * 32 + kh * 8];
      }
#pragma unroll
      for (int kk = 0; kk < 2; ++kk)
#pragma unroll
        for (int jt = 0; jt < 4; ++jt) {
          f16x8 bX = *(const f16x8*)&sXt[jt * 16 + lr][kk * 32 + kh * 8];
          f16x8 bBt = *(const f16x8*)&sBts[jt * 16 + lr][kk * 32 + kh * 8];
          Yacc[jt] = __builtin_amdgcn_mfma_f32_16x16x32_f16(aP[kk], bX, Yacc[jt], 0, 0, 0);
          Hacc[jt] = __builtin_amdgcn_mfma_f32_16x16x32_f16(aX[kk], bBt, Hacc[jt], 0, 0, 0);
        }
    }

    // G: epilogue — Y out (+D skip), h update
    float cpt = sCpt;
#pragma unroll
    for (int rr = 0; rr < 4; ++rr) {
      int lrow = 16 * w + kh * 4 + rr;
      int m = mbase + lrow;
#pragma unroll
      for (int jt = 0; jt < 4; ++jt) {
        int p = jt * 16 + lr;
        float xr = (float)XBC16[(size_t)m * DCONV_N + h * HD_N + p];
        Y[(size_t)m * DI_N + h * HD_N + p] = fmaf(Dh, xr, Yacc[jt][rr]);
        float hv = fmaf(cpt, sH32[lrow][jt * 16 + lr], Hacc[jt][rr]);
        sH32[lrow][jt * 16 + lr] = hv;
        sH[lrow][jt * 16 + lr] = (_Float16)hv;
      }
    }
  }
}

// ------- gate with silu(z) + RMSNorm (over DI) -> fp16; thread owns 8 contiguous c -------
__global__ __launch_bounds__(256) void k_gatenorm(
    const float* __restrict__ Y, const _Float16* __restrict__ ZX16,
    const float* __restrict__ nw, _Float16* __restrict__ YN16) {
  int m = blockIdx.x, t = threadIdx.x;
  const float* y = Y + (size_t)m * DI_N;
  const _Float16* z = ZX16 + (size_t)m * DPROJ_N;
  int c0 = t * 8;
  float4 y0 = *(const float4*)&y[c0];
  float4 y1 = *(const float4*)&y[c0 + 4];
  f16x8 z8 = *(const f16x8*)&z[c0];
  float yv[8] = {y0.x, y0.y, y0.z, y0.w, y1.x, y1.y, y1.z, y1.w};
  float vals[8];
  float ss = 0.f;
#pragma unroll
  for (int j = 0; j < 8; ++j) {
    float zz = (float)z8[j];
    float vv = yv[j] * zz * sigf(zz);
    vals[j] = vv;
    ss = fmaf(vv, vv, ss);
  }
#pragma unroll
  for (int o = 1; o < 64; o <<= 1) ss += __shfl_xor(ss, o);
  __shared__ float sred[4];
  if ((t & 63) == 0) sred[t >> 6] = ss;
  __syncthreads();
  float tot = sred[0] + sred[1] + sred[2] + sred[3];
  float scale = rsqrtf(tot * (1.f / DI_N) + EPSF);
  float4 nw0 = *(const float4*)&nw[c0];
  float4 nw1 = *(const float4*)&nw[c0 + 4];
  float nv[8] = {nw0.x, nw0.y, nw0.z, nw0.w, nw1.x, nw1.y, nw1.z, nw1.w};
  f16x8 o;
#pragma unroll
  for (int j = 0; j < 8; ++j) o[j] = (_Float16)(vals[j] * scale * nv[j]);
  *(f16x8*)&YN16[(size_t)m * DI_N + c0] = o;
}

// ------- final transpose: Tok16[m][d] -> out[b][d][l] fp32 -------
__global__ __launch_bounds__(256) void k_transpose(
    const _Float16* __restrict__ Tok16, float* __restrict__ out) {
  __shared__ float tile[32][33];
  int d0 = blockIdx.x * 32, m0 = blockIdx.y * 32;
  int tx = threadIdx.x & 31, ty = threadIdx.x >> 5;
  for (int i = ty; i < 32; i += 8)
    tile[i][tx] = (float)Tok16[(size_t)(m0 + i) * DM_N + d0 + tx];
  __syncthreads();
  int b = m0 >> 8, l0 = m0 & 255;
  for (int i = ty; i < 32; i += 8)
    out[((size_t)b * DM_N + d0 + i) * L_N + l0 + tx] = tile[tx][i];
}

extern "C" void kernel_launch(void* const* d_in, const int* in_sizes, int n_in,
                              void* d_out, int out_size, void* d_ws, size_t ws_size,
                              hipStream_t stream) {
  const float* image = (const float*)d_in[0];
  const float* conv1_w = (const float*)d_in[1];
  const float* bn1 = (const float*)d_in[2];
  const float* conv2_w = (const float*)d_in[3];
  const float* bn2 = (const float*)d_in[4];
  const float* ds_w = (const float*)d_in[5];
  const float* ds_bn = (const float*)d_in[6];
  const float* in_proj_w = (const float*)d_in[7];
  const float* conv1d_w = (const float*)d_in[8];
  const float* conv1d_b = (const float*)d_in[9];
  const float* dt_bias = (const float*)d_in[10];
  const float* A_log = (const float*)d_in[11];
  const float* Dpar = (const float*)d_in[12];
  const float* norm_w = (const float*)d_in[13];
  const float* out_proj_w = (const float*)d_in[14];
  const float* blk_bn = (const float*)d_in[15];
  const float* ff_w1 = (const float*)d_in[16];
  const float* ff_b1 = (const float*)d_in[17];
  const float* ff_bn1 = (const float*)d_in[18];
  const float* ff_w2 = (const float*)d_in[19];
  const float* ff_b2 = (const float*)d_in[20];
  const float* ff_bn2 = (const float*)d_in[21];

  // workspace: fp32 region (YR, DT, DLA) then fp16 region (~74 MB total)
  float* ws = (float*)d_ws;
  float* YR = ws;                           // 2048*2048 fp32; stem X1h aliases this
  float* DTb = YR + (size_t)NTOK * DI_N;    // 2048*32
  float* DLAb = DTb + (size_t)NTOK * NH_N;  // 2048*32
  _Float16* Tok16 = (_Float16*)(DLAb + (size_t)NTOK * NH_N);  // 2048*1024
  _Float16* ZX16 = Tok16 + (size_t)NTOK * DM_N;               // 2048*4256
  _Float16* XBC16 = ZX16 + (size_t)NTOK * DPROJ_N;            // 2048*2176
  _Float16* YN16 = XBC16 + (size_t)NTOK * DCONV_N;            // 2048*2048
  _Float16* H116 = YN16 + (size_t)NTOK * DI_N;                // 2048*2048
  _Float16* W16 = H116 + (size_t)NTOK * DI_N;                 // 4352*1024
  _Float16* W2t = W16 + (size_t)NPAD_INPROJ * DM_N;           // 49*64*32
  _Float16* W1t = W2t + (size_t)49 * 64 * 32;                 // 32*64
  _Float16* X1h = (_Float16*)YR;

  k_w1t<<<8, 256, 0, stream>>>(conv1_w, W1t);
  k_conv1m<<<dim3(8, 32, 4), 256, 0, stream>>>(image, W1t, bn1, X1h);
  k_w2t<<<(49 * 64 * 32 + 255) / 256, 256, 0, stream>>>(conv2_w, W2t);
  k_conv2m<<<dim3(8, 16, 2), 512, 0, stream>>>(X1h, W2t, bn2, image, ds_w, ds_bn, Tok16);

  for (int i = 0; i < 4; ++i) {
    const float* Wi = in_proj_w + (size_t)i * DPROJ_N * DM_N;
    const float* cw = conv1d_w + (size_t)i * DCONV_N * 4;
    const float* cb = conv1d_b + (size_t)i * DCONV_N;
    const float* dtb = dt_bias + i * NH_N;
    const float* al = A_log + i * NH_N;
    const float* dd = Dpar + i * NH_N;
    const float* nw = norm_w + i * DI_N;
    const float* Wo = out_proj_w + (size_t)i * DM_N * DI_N;
    const float* bbn = blk_bn + (size_t)i * 4 * DM_N;
    const float* w1 = ff_w1 + (size_t)i * FFH_N * DM_N;
    const float* b1 = ff_b1 + i * FFH_N;
    const float* fbn1 = ff_bn1 + (size_t)i * 4 * FFH_N;
    const float* w2 = ff_w2 + (size_t)i * DM_N * FFH_N;
    const float* b2 = ff_b2 + i * DM_N;
    const float* fbn2 = ff_bn2 + (size_t)i * 4 * DM_N;

    // in_proj: ZX16[2048,4256] = Tok16 x Wi^T   (BM=64,BN=128 -> 1088 blocks)
    k_tohalf8<<<(NPAD_INPROJ * 1024 / 8 + 255) / 256, 256, 0, stream>>>(
        Wi, W16, DPROJ_N * DM_N, NPAD_INPROJ * DM_N);
    k_mgemm<0, 64, 128><<<dim3(34, 32), 256, 0, stream>>>(
        Tok16, W16, NTOK, DPROJ_N, DM_N, nullptr, nullptr, nullptr, ZX16);
    k_convprep<<<dim3(NTOK, 9), 256, 0, stream>>>(ZX16, cw, cb, dtb, al, XBC16, DTb, DLAb);
    k_scan<<<256, 256, 0, stream>>>(XBC16, DTb, DLAb, dd, YR);
    k_gatenorm<<<NTOK, 256, 0, stream>>>(YR, ZX16, nw, YN16);
    // out_proj: Tok16 = bn(YN16 x Wo^T) + Tok16   (BM=64,BN=64 -> 512 blocks)
    k_tohalf8<<<(DM_N * DI_N / 8 + 255) / 256, 256, 0, stream>>>(
        Wo, W16, DM_N * DI_N, DM_N * DI_N);
    k_mgemm<1, 64, 64><<<dim3(16, 32), 256, 0, stream>>>(
        YN16, W16, NTOK, DM_N, DI_N, nullptr, bbn, Tok16, Tok16);
    // ff1: H116 = relu(bn(Tok16 x w1^T + b1))   (BM=64,BN=128 -> 512 blocks)
    k_tohalf8<<<(FFH_N * DM_N / 8 + 255) / 256, 256, 0, stream>>>(
        w1, W16, FFH_N * DM_N, FFH_N * DM_N);
    k_mgemm<2, 64, 128><<<dim3(16, 32), 256, 0, stream>>>(
        Tok16, W16, NTOK, FFH_N, DM_N, b1, fbn1, nullptr, H116);
    // ff2: Tok16 = bn(H116 x w2^T + b2) + Tok16   (BM=64,BN=64 -> 512 blocks)
    k_tohalf8<<<(DM_N * FFH_N / 8 + 255) / 256, 256, 0, stream>>>(
        w2, W16, DM_N * FFH_N, DM_N * FFH_N);
    k_mgemm<3, 64, 64><<<dim3(16, 32), 256, 0, stream>>>(
        H116, W16, NTOK, DM_N, FFH_N, b2, fbn2, Tok16, Tok16);
  }
  k_transpose<<<dim3(32, 64), 256, 0, stream>>>(Tok16, (float*)d_out);
}

// Round 11
// 691.437 us; speedup vs baseline: 7.3924x; 1.0907x over previous
//
#include <hip/hip_runtime.h>
#include <hip/hip_bf16.h>
#include <hip/hip_fp16.h>
#include <math.h>

#define EPSF 1e-5f
#define B_N 8
#define L_N 256
#define DM_N 1024
#define DI_N 2048
#define DS_N 64
#define NH_N 32
#define HD_N 64
#define DCONV_N 2176
#define DPROJ_N 4256
#define NTOK 2048
#define FFH_N 2048
#define NPAD_INPROJ 4352  // 4256 padded to multiple of 128

typedef _Float16 f16x8 __attribute__((ext_vector_type(8)));
typedef float f32x4 __attribute__((ext_vector_type(4)));

__device__ __forceinline__ float sigf(float x) { return 1.f / (1.f + __expf(-x)); }

__device__ __forceinline__ void gll16(const void* g, void* l) {
  typedef __attribute__((address_space(1))) const void gv;
  typedef __attribute__((address_space(3))) void lv;
  __builtin_amdgcn_global_load_lds((gv*)g, (lv*)l, 16, 0, 0);
}

__device__ __forceinline__ f16x8 cvt8(float4 a, float4 b) {
  f16x8 o;
  o[0] = (_Float16)a.x; o[1] = (_Float16)a.y; o[2] = (_Float16)a.z; o[3] = (_Float16)a.w;
  o[4] = (_Float16)b.x; o[5] = (_Float16)b.y; o[6] = (_Float16)b.z; o[7] = (_Float16)b.w;
  return o;
}

// ---------------- fp32 -> fp16 converter (8 elems/thread), zero-pads to ntot ----------------
__global__ __launch_bounds__(256) void k_tohalf8(
    const float* __restrict__ src, _Float16* __restrict__ dst, int n, int ntot) {
  int i = (blockIdx.x * 256 + threadIdx.x) * 8;
  if (i >= ntot) return;
  f16x8 o;
  if (i < n) {
    float4 a = *(const float4*)(src + i);
    float4 b = *(const float4*)(src + i + 4);
    o = cvt8(a, b);
  } else {
#pragma unroll
    for (int j = 0; j < 8; ++j) o[j] = (_Float16)0.f;
  }
  *(f16x8*)(dst + i) = o;
}

// ---- conv1 weights: w[32][49] fp32 -> W1t[32][64] fp16, K zero-padded ----
__global__ __launch_bounds__(256) void k_w1t(
    const float* __restrict__ w1, _Float16* __restrict__ W1t) {
  int i = blockIdx.x * 256 + threadIdx.x;
  if (i >= 32 * 64) return;
  int co = i >> 6, k = i & 63;
  W1t[i] = (k < 49) ? (_Float16)w1[co * 49 + k] : (_Float16)0.f;
}

// ---- conv1 as MFMA implicit GEMM: M=pixels(131072), N=co(32), K=49->64 ----
__global__ __launch_bounds__(256) void k_conv1m(
    const float* __restrict__ img, const _Float16* __restrict__ W1t,
    const float* __restrict__ bnp, _Float16* __restrict__ X1h) {
  __shared__ float sIn[7][264];     // x-window [2*x0-3 .. +262)
  __shared__ _Float16 sA[128][72];  // im2col rows, 144B stride
  __shared__ _Float16 sB[32][72];
  int b = blockIdx.x, y = blockIdx.y, x0 = blockIdx.z * 128;
  int t = threadIdx.x;
  {  // stage B: 32 rows x 64 k = 256 chunks of 8
    int r = t >> 3, c = (t & 7) * 8;
    *(f16x8*)&sB[r][c] = *(const f16x8*)&W1t[r * 64 + c];
  }
  const float* ip = img + (size_t)b * 64 * 1024;
#pragma unroll
  for (int r = 0; r < 7; ++r) {
    int yy = 2 * y - 3 + r;
    for (int c = t; c < 262; c += 256) {
      int xx = 2 * x0 - 3 + c;
      float v = 0.f;
      if (yy >= 0 && yy < 64 && xx >= 0 && xx < 1024) v = ip[yy * 1024 + xx];
      sIn[r][c] = v;
    }
  }
  __syncthreads();
  {  // im2col: thread -> (pixel p = t>>1, k-half = t&1)
    int p = t >> 1, half = t & 1;
    _Float16 av[32];
    if (half == 0) {
#pragma unroll
      for (int k = 0; k < 32; ++k)
        av[k] = (_Float16)sIn[k / 7][2 * p + (k % 7)];
    } else {
#pragma unroll
      for (int k = 32; k < 64; ++k)
        av[k - 32] = (k < 49) ? (_Float16)sIn[k / 7][2 * p + (k % 7)] : (_Float16)0.f;
    }
    *(f16x8*)&sA[p][half * 32 + 0] = *(f16x8*)&av[0];
    *(f16x8*)&sA[p][half * 32 + 8] = *(f16x8*)&av[8];
    *(f16x8*)&sA[p][half * 32 + 16] = *(f16x8*)&av[16];
    *(f16x8*)&sA[p][half * 32 + 24] = *(f16x8*)&av[24];
  }
  __syncthreads();
  int w = t >> 6, lane = t & 63, lr = lane & 15, kh = lane >> 4;
  f32x4 acc[2][2];
#pragma unroll
  for (int i = 0; i < 2; ++i)
#pragma unroll
    for (int j = 0; j < 2; ++j) acc[i][j] = (f32x4)(0.f);
#pragma unroll
  for (int ks = 0; ks < 2; ++ks) {
    f16x8 af[2], bf[2];
#pragma unroll
    for (int i = 0; i < 2; ++i)
      af[i] = *(const f16x8*)&sA[w * 32 + i * 16 + lr][ks * 32 + kh * 8];
#pragma unroll
    for (int j = 0; j < 2; ++j)
      bf[j] = *(const f16x8*)&sB[j * 16 + lr][ks * 32 + kh * 8];
#pragma unroll
    for (int i = 0; i < 2; ++i)
#pragma unroll
      for (int j = 0; j < 2; ++j)
        acc[i][j] = __builtin_amdgcn_mfma_f32_16x16x32_f16(af[i], bf[j], acc[i][j], 0, 0, 0);
  }
#pragma unroll
  for (int j = 0; j < 2; ++j) {
    int co = j * 16 + lr;
    float g = bnp[co], be = bnp[32 + co], mm = bnp[64 + co], vv = bnp[96 + co];
    float sc = rsqrtf(vv + EPSF) * g, sh = be - mm * sc;
#pragma unroll
    for (int i = 0; i < 2; ++i) {
#pragma unroll
      for (int rr = 0; rr < 4; ++rr) {
        int pix = w * 32 + i * 16 + kh * 4 + rr;
        int x = x0 + pix;
        X1h[((size_t)(b * 32 + y) * 512 + x) * 32 + co] =
            (_Float16)fmaf(acc[i][j][rr], sc, sh);
      }
    }
  }
}

// ---- w2[co][ci][r][s] -> W2t[rs][co][ci] fp16 ----
__global__ __launch_bounds__(256) void k_w2t(
    const float* __restrict__ w2, _Float16* __restrict__ W2t) {
  int i = blockIdx.x * 256 + threadIdx.x;
  if (i >= 49 * 64 * 32) return;
  int ci = i & 31, co = (i >> 5) & 63, rs = i >> 11;
  W2t[rs * 2048 + co * 32 + ci] = (_Float16)w2[co * 1568 + ci * 49 + rs];
}

// ---- conv2 v2: MFMA implicit GEMM, 2-rs K-steps (K=64/step, 25 steps), 64x64 tile ----
// grid (8, 16, 4) = 512 blocks (2/CU); 256 thr (4 waves, 2x2 of 32x32). LDS rows stride 72.
__global__ __launch_bounds__(256) void k_conv2m(
    const _Float16* __restrict__ X1h, const _Float16* __restrict__ W2t,
    const float* __restrict__ bn2p, const float* __restrict__ img,
    const float* __restrict__ dsw, const float* __restrict__ dsbnp,
    _Float16* __restrict__ Tok16) {
  __shared__ _Float16 As[2][64 * 72];
  __shared__ _Float16 Bs[2][64 * 72];
  int b = blockIdx.x, ho = blockIdx.y, wo0 = blockIdx.z * 64;
  int t = threadIdx.x;
  int w = t >> 6, lane = t & 63;
  int lr = lane & 15, kh = lane >> 4;
  int wm = w >> 1, wn = w & 1;
  f32x4 acc[2][2];
#pragma unroll
  for (int i = 0; i < 2; ++i)
#pragma unroll
    for (int j = 0; j < 2; ++j) acc[i][j] = (f32x4)(0.f);

  const _Float16* xb = X1h + (size_t)b * 32 * 512 * 32;

  auto LOADA = [&](int step, int u, f16x8& ra) {
    int c = u * 256 + t;
    int row = c >> 3, s = c & 7;
    int rsl = s >> 2, ciq = s & 3;
    int rs = step * 2 + rsl;
#pragma unroll
    for (int q = 0; q < 8; ++q) ra[q] = (_Float16)0.f;
    if (rs < 49) {
      int r = rs / 7, ss = rs - 7 * r;
      int y = 2 * ho + r - 3, xx = 2 * (wo0 + row) + ss - 3;
      if (y >= 0 && y < 32 && xx >= 0 && xx < 512)
        ra = *(const f16x8*)(xb + ((size_t)(y * 512 + xx)) * 32 + ciq * 8);
    }
  };
  auto LOADB = [&](int step, int u, f16x8& rb) {
    int c = u * 256 + t;
    int co = c >> 3, s = c & 7;
    int rsl = s >> 2, ciq = s & 3;
    int rs = step * 2 + rsl;
#pragma unroll
    for (int q = 0; q < 8; ++q) rb[q] = (_Float16)0.f;
    if (rs < 49) rb = *(const f16x8*)(W2t + rs * 2048 + co * 32 + ciq * 8);
  };

  f16x8 ra[2], rb[2];
#pragma unroll
  for (int u = 0; u < 2; ++u) { LOADA(0, u, ra[u]); LOADB(0, u, rb[u]); }
#pragma unroll
  for (int u = 0; u < 2; ++u) {
    int c = u * 256 + t, row = c >> 3, s = c & 7;
    *(f16x8*)&As[0][row * 72 + s * 8] = ra[u];
    *(f16x8*)&Bs[0][row * 72 + s * 8] = rb[u];
  }
  __syncthreads();

  int cur = 0;
  for (int st = 0; st < 25; ++st) {
    f16x8 na[2], nb[2];
    if (st + 1 < 25) {
#pragma unroll
      for (int u = 0; u < 2; ++u) { LOADA(st + 1, u, na[u]); LOADB(st + 1, u, nb[u]); }
    }
    f16x8 af[2][2], bf[2][2];
#pragma unroll
    for (int i = 0; i < 2; ++i)
#pragma unroll
      for (int kk = 0; kk < 2; ++kk)
        af[i][kk] = *(const f16x8*)&As[cur][(wm * 32 + i * 16 + lr) * 72 + (kk * 4 + kh) * 8];
#pragma unroll
    for (int j = 0; j < 2; ++j)
#pragma unroll
      for (int kk = 0; kk < 2; ++kk)
        bf[j][kk] = *(const f16x8*)&Bs[cur][(wn * 32 + j * 16 + lr) * 72 + (kk * 4 + kh) * 8];
#pragma unroll
    for (int kk = 0; kk < 2; ++kk)
#pragma unroll
      for (int i = 0; i < 2; ++i)
#pragma unroll
        for (int j = 0; j < 2; ++j)
          acc[i][j] = __builtin_amdgcn_mfma_f32_16x16x32_f16(af[i][kk], bf[j][kk], acc[i][j], 0, 0, 0);
    if (st + 1 < 25) {
#pragma unroll
      for (int u = 0; u < 2; ++u) {
        int c = u * 256 + t, row = c >> 3, s = c & 7;
        *(f16x8*)&As[cur ^ 1][row * 72 + s * 8] = na[u];
        *(f16x8*)&Bs[cur ^ 1][row * 72 + s * 8] = nb[u];
      }
      __syncthreads();
      cur ^= 1;
    }
  }

#pragma unroll
  for (int j = 0; j < 2; ++j) {
    int co = wn * 32 + j * 16 + lr;
    float g = bn2p[co], be = bn2p[64 + co], mm = bn2p[128 + co], vv = bn2p[192 + co];
    float sc = rsqrtf(vv + EPSF) * g, sh = be - mm * sc;
    float dg = dsbnp[co], dbe = dsbnp[64 + co], dmm = dsbnp[128 + co], dvv = dsbnp[192 + co];
    float dsc = rsqrtf(dvv + EPSF) * dg, dsh = dbe - dmm * dsc;
    float wv = dsw[co];
#pragma unroll
    for (int i = 0; i < 2; ++i) {
#pragma unroll
      for (int rr = 0; rr < 4; ++rr) {
        int row = wm * 32 + i * 16 + kh * 4 + rr;
        int wo = wo0 + row;
        float dval = fmaf(img[((size_t)(b * 64 + 4 * ho)) * 1024 + 4 * wo] * wv, dsc, dsh);
        float v = fmaf(acc[i][j][rr], sc, sh) + dval;
        v = v > 0.f ? v : 0.f;
        Tok16[((size_t)(b * 256 + wo)) * DM_N + co * 16 + ho] = (_Float16)v;
      }
    }
  }
}

// ------ MFMA fp16 GEMM, BK=64, XOR-swizzled LDS (conflict-free ds_read_b128) ------
// Both-sides swizzle (rule 21): global source chunk = (s ^ (row&7)), linear LDS dest;
// reads XOR the same involution. MODE 0: store. 1: bn+res. 2: relu(bn(+bias)). 3: bn(+bias)+res.
template <int MODE, int BM, int BN>
__global__ __launch_bounds__(256) void k_mgemm(
    const _Float16* __restrict__ A, const _Float16* __restrict__ W,
    int M, int N, int K,
    const float* __restrict__ bias, const float* __restrict__ bnp,
    const _Float16* __restrict__ res16, _Float16* __restrict__ C16) {
  constexpr int MI = BM / 32, NJ = BN / 32;
  __shared__ _Float16 As[2][BM * 64];
  __shared__ _Float16 Bs[2][BN * 64];
  const int t = threadIdx.x;
  const int w = t >> 6, lane = t & 63;
  const int lr = lane & 15, kh = lane >> 4;
  const int wm = w >> 1, wn = w & 1;
  const int m0 = blockIdx.y * BM, n0 = blockIdx.x * BN;
  f32x4 acc[MI][NJ];
#pragma unroll
  for (int i = 0; i < MI; ++i)
#pragma unroll
    for (int j = 0; j < NJ; ++j) acc[i][j] = (f32x4)(0.f);

  const int nt = K >> 6;
  auto STAGE = [&](int bb, int kt) {
    const int k0 = kt << 6;
#pragma unroll
    for (int it = 0; it < BM / 32; ++it) {  // 256 chunks per it (32 rows x 8 slots)
      int c = it * 256 + w * 64 + lane;
      int row = c >> 3, s = c & 7;
      int kg = (s ^ (row & 7)) * 8;
      gll16(A + (size_t)(m0 + row) * K + k0 + kg,
            &As[bb][(size_t)(it * 256 + w * 64) * 8]);
    }
#pragma unroll
    for (int it = 0; it < BN / 32; ++it) {
      int c = it * 256 + w * 64 + lane;
      int row = c >> 3, s = c & 7;
      int kg = (s ^ (row & 7)) * 8;
      gll16(W + (size_t)(n0 + row) * K + k0 + kg,
            &Bs[bb][(size_t)(it * 256 + w * 64) * 8]);
    }
  };

  STAGE(0, 0);
  __syncthreads();
  int bb = 0;
  const int sw = lr & 7;  // row&7 for all fragment rows (offsets are multiples of 8)
  for (int kt = 0; kt < nt; ++kt) {
    if (kt + 1 < nt) STAGE(bb ^ 1, kt + 1);
    f16x8 af[MI][2], bf[NJ][2];
#pragma unroll
    for (int i = 0; i < MI; ++i)
#pragma unroll
      for (int kk = 0; kk < 2; ++kk)
        af[i][kk] = *(const f16x8*)&As[bb][(size_t)(wm * (BM / 2) + i * 16 + lr) * 64 +
                                           ((kk * 4 + kh) ^ sw) * 8];
#pragma unroll
    for (int j = 0; j < NJ; ++j)
#pragma unroll
      for (int kk = 0; kk < 2; ++kk)
        bf[j][kk] = *(const f16x8*)&Bs[bb][(size_t)(wn * (BN / 2) + j * 16 + lr) * 64 +
                                           ((kk * 4 + kh) ^ sw) * 8];
#pragma unroll
    for (int kk = 0; kk < 2; ++kk)
#pragma unroll
      for (int i = 0; i < MI; ++i)
#pragma unroll
        for (int j = 0; j < NJ; ++j)
          acc[i][j] = __builtin_amdgcn_mfma_f32_16x16x32_f16(af[i][kk], bf[j][kk], acc[i][j], 0, 0, 0);
    __syncthreads();
    bb ^= 1;
  }

#pragma unroll
  for (int j = 0; j < NJ; ++j) {
    int cn = n0 + wn * (BN / 2) + j * 16 + lr;
    if (cn >= N) continue;
    float sc = 1.f, sh = 0.f, bs = 0.f;
    if (MODE >= 1) {
      float g = bnp[cn], be = bnp[N + cn];
      float mm = bnp[2 * N + cn], vv = bnp[3 * N + cn];
      sc = rsqrtf(vv + EPSF) * g;
      sh = be - mm * sc;
    }
    if (MODE == 2 || MODE == 3) bs = bias[cn];
#pragma unroll
    for (int i = 0; i < MI; ++i) {
#pragma unroll
      for (int rr = 0; rr < 4; ++rr) {
        int r = m0 + wm * (BM / 2) + i * 16 + kh * 4 + rr;
        float v = acc[i][j][rr];
        if (MODE == 2 || MODE == 3) v += bs;
        if (MODE >= 1) v = fmaf(v, sc, sh);
        if (MODE == 2) v = v > 0.f ? v : 0.f;
        size_t o = (size_t)r * N + cn;
        if (MODE == 1 || MODE == 3) v += (float)res16[o];
        C16[o] = (_Float16)v;
      }
    }
  }
}

// ------- causal depthwise conv1d + silu on xBC (fp16 in/out); softplus dt; LOG-decay -------
__global__ __launch_bounds__(256) void k_convprep(
    const _Float16* __restrict__ ZX16, const float* __restrict__ cw,
    const float* __restrict__ cb, const float* __restrict__ dtb,
    const float* __restrict__ Alog, _Float16* __restrict__ XBC16,
    float* __restrict__ DT, float* __restrict__ DLA) {
  int m = blockIdx.x;
  int c = blockIdx.y * 256 + threadIdx.x;
  int l = m & 255;
  if (c < DCONV_N) {
    const float* cwp = cw + c * 4;
    float acc = cb[c];
#pragma unroll
    for (int k = 0; k < 4; ++k) {
      int dl = l + k - 3;
      if (dl >= 0)
        acc = fmaf((float)ZX16[(size_t)(m + k - 3) * DPROJ_N + DI_N + c], cwp[k], acc);
    }
    XBC16[(size_t)m * DCONV_N + c] = (_Float16)(acc * sigf(acc));
  } else if (c < DCONV_N + NH_N) {
    int h = c - DCONV_N;
    float xx = (float)ZX16[(size_t)m * DPROJ_N + DI_N + DCONV_N + h] + dtb[h];
    float dt = xx > 20.f ? xx : log1pf(__expf(xx));
    DT[m * NH_N + h] = dt;
    DLA[m * NH_N + h] = -dt * __expf(Alog[h]);  // log(dA), always finite, <= 0
  }
}

// ------- selective scan v3: Mamba2 SSD chunked, MFMA. grid 256=(b,h), 256 thr (4 waves) -------
__global__ __launch_bounds__(256) void k_scan(
    const _Float16* __restrict__ XBC16, const float* __restrict__ DT,
    const float* __restrict__ DLA, const float* __restrict__ Dp,
    float* __restrict__ Y) {
  __shared__ _Float16 sC[64][72];    // C[l][n]
  __shared__ _Float16 sB[64][72];    // B[l][n]
  __shared__ _Float16 sBts[64][72];  // [n][j] = B[j][n]*es[j]
  __shared__ _Float16 sXt[64][72];   // [p][l] = dt[l]*x[l][p]
  __shared__ _Float16 sP[64][72];    // P[l][j]
  __shared__ _Float16 sH[64][72];    // h[p][n] fp16 mirror
  __shared__ float sH32[64][68];     // h[p][n] fp32 master
  __shared__ float sS[64], sEl[64], sEs[64], sDt[64];
  __shared__ float sCpt;

  const int b = blockIdx.x >> 5, h = blockIdx.x & 31;
  const int t = threadIdx.x;
  const int w = t >> 6, lane = t & 63;
  const int lr = lane & 15, kh = lane >> 4;
  const float Dh = Dp[h];

  {  // zero h
    _Float16* hp = &sH[0][0];
    float* h32p = &sH32[0][0];
    for (int i = t; i < 64 * 72; i += 256) hp[i] = (_Float16)0.f;
    for (int i = t; i < 64 * 68; i += 256) h32p[i] = 0.f;
  }

  for (int c = 0; c < 4; ++c) {
    const int mbase = b * L_N + c * 64;
    __syncthreads();  // A: protect LDS reuse across chunks (incl. h16 writes)

    if (t < 64) {  // B: segsum in wave 0
      int l = t;
      float v = DLA[(mbase + l) * NH_N + h];
#pragma unroll
      for (int o = 1; o < 64; o <<= 1) {
        float u = __shfl_up(v, o);
        v += (l >= o) ? u : 0.f;
      }
      sS[l] = v;
      sEl[l] = __expf(v);
      float s63 = __shfl(v, 63);
      sEs[l] = __expf(s63 - v);
      if (l == 63) sCpt = __expf(s63);
      sDt[l] = DT[(mbase + l) * NH_N + h];
    }
    __syncthreads();  // B -> C

    {  // C: build tiles. thread = (row l = t>>2, col quarter q = t&3)
      int l = t >> 2, q = t & 3;
      const _Float16* row = XBC16 + (size_t)(mbase + l) * DCONV_N;
      float dt_l = sDt[l], es_l = sEs[l];
      // B
      f16x8 b0 = *(const f16x8*)&row[DI_N + q * 16];
      f16x8 b1 = *(const f16x8*)&row[DI_N + q * 16 + 8];
      *(f16x8*)&sB[l][q * 16] = b0;
      *(f16x8*)&sB[l][q * 16 + 8] = b1;
#pragma unroll
      for (int i = 0; i < 8; ++i) {
        sBts[q * 16 + i][l] = (_Float16)((float)b0[i] * es_l);
        sBts[q * 16 + 8 + i][l] = (_Float16)((float)b1[i] * es_l);
      }
      // C
      *(f16x8*)&sC[l][q * 16] = *(const f16x8*)&row[DI_N + DS_N + q * 16];
      *(f16x8*)&sC[l][q * 16 + 8] = *(const f16x8*)&row[DI_N + DS_N + q * 16 + 8];
      // x -> Xd^T
      f16x8 x0 = *(const f16x8*)&row[h * HD_N + q * 16];
      f16x8 x1 = *(const f16x8*)&row[h * HD_N + q * 16 + 8];
#pragma unroll
      for (int i = 0; i < 8; ++i) {
        sXt[q * 16 + i][l] = (_Float16)((float)x0[i] * dt_l);
        sXt[q * 16 + 8 + i][l] = (_Float16)((float)x1[i] * dt_l);
      }
    }
    __syncthreads();  // C -> D

    // D: S = C@B^T ; Yinter = C@h^T
    f32x4 Sacc[4], Yacc[4];
#pragma unroll
    for (int j = 0; j < 4; ++j) { Sacc[j] = (f32x4)(0.f); Yacc[j] = (f32x4)(0.f); }
    {
      f16x8 aC[2];
#pragma unroll
      for (int kk = 0; kk < 2; ++kk)
        aC[kk] = *(const f16x8*)&sC[16 * w + lr][kk * 32 + kh * 8];
#pragma unroll
      for (int kk = 0; kk < 2; ++kk)
#pragma unroll
        for (int jt = 0; jt < 4; ++jt) {
          f16x8 bB = *(const f16x8*)&sB[jt * 16 + lr][kk * 32 + kh * 8];
          f16x8 bH = *(const f16x8*)&sH[jt * 16 + lr][kk * 32 + kh * 8];
          Sacc[jt] = __builtin_amdgcn_mfma_f32_16x16x32_f16(aC[kk], bB, Sacc[jt], 0, 0, 0);
          Yacc[jt] = __builtin_amdgcn_mfma_f32_16x16x32_f16(aC[kk], bH, Yacc[jt], 0, 0, 0);
        }
    }

    // E: mask P, scale Yinter rows by el
#pragma unroll
    for (int rr = 0; rr < 4; ++rr) {
      int l = 16 * w + kh * 4 + rr;
      float sl = sS[l], el = sEl[l];
#pragma unroll
      for (int jt = 0; jt < 4; ++jt) {
        int j = jt * 16 + lr;
        float pv = (j <= l) ? Sacc[jt][rr] * __expf(sl - sS[j]) : 0.f;
        sP[l][j] = (_Float16)pv;
        Yacc[jt][rr] *= el;
      }
    }
    __syncthreads();  // E -> F

    // F: Y += P@Xd^T ; Hacc = Xd^T-rows @ Bts^T
    f32x4 Hacc[4];
#pragma unroll
    for (int j = 0; j < 4; ++j) Hacc[j] = (f32x4)(0.f);
    {
      f16x8 aP[2], aX[2];
#pragma unroll
      for (int kk = 0; kk < 2; ++kk) {
        aP[kk] = *(const f16x8*)&sP[16 * w + lr][kk * 32 + kh * 8];
        aX[kk] = *(const f16x8*)&sXt[16 * w + lr][kk * 32 + kh * 8];
      }
#pragma unroll
      for (int kk = 0; kk < 2; ++kk)
#pragma unroll
        for (int jt = 0; jt < 4; ++jt) {
          f16x8 bX = *(const f16x8*)&sXt[jt * 16 + lr][kk * 32 + kh * 8];
          f16x8 bBt = *(const f16x8*)&sBts[jt * 16 + lr][kk * 32 + kh * 8];
          Yacc[jt] = __builtin_amdgcn_mfma_f32_16x16x32_f16(aP[kk], bX, Yacc[jt], 0, 0, 0);
          Hacc[jt] = __builtin_amdgcn_mfma_f32_16x16x32_f16(aX[kk], bBt, Hacc[jt], 0, 0, 0);
        }
    }

    // G: epilogue — Y out (+D skip), h update
    float cpt = sCpt;
#pragma unroll
    for (int rr = 0; rr < 4; ++rr) {
      int lrow = 16 * w + kh * 4 + rr;
      int m = mbase + lrow;
#pragma unroll
      for (int jt = 0; jt < 4; ++jt) {
        int p = jt * 16 + lr;
        float xr = (float)XBC16[(size_t)m * DCONV_N + h * HD_N + p];
        Y[(size_t)m * DI_N + h * HD_N + p] = fmaf(Dh, xr, Yacc[jt][rr]);
        float hv = fmaf(cpt, sH32[lrow][jt * 16 + lr], Hacc[jt][rr]);
        sH32[lrow][jt * 16 + lr] = hv;
        sH[lrow][jt * 16 + lr] = (_Float16)hv;
      }
    }
  }
}

// ------- gate with silu(z) + RMSNorm (over DI) -> fp16; thread owns 8 contiguous c -------
__global__ __launch_bounds__(256) void k_gatenorm(
    const float* __restrict__ Y, const _Float16* __restrict__ ZX16,
    const float* __restrict__ nw, _Float16* __restrict__ YN16) {
  int m = blockIdx.x, t = threadIdx.x;
  const float* y = Y + (size_t)m * DI_N;
  const _Float16* z = ZX16 + (size_t)m * DPROJ_N;
  int c0 = t * 8;
  float4 y0 = *(const float4*)&y[c0];
  float4 y1 = *(const float4*)&y[c0 + 4];
  f16x8 z8 = *(const f16x8*)&z[c0];
  float yv[8] = {y0.x, y0.y, y0.z, y0.w, y1.x, y1.y, y1.z, y1.w};
  float vals[8];
  float ss = 0.f;
#pragma unroll
  for (int j = 0; j < 8; ++j) {
    float zz = (float)z8[j];
    float vv = yv[j] * zz * sigf(zz);
    vals[j] = vv;
    ss = fmaf(vv, vv, ss);
  }
#pragma unroll
  for (int o = 1; o < 64; o <<= 1) ss += __shfl_xor(ss, o);
  __shared__ float sred[4];
  if ((t & 63) == 0) sred[t >> 6] = ss;
  __syncthreads();
  float tot = sred[0] + sred[1] + sred[2] + sred[3];
  float scale = rsqrtf(tot * (1.f / DI_N) + EPSF);
  float4 nw0 = *(const float4*)&nw[c0];
  float4 nw1 = *(const float4*)&nw[c0 + 4];
  float nv[8] = {nw0.x, nw0.y, nw0.z, nw0.w, nw1.x, nw1.y, nw1.z, nw1.w};
  f16x8 o;
#pragma unroll
  for (int j = 0; j < 8; ++j) o[j] = (_Float16)(vals[j] * scale * nv[j]);
  *(f16x8*)&YN16[(size_t)m * DI_N + c0] = o;
}

// ------- final transpose: Tok16[m][d] -> out[b][d][l] fp32 -------
__global__ __launch_bounds__(256) void k_transpose(
    const _Float16* __restrict__ Tok16, float* __restrict__ out) {
  __shared__ float tile[32][33];
  int d0 = blockIdx.x * 32, m0 = blockIdx.y * 32;
  int tx = threadIdx.x & 31, ty = threadIdx.x >> 5;
  for (int i = ty; i < 32; i += 8)
    tile[i][tx] = (float)Tok16[(size_t)(m0 + i) * DM_N + d0 + tx];
  __syncthreads();
  int b = m0 >> 8, l0 = m0 & 255;
  for (int i = ty; i < 32; i += 8)
    out[((size_t)b * DM_N + d0 + i) * L_N + l0 + tx] = tile[tx][i];
}

extern "C" void kernel_launch(void* const* d_in, const int* in_sizes, int n_in,
                              void* d_out, int out_size, void* d_ws, size_t ws_size,
                              hipStream_t stream) {
  const float* image = (const float*)d_in[0];
  const float* conv1_w = (const float*)d_in[1];
  const float* bn1 = (const float*)d_in[2];
  const float* conv2_w = (const float*)d_in[3];
  const float* bn2 = (const float*)d_in[4];
  const float* ds_w = (const float*)d_in[5];
  const float* ds_bn = (const float*)d_in[6];
  const float* in_proj_w = (const float*)d_in[7];
  const float* conv1d_w = (const float*)d_in[8];
  const float* conv1d_b = (const float*)d_in[9];
  const float* dt_bias = (const float*)d_in[10];
  const float* A_log = (const float*)d_in[11];
  const float* Dpar = (const float*)d_in[12];
  const float* norm_w = (const float*)d_in[13];
  const float* out_proj_w = (const float*)d_in[14];
  const float* blk_bn = (const float*)d_in[15];
  const float* ff_w1 = (const float*)d_in[16];
  const float* ff_b1 = (const float*)d_in[17];
  const float* ff_bn1 = (const float*)d_in[18];
  const float* ff_w2 = (const float*)d_in[19];
  const float* ff_b2 = (const float*)d_in[20];
  const float* ff_bn2 = (const float*)d_in[21];

  // workspace: fp32 region (YR, DT, DLA) then fp16 region (~74 MB total)
  float* ws = (float*)d_ws;
  float* YR = ws;                           // 2048*2048 fp32; stem X1h aliases this
  float* DTb = YR + (size_t)NTOK * DI_N;    // 2048*32
  float* DLAb = DTb + (size_t)NTOK * NH_N;  // 2048*32
  _Float16* Tok16 = (_Float16*)(DLAb + (size_t)NTOK * NH_N);  // 2048*1024
  _Float16* ZX16 = Tok16 + (size_t)NTOK * DM_N;               // 2048*4256
  _Float16* XBC16 = ZX16 + (size_t)NTOK * DPROJ_N;            // 2048*2176
  _Float16* YN16 = XBC16 + (size_t)NTOK * DCONV_N;            // 2048*2048
  _Float16* H116 = YN16 + (size_t)NTOK * DI_N;                // 2048*2048
  _Float16* W16 = H116 + (size_t)NTOK * DI_N;                 // 4352*1024
  _Float16* W2t = W16 + (size_t)NPAD_INPROJ * DM_N;           // 49*64*32
  _Float16* W1t = W2t + (size_t)49 * 64 * 32;                 // 32*64
  _Float16* X1h = (_Float16*)YR;

  k_w1t<<<8, 256, 0, stream>>>(conv1_w, W1t);
  k_conv1m<<<dim3(8, 32, 4), 256, 0, stream>>>(image, W1t, bn1, X1h);
  k_w2t<<<(49 * 64 * 32 + 255) / 256, 256, 0, stream>>>(conv2_w, W2t);
  k_conv2m<<<dim3(8, 16, 4), 256, 0, stream>>>(X1h, W2t, bn2, image, ds_w, ds_bn, Tok16);

  for (int i = 0; i < 4; ++i) {
    const float* Wi = in_proj_w + (size_t)i * DPROJ_N * DM_N;
    const float* cw = conv1d_w + (size_t)i * DCONV_N * 4;
    const float* cb = conv1d_b + (size_t)i * DCONV_N;
    const float* dtb = dt_bias + i * NH_N;
    const float* al = A_log + i * NH_N;
    const float* dd = Dpar + i * NH_N;
    const float* nw = norm_w + i * DI_N;
    const float* Wo = out_proj_w + (size_t)i * DM_N * DI_N;
    const float* bbn = blk_bn + (size_t)i * 4 * DM_N;
    const float* w1 = ff_w1 + (size_t)i * FFH_N * DM_N;
    const float* b1 = ff_b1 + i * FFH_N;
    const float* fbn1 = ff_bn1 + (size_t)i * 4 * FFH_N;
    const float* w2 = ff_w2 + (size_t)i * DM_N * FFH_N;
    const float* b2 = ff_b2 + i * DM_N;
    const float* fbn2 = ff_bn2 + (size_t)i * 4 * DM_N;

    // in_proj: ZX16[2048,4256] = Tok16 x Wi^T   (BM=64,BN=128 -> 1088 blocks)
    k_tohalf8<<<(NPAD_INPROJ * 1024 / 8 + 255) / 256, 256, 0, stream>>>(
        Wi, W16, DPROJ_N * DM_N, NPAD_INPROJ * DM_N);
    k_mgemm<0, 64, 128><<<dim3(34, 32), 256, 0, stream>>>(
        Tok16, W16, NTOK, DPROJ_N, DM_N, nullptr, nullptr, nullptr, ZX16);
    k_convprep<<<dim3(NTOK, 9), 256, 0, stream>>>(ZX16, cw, cb, dtb, al, XBC16, DTb, DLAb);
    k_scan<<<256, 256, 0, stream>>>(XBC16, DTb, DLAb, dd, YR);
    k_gatenorm<<<NTOK, 256, 0, stream>>>(YR, ZX16, nw, YN16);
    // out_proj: Tok16 = bn(YN16 x Wo^T) + Tok16   (BM=64,BN=64 -> 512 blocks)
    k_tohalf8<<<(DM_N * DI_N / 8 + 255) / 256, 256, 0, stream>>>(
        Wo, W16, DM_N * DI_N, DM_N * DI_N);
    k_mgemm<1, 64, 64><<<dim3(16, 32), 256, 0, stream>>>(
        YN16, W16, NTOK, DM_N, DI_N, nullptr, bbn, Tok16, Tok16);
    // ff1: H116 = relu(bn(Tok16 x w1^T + b1))   (BM=64,BN=128 -> 512 blocks)
    k_tohalf8<<<(FFH_N * DM_N / 8 + 255) / 256, 256, 0, stream>>>(
        w1, W16, FFH_N * DM_N, FFH_N * DM_N);
    k_mgemm<2, 64, 128><<<dim3(16, 32), 256, 0, stream>>>(
        Tok16, W16, NTOK, FFH_N, DM_N, b1, fbn1, nullptr, H116);
    // ff2: Tok16 = bn(H116 x w2^T + b2) + Tok16   (BM=64,BN=64 -> 512 blocks)
    k_tohalf8<<<(DM_N * FFH_N / 8 + 255) / 256, 256, 0, stream>>>(
        w2, W16, DM_N * FFH_N, DM_N * FFH_N);
    k_mgemm<3, 64, 64><<<dim3(16, 32), 256, 0, stream>>>(
        H116, W16, NTOK, DM_N, FFH_N, b2, fbn2, Tok16, Tok16);
  }
  k_transpose<<<dim3(32, 64), 256, 0, stream>>>(Tok16, (float*)d_out);
}